// Round 8
// baseline (280.956 us; speedup 1.0000x reference)
//
#include <hip/hip_runtime.h>
#include <cstdint>

// Problem constants
constexpr int BB   = 2;
constexpr int SS   = 2048;
constexpr int DD   = 768;
constexpr int HH   = 12;
constexpr int NTOK = BB * SS;          // 4096
constexpr int KSEL = 409;              // int((1-0.8)*2048)
constexpr int KPAD = 448;              // 7 kv-tiles of 64
constexpr int NKT  = 7;                // kv tiles of 64 keys

typedef __bf16 bf16x8 __attribute__((ext_vector_type(8)));
typedef float  f32x4  __attribute__((ext_vector_type(4)));

__device__ __forceinline__ float b2f(unsigned short u) {
  return __uint_as_float(((unsigned)u) << 16);
}
__device__ __forceinline__ unsigned short f2b(float f) {
  unsigned u = __float_as_uint(f);
  u += 0x7fffu + ((u >> 16) & 1u);   // RNE
  return (unsigned short)(u >> 16);
}

__device__ __forceinline__ void gload_lds16(const void* gsrc, void* ldst) {
  __builtin_amdgcn_global_load_lds(
      (__attribute__((address_space(1))) void*)(gsrc),
      (__attribute__((address_space(3))) void*)(ldst), 16, 0, 0);
}

// -------- fused prep: xb, xpb (=x+PE), importance = x @ w_sparse + b --------
__global__ __launch_bounds__(256) void prep_imp(const float* __restrict__ x,
                                                const float* __restrict__ wsp,
                                                const float* __restrict__ bsp,
                                                unsigned short* __restrict__ xb,
                                                unsigned short* __restrict__ xpb,
                                                float* __restrict__ imp) {
  int row = blockIdx.x;                 // 0..4095
  int srow = row & (SS - 1);
  int tid = threadIdx.x;
  const float* xr = x + (long)row * DD;
  float acc = 0.f;
#pragma unroll
  for (int k = 0; k < 3; ++k) {
    int c = tid + k * 256;
    float xv = xr[c];
    xb[(long)row * DD + c] = f2b(xv);
    int j2 = c & ~1;
    float freq = __expf((float)j2 * -0.011992630692677323f);  // exp(-j2*ln(1e4)/768)
    float ang = (float)srow * freq;
    float pe = (c & 1) ? cosf(ang) : sinf(ang);
    xpb[(long)row * DD + c] = f2b(xv + pe);
    acc += xv * wsp[c];
  }
#pragma unroll
  for (int m = 1; m < 64; m <<= 1) acc += __shfl_xor(acc, m, 64);
  __shared__ float red[4];
  int wv = tid >> 6, lane = tid & 63;
  if (lane == 0) red[wv] = acc;
  __syncthreads();
  if (tid == 0) imp[row] = red[0] + red[1] + red[2] + red[3] + bsp[0];
}

// ---------------- transpose all weights to bf16 B^T (N x K) -----------------
// dest layout: WTx4 = [wgq|wlq|wlk|wlv] (3072xK), WTkv = [wgk|wgv] (1536xK),
// WTqt = wtq (768xK), WTtkv = [wtk|wtv] (1536xK), WTo = w_out^T (768x2304)
__global__ void transpose_all(const float* w0, const float* w1, const float* w2,
                              const float* w3, const float* w4, const float* w5,
                              const float* w6, const float* w7, const float* w8,
                              const float* w9,
                              unsigned short* WTx4, unsigned short* WTkv,
                              unsigned short* WTqt, unsigned short* WTtkv,
                              unsigned short* WTo) {
  __shared__ float tile[32][33];
  int z = blockIdx.z;
  const float* srcs[10] = {w0, w1, w2, w3, w4, w5, w6, w7, w8, w9};
  const float* src = srcs[z];
  unsigned short* dst;
  int R = DD;
  switch (z) {
    case 0: dst = WTx4;                       break;  // wgq
    case 1: dst = WTkv;                       break;  // wgk
    case 2: dst = WTkv + (long)DD * DD;       break;  // wgv
    case 3: dst = WTx4 + (long)DD * DD;       break;  // wlq
    case 4: dst = WTx4 + (long)2 * DD * DD;   break;  // wlk
    case 5: dst = WTx4 + (long)3 * DD * DD;   break;  // wlv
    case 6: dst = WTqt;                       break;  // wtq
    case 7: dst = WTtkv;                      break;  // wtk
    case 8: dst = WTtkv + (long)DD * DD;      break;  // wtv
    default: dst = WTo; R = 2304;             break;  // w_out
  }
  int r0 = blockIdx.y * 32;
  if (r0 >= R) return;
  int c0 = blockIdx.x * 32;
  int tx = threadIdx.x, ty = threadIdx.y;
  for (int i = ty; i < 32; i += 8) tile[i][tx] = src[(long)(r0 + i) * DD + c0 + tx];
  __syncthreads();
  for (int i = ty; i < 32; i += 8) dst[(long)(c0 + i) * R + r0 + tx] = f2b(tile[tx][i]);
}

// ---------------- top-k via bitonic sort (value desc, index asc) ------------
__global__ __launch_bounds__(1024) void topk_kernel(const float* __restrict__ imp,
                                                    int* __restrict__ sel) {
  __shared__ unsigned long long keys[SS];
  int b = blockIdx.x, tid = threadIdx.x;
  for (int i = tid; i < SS; i += 1024) {
    float v = imp[b * SS + i];
    unsigned u = __float_as_uint(v);
    u = (u & 0x80000000u) ? ~u : (u | 0x80000000u);   // ascending-order map
    unsigned du = ~u;                                  // descending
    keys[i] = ((unsigned long long)du << 32) | (unsigned)i;
  }
  __syncthreads();
  for (int k = 2; k <= SS; k <<= 1) {
    for (int j = k >> 1; j > 0; j >>= 1) {
      for (int i = tid; i < SS; i += 1024) {
        int p = i ^ j;
        if (p > i) {
          unsigned long long a = keys[i], bb = keys[p];
          bool up = ((i & k) == 0);
          if ((a > bb) == up) { keys[i] = bb; keys[p] = a; }
        }
      }
      __syncthreads();
    }
  }
  for (int i = tid; i < KSEL; i += 1024) sel[b * KSEL + i] = (int)(keys[i] & 0xffffffffu);
}

// ---------------- gate: mean over s, then softmax(mean @ w_gate + b) --------
__global__ __launch_bounds__(256) void gate1(const float* __restrict__ x,
                                             float* __restrict__ partial) {
  int b = blockIdx.y, chunk = blockIdx.x, tid = threadIdx.x;
  for (int c = tid; c < DD; c += 256) {
    const float* xp = x + ((long)(b * SS + chunk * 128)) * DD + c;
    float acc = 0.f;
    for (int s2 = 0; s2 < 128; ++s2) acc += xp[(long)s2 * DD];
    partial[(long)(b * 16 + chunk) * DD + c] = acc;
  }
}

__global__ __launch_bounds__(256) void gate2(const float* __restrict__ partial,
                                             const float* __restrict__ w_gate,
                                             const float* __restrict__ b_gate,
                                             float* __restrict__ fw) {
  int b = blockIdx.x, tid = threadIdx.x;
  __shared__ float meanbuf[DD];
  __shared__ float lg[3];
  for (int c = tid; c < DD; c += 256) {
    float acc = 0.f;
    for (int p = 0; p < 16; ++p) acc += partial[(long)(b * 16 + p) * DD + c];
    meanbuf[c] = acc * (1.0f / (float)SS);
  }
  __syncthreads();
  if (tid < 3) {
    float acc = b_gate[tid];
    for (int d = 0; d < DD; ++d) acc += meanbuf[d] * w_gate[d * 3 + tid];
    lg[tid] = acc;
  }
  __syncthreads();
  if (tid == 0) {
    float mx = fmaxf(lg[0], fmaxf(lg[1], lg[2]));
    float e0 = expf(lg[0] - mx), e1 = expf(lg[1] - mx), e2 = expf(lg[2] - mx);
    float inv = 1.f / (e0 + e1 + e2);
    fw[b * 3 + 0] = e0 * inv; fw[b * 3 + 1] = e1 * inv; fw[b * 3 + 2] = e2 * inv;
  }
}

// ---------------- MFMA GEMM: C = A(MxK) * BT(NxK)^T --------------------------
// 128x128 tile, BK=32, 2-phase double-buffered staging, XCD-aware bijective
// block swizzle (identity when nwg % 8 != 0).
template <int OUT_BF16>
__global__ __launch_bounds__(256) void gemm_tile(const unsigned short* __restrict__ A,
                                                 const unsigned short* __restrict__ BT,
                                                 void* __restrict__ C,
                                                 const float* __restrict__ bias,
                                                 int N, int K) {
  __shared__ unsigned short As[2][128 * 32];
  __shared__ unsigned short Bs[2][128 * 32];
  const int tid = threadIdx.x;
  const int lane = tid & 63;
  const int wv = tid >> 6;
  const int wr = wv >> 1, wc = wv & 1;

  int nwg = gridDim.x * gridDim.y;
  int lin = blockIdx.y * gridDim.x + blockIdx.x;
  int swz = lin;
  if ((nwg & 7) == 0) {
    int chunk = nwg >> 3;
    swz = (lin & 7) * chunk + (lin >> 3);
  }
  const long rowBase = (long)(swz / gridDim.x) * 128;
  const long colBase = (long)(swz % gridDim.x) * 128;

  f32x4 acc[4][4];
#pragma unroll
  for (int i = 0; i < 4; ++i)
#pragma unroll
    for (int j = 0; j < 4; ++j)
#pragma unroll
      for (int r = 0; r < 4; ++r) acc[i][j][r] = 0.f;

  const int g0 = tid, g1 = tid + 256;
  const int r0 = g0 >> 2, k80 = (g0 & 3) ^ ((r0 >> 1) & 3);
  const int r1 = g1 >> 2, k81 = (g1 & 3) ^ ((r1 >> 1) & 3);
  const unsigned short* ga0 = A + (rowBase + r0) * (long)K + k80 * 8;
  const unsigned short* ga1 = A + (rowBase + r1) * (long)K + k81 * 8;
  const unsigned short* gb0 = BT + (colBase + r0) * (long)K + k80 * 8;
  const unsigned short* gb1 = BT + (colBase + r1) * (long)K + k81 * 8;

  const int k8 = lane >> 4;
  const int fr = lane & 15;
  int aoff[4], boff[4];
#pragma unroll
  for (int i = 0; i < 4; ++i) {
    int rowA = wr * 64 + i * 16 + fr;
    aoff[i] = (rowA * 4 + (k8 ^ ((rowA >> 1) & 3))) * 8;
    int rowB = wc * 64 + i * 16 + fr;
    boff[i] = (rowB * 4 + (k8 ^ ((rowB >> 1) & 3))) * 8;
  }

  auto stage = [&](int buf, int t) {
    int ko = t * 32;
    gload_lds16(ga0 + ko, &As[buf][g0 * 8]);
    gload_lds16(ga1 + ko, &As[buf][g1 * 8]);
    gload_lds16(gb0 + ko, &Bs[buf][g0 * 8]);
    gload_lds16(gb1 + ko, &Bs[buf][g1 * 8]);
  };

  const int nk = K >> 5;
  stage(0, 0);
  __syncthreads();
  for (int t = 0; t < nk; ++t) {
    int cur = t & 1;
    if (t + 1 < nk) stage(cur ^ 1, t + 1);
    bf16x8 af[4], bfr[4];
#pragma unroll
    for (int i = 0; i < 4; ++i) af[i] = *(const bf16x8*)(&As[cur][aoff[i]]);
#pragma unroll
    for (int i = 0; i < 4; ++i) bfr[i] = *(const bf16x8*)(&Bs[cur][boff[i]]);
#pragma unroll
    for (int mi = 0; mi < 4; ++mi)
#pragma unroll
      for (int ni = 0; ni < 4; ++ni)
        acc[mi][ni] = __builtin_amdgcn_mfma_f32_16x16x32_bf16(af[mi], bfr[ni], acc[mi][ni], 0, 0, 0);
    __syncthreads();   // drains vmcnt for the t+1 stage + protects buffers
  }

  const int orow0 = (lane >> 4) * 4;
#pragma unroll
  for (int mi = 0; mi < 4; ++mi) {
    long gr = rowBase + wr * 64 + mi * 16 + orow0;
#pragma unroll
    for (int ni = 0; ni < 4; ++ni) {
      long gc = colBase + wc * 64 + ni * 16 + fr;
#pragma unroll
      for (int r = 0; r < 4; ++r) {
        float v = acc[mi][ni][r];
        if (OUT_BF16) {
          ((unsigned short*)C)[(gr + r) * (long)N + gc] = f2b(v);
        } else {
          ((float*)C)[(gr + r) * (long)N + gc] = v + bias[gc];
        }
      }
    }
  }
}

// ---------------- gather selected x rows: A_sel[b*448+j] = xb[sel] ----------
__global__ __launch_bounds__(192) void gather_asel(const unsigned short* __restrict__ xb,
                                                   const int* __restrict__ sel,
                                                   unsigned short* __restrict__ A_sel) {
  int j = blockIdx.x;           // 0..447
  int b = blockIdx.y;
  int tid = threadIdx.x;        // 192 * 8B = 1536B = 768 bf16
  uint2* dst = (uint2*)(A_sel + ((long)b * KPAD + j) * DD);
  if (j < KSEL) {
    const uint2* src = (const uint2*)(xb + (long)(b * SS + sel[b * KSEL + j]) * DD);
    dst[tid] = src[tid];
  } else {
    dst[tid] = uint2{0u, 0u};
  }
}

// ---------------- build A_t8: 16 temporal xpb rows, zero-padded to 128 ------
__global__ __launch_bounds__(192) void build_at8(const unsigned short* __restrict__ xpb,
                                                 unsigned short* __restrict__ A_t8) {
  int r = blockIdx.x;           // 0..127
  int tid = threadIdx.x;
  uint2* dst = (uint2*)(A_t8 + (long)r * DD);
  if (r < 16) {
    int b = r >> 3, j = (r & 7) * 256;
    const uint2* src = (const uint2*)(xpb + (long)(b * SS + j) * DD);
    dst[tid] = src[tid];
  } else {
    dst[tid] = uint2{0u, 0u};
  }
}

// ---------------- reformat T8 [128][1536] -> K8 [b][16][768], Vt8 [b][768][32]
__global__ __launch_bounds__(256) void reformat_t8(const unsigned short* __restrict__ T8,
                                                   unsigned short* __restrict__ K8,
                                                   unsigned short* __restrict__ Vt8) {
  int b = blockIdx.y;
  int c = blockIdx.x * 256 + threadIdx.x;   // grid.x = 3 -> c in [0,768)
#pragma unroll
  for (int j = 0; j < 8; ++j) {
    const unsigned short* src = T8 + (long)(b * 8 + j) * 1536;
    K8[((long)b * 16 + j) * DD + c]  = src[c];
    Vt8[((long)b * DD + c) * 32 + j] = src[768 + c];
  }
#pragma unroll
  for (int j = 8; j < 16; ++j) K8[((long)b * 16 + j) * DD + c] = 0;
#pragma unroll
  for (int j = 8; j < 32; ++j) Vt8[((long)b * DD + c) * 32 + j] = 0;
}

// -------- gather V transposed from compact KVg: Vt[b][c][j] -----------------
__global__ __launch_bounds__(256) void gather_vt(const unsigned short* __restrict__ KVg,
                                                 unsigned short* __restrict__ Vt) {
  __shared__ unsigned short tile[16][68];
  int jt = blockIdx.x, ct = blockIdx.y, b = blockIdx.z;   // 28, 12, 2
  int tid = threadIdx.x;
  int jj = tid & 15, cl = tid >> 4;                        // cl 0..15, 4 c each
  int j = jt * 16 + jj;
  const unsigned short* src = KVg + ((long)b * KPAD + j) * 1536 + 768 + ct * 64;
  *(uint2*)&tile[jj][cl * 4] = *(const uint2*)&src[cl * 4];
  __syncthreads();
  int c = tid >> 2;             // 0..63
  int jl = (tid & 3) * 4;       // 0,4,8,12
  unsigned v0 = tile[jl + 0][c], v1 = tile[jl + 1][c];
  unsigned v2 = tile[jl + 2][c], v3 = tile[jl + 3][c];
  unsigned short* dst = Vt + ((long)b * DD + ct * 64 + c) * KPAD + jt * 16 + jl;
  *(uint2*)dst = uint2{v0 | (v1 << 16), v2 | (v3 << 16)};
}

// ---------------- full V transpose for local branch: Vtl[b][c][s] -----------
__global__ __launch_bounds__(256) void transpose_vl(const unsigned short* __restrict__ QKV4,
                                                    unsigned short* __restrict__ Vtl) {
  __shared__ unsigned short tile[16][68];
  int jt = blockIdx.x, ct = blockIdx.y, b = blockIdx.z;   // 128, 12, 2
  int tid = threadIdx.x;
  int jj = tid & 15, cl = tid >> 4;
  const unsigned short* src = QKV4 + ((long)b * SS + jt * 16 + jj) * 3072 + 2304 + ct * 64;
  *(uint2*)&tile[jj][cl * 4] = *(const uint2*)&src[cl * 4];
  __syncthreads();
  int c = tid >> 2;
  int jl = (tid & 3) * 4;
  unsigned v0 = tile[jl + 0][c], v1 = tile[jl + 1][c];
  unsigned v2 = tile[jl + 2][c], v3 = tile[jl + 3][c];
  unsigned short* dst = Vtl + ((long)b * DD + ct * 64 + c) * (long)SS + jt * 16 + jl;
  *(uint2*)dst = uint2{v0 | (v1 << 16), v2 | (v3 << 16)};
}

// ---------------- global-branch flash MFMA attention ------------------------
// Q from QKV4 (col 0, ld 3072), K from compact KVg (cols 0..767, ld 1536,
// rows already in selection order, pad rows zero), V from gathered Vt.
__global__ __launch_bounds__(256) void attn_global_flash(
    const unsigned short* __restrict__ QKV4,  // [4096][3072]
    const unsigned short* __restrict__ KVg,   // [b*448][1536]
    const unsigned short* __restrict__ Vt,    // [b][768][448]
    float* __restrict__ Outp) {               // [b*2048+q][768]
  __shared__ unsigned short Kl[2][64 * 64];
  __shared__ unsigned short Vl[2][64 * 64];
  __shared__ unsigned short Pl[4][16 * 68];
  int tid = threadIdx.x, w = tid >> 6, lane = tid & 63;
  int fr = lane & 15, g = lane >> 4;
  int b = blockIdx.y / HH, h = blockIdx.y % HH, hoff = h * 64;
  int qbase = blockIdx.x * 64 + w * 16;
  long qrow = (long)b * SS + qbase + fr;

  const unsigned short* qptr = QKV4 + qrow * 3072 + hoff + g * 8;
  bf16x8 bq0 = *(const bf16x8*)(qptr);
  bf16x8 bq1 = *(const bf16x8*)(qptr + 32);

  const int s0 = tid, s1 = tid + 256;
  const int r0 = s0 >> 3, c0 = (s0 & 7) ^ (r0 & 7);
  const int r1 = s1 >> 3, c1 = (s1 & 7) ^ (r1 & 7);
  const unsigned short* kg_b = KVg + (long)b * KPAD * 1536 + hoff;
  const unsigned short* vt_b = Vt + ((long)b * DD + hoff) * KPAD;

  auto stage = [&](int buf, int t0) {
    gload_lds16(kg_b + (long)(t0 * 64 + r0) * 1536 + c0 * 8, &Kl[buf][s0 * 8]);
    gload_lds16(kg_b + (long)(t0 * 64 + r1) * 1536 + c1 * 8, &Kl[buf][s1 * 8]);
    gload_lds16(vt_b + (long)r0 * KPAD + t0 * 64 + c0 * 8, &Vl[buf][s0 * 8]);
    gload_lds16(vt_b + (long)r1 * KPAD + t0 * 64 + c1 * 8, &Vl[buf][s1 * 8]);
  };

  f32x4 oacc[4];
#pragma unroll
  for (int mf = 0; mf < 4; ++mf)
#pragma unroll
    for (int r = 0; r < 4; ++r) oacc[mf][r] = 0.f;
  float m = -3.0e38f, l = 0.f;

  stage(0, 0);
  asm volatile("s_waitcnt vmcnt(0)" ::: "memory");
  __syncthreads();

  for (int t = 0; t < NKT; ++t) {
    int cur = t & 1;
    if (t + 1 < NKT) stage(cur ^ 1, t + 1);

    f32x4 st[4];
#pragma unroll
    for (int kt = 0; kt < 4; ++kt) {
      int row = kt * 16 + fr;
      bf16x8 a0 = *(const bf16x8*)(&Kl[cur][(row * 8 + (g ^ (row & 7))) * 8]);
      bf16x8 a1 = *(const bf16x8*)(&Kl[cur][(row * 8 + ((4 + g) ^ (row & 7))) * 8]);
      f32x4 z = {0.f, 0.f, 0.f, 0.f};
      z = __builtin_amdgcn_mfma_f32_16x16x32_bf16(a0, bq0, z, 0, 0, 0);
      st[kt] = __builtin_amdgcn_mfma_f32_16x16x32_bf16(a1, bq1, z, 0, 0, 0);
    }

    float tm = -3.0e38f;
#pragma unroll
    for (int kt = 0; kt < 4; ++kt)
#pragma unroll
      for (int r = 0; r < 4; ++r) {
        int key = t * 64 + kt * 16 + g * 4 + r;
        float s = (key < KSEL) ? st[kt][r] * 0.125f : -1.0e30f;
        st[kt][r] = s;
        tm = fmaxf(tm, s);
      }
    tm = fmaxf(tm, __shfl_xor(tm, 16, 64));
    tm = fmaxf(tm, __shfl_xor(tm, 32, 64));
    float newm = fmaxf(m, tm);
    float f = __expf(m - newm);
    float tsum = 0.f;
#pragma unroll
    for (int kt = 0; kt < 4; ++kt)
#pragma unroll
      for (int r = 0; r < 4; ++r) {
        float e = __expf(st[kt][r] - newm);
        st[kt][r] = e;
        tsum += e;
      }
    tsum += __shfl_xor(tsum, 16, 64);
    tsum += __shfl_xor(tsum, 32, 64);
    l = l * f + tsum;
    m = newm;
#pragma unroll
    for (int mf = 0; mf < 4; ++mf)
#pragma unroll
      for (int r = 0; r < 4; ++r) oacc[mf][r] *= f;

    unsigned short* pw = &Pl[w][fr * 68 + g * 4];
#pragma unroll
    for (int kt = 0; kt < 4; ++kt) {
      uint2 pk;
      pk.x = (unsigned)f2b(st[kt][0]) | ((unsigned)f2b(st[kt][1]) << 16);
      pk.y = (unsigned)f2b(st[kt][2]) | ((unsigned)f2b(st[kt][3]) << 16);
      *(uint2*)(pw + kt * 16) = pk;
    }

    const unsigned short* prd = &Pl[w][fr * 68];
#pragma unroll
    for (int ks2 = 0; ks2 < 2; ++ks2) {
      bf16x8 pf = *(const bf16x8*)(prd + ks2 * 32 + g * 8);
#pragma unroll
      for (int mf = 0; mf < 4; ++mf) {
        int vr = mf * 16 + fr;
        int vc = ks2 * 4 + g;
        bf16x8 vf = *(const bf16x8*)(&Vl[cur][(vr * 8 + (vc ^ (vr & 7))) * 8]);
        oacc[mf] = __builtin_amdgcn_mfma_f32_16x16x32_bf16(vf, pf, oacc[mf], 0, 0, 0);
      }
    }

    asm volatile("s_waitcnt vmcnt(0)" ::: "memory");
    __syncthreads();
  }

  float inv = 1.f / l;
  float* orow = Outp + qrow * DD + hoff;
#pragma unroll
  for (int mf = 0; mf < 4; ++mf) {
    f32x4 ov;
#pragma unroll
    for (int r = 0; r < 4; ++r) ov[r] = oacc[mf][r] * inv;
    *(f32x4*)(orow + mf * 16 + g * 4) = ov;
  }
}

// ---------------- window MFMA attention (local / temporal) ------------------
// MODE 0 (local): QKV4 ld 3072, q_l at 768, k_l at 1536; V from Vtl.
// MODE 1 (temporal): Q from Qt (ld 768, off 0); K8/Vt8 padded buffers.
template <int MODE>
__global__ __launch_bounds__(256) void attn_win_mfma(
    const unsigned short* __restrict__ QKV,
    const unsigned short* __restrict__ K8,    // MODE1 only: [b][16][768]
    const unsigned short* __restrict__ Vt,    // MODE0: [b][768][2048]; MODE1: [b][768][32]
    float* __restrict__ Outp) {
  constexpr int LD   = (MODE == 0) ? 3072 : 768;
  constexpr int QO   = (MODE == 0) ? 768 : 0;
  constexpr int KO   = 1536;
  constexpr long VSTR = (MODE == 0) ? SS : 32;
  __shared__ unsigned short P_lds[4][16 * 40];
  int tid = threadIdx.x, w = tid >> 6, lane = tid & 63;
  int fr = lane & 15, g = lane >> 4;
  int b = blockIdx.y / HH, h = blockIdx.y % HH, hoff = h * 64;
  int qbase = blockIdx.x * 64 + w * 16;
  long qrow = (long)b * SS + qbase + fr;

  const unsigned short* qptr = QKV + qrow * LD + QO + hoff + g * 8;
  bf16x8 bq0 = *(const bf16x8*)(qptr);
  bf16x8 bq1 = *(const bf16x8*)(qptr + 32);

  int kstart = qbase - 8;
  if (kstart < 0) kstart = 0;
  if (kstart > SS - 32) kstart = SS - 32;

  f32x4 st[2];
  if (MODE == 0) {
#pragma unroll
    for (int kt = 0; kt < 2; ++kt) {
      const unsigned short* kp =
          QKV + ((long)b * SS + kstart + kt * 16 + fr) * LD + KO + hoff + g * 8;
      bf16x8 a0 = *(const bf16x8*)(kp);
      bf16x8 a1 = *(const bf16x8*)(kp + 32);
      f32x4 z = {0.f, 0.f, 0.f, 0.f};
      z = __builtin_amdgcn_mfma_f32_16x16x32_bf16(a0, bq0, z, 0, 0, 0);
      st[kt] = __builtin_amdgcn_mfma_f32_16x16x32_bf16(a1, bq1, z, 0, 0, 0);
    }
  } else {
    const unsigned short* kp = K8 + ((long)b * 16 + fr) * DD + hoff + g * 8;
    bf16x8 a0 = *(const bf16x8*)(kp);
    bf16x8 a1 = *(const bf16x8*)(kp + 32);
    f32x4 z = {0.f, 0.f, 0.f, 0.f};
    z = __builtin_amdgcn_mfma_f32_16x16x32_bf16(a0, bq0, z, 0, 0, 0);
    st[0] = __builtin_amdgcn_mfma_f32_16x16x32_bf16(a1, bq1, z, 0, 0, 0);
    st[1] = f32x4{0.f, 0.f, 0.f, 0.f};
  }

  float m = -3.0e38f;
#pragma unroll
  for (int kt = 0; kt < 2; ++kt)
#pragma unroll
    for (int r = 0; r < 4; ++r) {
      int idx = kt * 16 + g * 4 + r;
      bool valid;
      if (MODE == 0) {
        int rel = kstart + idx - qbase - fr;
        valid = (rel >= -8) && (rel <= 8);
      } else {
        valid = (idx < 8);
      }
      float s = valid ? st[kt][r] * 0.125f : -1.0e30f;
      st[kt][r] = s;
      m = fmaxf(m, s);
    }
  m = fmaxf(m, __shfl_xor(m, 16, 64));
  m = fmaxf(m, __shfl_xor(m, 32, 64));

  float lsum = 0.f;
#pragma unroll
  for (int kt = 0; kt < 2; ++kt)
#pragma unroll
    for (int r = 0; r < 4; ++r) {
      float e = __expf(st[kt][r] - m);
      st[kt][r] = e;
      lsum += e;
    }
  lsum += __shfl_xor(lsum, 16, 64);
  lsum += __shfl_xor(lsum, 32, 64);

  unsigned short* pl = &P_lds[w][fr * 40 + g * 4];
#pragma unroll
  for (int kt = 0; kt < 2; ++kt) {
    uint2 pk;
    pk.x = (unsigned)f2b(st[kt][0]) | ((unsigned)f2b(st[kt][1]) << 16);
    pk.y = (unsigned)f2b(st[kt][2]) | ((unsigned)f2b(st[kt][3]) << 16);
    *(uint2*)(pl + kt * 16) = pk;
  }

  f32x4 oacc[4];
#pragma unroll
  for (int mf = 0; mf < 4; ++mf)
#pragma unroll
    for (int r = 0; r < 4; ++r) oacc[mf][r] = 0.f;

  const unsigned short* pr = &P_lds[w][fr * 40 + g * 8];
  bf16x8 pf = *(const bf16x8*)(pr);
  long kb2 = (MODE == 0) ? kstart : 0;
#pragma unroll
  for (int mf = 0; mf < 4; ++mf) {
    const unsigned short* vp =
        Vt + ((long)b * DD + hoff + mf * 16 + fr) * VSTR + kb2 + g * 8;
    bf16x8 vf = *(const bf16x8*)(vp);
    oacc[mf] = __builtin_amdgcn_mfma_f32_16x16x32_bf16(vf, pf, oacc[mf], 0, 0, 0);
  }

  float inv = 1.f / lsum;
  float* orow = Outp + qrow * DD + hoff;
#pragma unroll
  for (int mf = 0; mf < 4; ++mf) {
    f32x4 ov;
#pragma unroll
    for (int r = 0; r < 4; ++r) ov[r] = oacc[mf][r] * inv;
    *(f32x4*)(orow + mf * 16 + g * 4) = ov;
  }
}

// ---------------- layernorm + gate scale + concat to bf16 -------------------
__global__ __launch_bounds__(256) void ln_gate_concat(
    const float* __restrict__ gsrc, const float* __restrict__ lsrc, const float* __restrict__ tsrc,
    const float* __restrict__ gg, const float* __restrict__ gb,
    const float* __restrict__ lgam, const float* __restrict__ lbet,
    const float* __restrict__ tg, const float* __restrict__ tb,
    const float* __restrict__ fw, unsigned short* __restrict__ comb) {
  int row = blockIdx.x;
  int b = row >> 11;
  int tid = threadIdx.x;
  __shared__ float red[8];
  const float* srcs[3] = {gsrc, lsrc, tsrc};
  const float* gams[3] = {gg, lgam, tg};
  const float* bets[3] = {gb, lbet, tb};
#pragma unroll
  for (int br = 0; br < 3; ++br) {
    const float* src = srcs[br] + (long)row * DD;
    float x0 = src[tid], x1 = src[tid + 256], x2 = src[tid + 512];
    float s = x0 + x1 + x2;
    float ss = x0 * x0 + x1 * x1 + x2 * x2;
#pragma unroll
    for (int msk = 1; msk < 64; msk <<= 1) {
      s += __shfl_xor(s, msk, 64);
      ss += __shfl_xor(ss, msk, 64);
    }
    int wv = tid >> 6, lane = tid & 63;
    if (lane == 0) { red[wv] = s; red[4 + wv] = ss; }
    __syncthreads();
    float S4 = red[0] + red[1] + red[2] + red[3];
    float SQ = red[4] + red[5] + red[6] + red[7];
    float mean = S4 * (1.f / (float)DD);
    float var = SQ * (1.f / (float)DD) - mean * mean;
    float rs = rsqrtf(var + 1e-5f);
    float gate = fw[b * 3 + br];
    const float* gam = gams[br];
    const float* bet = bets[br];
    unsigned short* dst = comb + (long)row * 2304 + br * DD;
    dst[tid]       = f2b(((x0 - mean) * rs * gam[tid]       + bet[tid])       * gate);
    dst[tid + 256] = f2b(((x1 - mean) * rs * gam[tid + 256] + bet[tid + 256]) * gate);
    dst[tid + 512] = f2b(((x2 - mean) * rs * gam[tid + 512] + bet[tid + 512]) * gate);
    __syncthreads();
  }
}

// ---------------- launcher ---------------------------------------------------
extern "C" void kernel_launch(void* const* d_in, const int* in_sizes, int n_in,
                              void* d_out, int out_size, void* d_ws, size_t ws_size,
                              hipStream_t stream) {
  const float* x        = (const float*)d_in[0];
  const float* wgq      = (const float*)d_in[1];
  const float* wgk      = (const float*)d_in[2];
  const float* wgv      = (const float*)d_in[3];
  const float* wlq      = (const float*)d_in[4];
  const float* wlk      = (const float*)d_in[5];
  const float* wlv      = (const float*)d_in[6];
  const float* wtq      = (const float*)d_in[7];
  const float* wtk      = (const float*)d_in[8];
  const float* wtv      = (const float*)d_in[9];
  const float* w_out    = (const float*)d_in[10];
  const float* b_out    = (const float*)d_in[11];
  const float* w_gate   = (const float*)d_in[12];
  const float* b_gate   = (const float*)d_in[13];
  const float* w_sparse = (const float*)d_in[14];
  const float* b_sparse = (const float*)d_in[15];
  const float* g_gamma  = (const float*)d_in[16];
  const float* g_beta   = (const float*)d_in[17];
  const float* l_gamma  = (const float*)d_in[18];
  const float* l_beta   = (const float*)d_in[19];
  const float* t_gamma  = (const float*)d_in[20];
  const float* t_beta   = (const float*)d_in[21];
  float* outp = (float*)d_out;

  unsigned short* xb    = (unsigned short*)d_ws;
  unsigned short* xpb   = xb    + (long)NTOK * DD;
  unsigned short* WTx4  = xpb   + (long)NTOK * DD;        // [3072][768]
  unsigned short* WTkv  = WTx4  + (long)3072 * DD;        // [1536][768]
  unsigned short* WTqt  = WTkv  + (long)1536 * DD;        // [768][768]
  unsigned short* WTtkv = WTqt  + (long)DD * DD;          // [1536][768]
  unsigned short* WTo   = WTtkv + (long)1536 * DD;        // [768][2304]
  unsigned short* QKV4  = WTo   + (long)DD * 2304;        // [4096][3072]
  unsigned short* Qt    = QKV4  + (long)NTOK * 3072;      // [4096][768]
  unsigned short* A_sel = Qt    + (long)NTOK * DD;        // [896][768]
  unsigned short* KVg   = A_sel + (long)BB * KPAD * DD;   // [896][1536]
  unsigned short* A_t8  = KVg   + (long)BB * KPAD * 1536; // [128][768]
  unsigned short* T8    = A_t8  + (long)128 * DD;         // [128][1536]
  unsigned short* K8    = T8    + (long)128 * 1536;       // [2][16][768]
  unsigned short* Vt8   = K8    + (long)BB * 16 * DD;     // [2][768][32]
  unsigned short* Vt    = Vt8   + (long)BB * DD * 32;     // [2][768][448]
  unsigned short* comb  = Vt    + (long)BB * DD * KPAD;   // [4096][2304]
  float* gout    = (float*)(comb + (long)NTOK * 2304);
  float* lout    = gout + (long)NTOK * DD;
  float* tout    = lout + (long)NTOK * DD;
  float* imp     = tout + (long)NTOK * DD;
  float* partial = imp + NTOK;
  float* fw      = partial + 32 * DD;
  int*   sel     = (int*)(fw + 8);
  // Vtl reuses xpb (dead after Qt GEMM + A_t8 build)
  unsigned short* Vtl = xpb;                              // [2][768][2048]

  prep_imp<<<NTOK, 256, 0, stream>>>(x, w_sparse, b_sparse, xb, xpb, imp);
  transpose_all<<<dim3(24, 72, 10), dim3(32, 8), 0, stream>>>(
      wgq, wgk, wgv, wlq, wlk, wlv, wtq, wtk, wtv, w_out,
      WTx4, WTkv, WTqt, WTtkv, WTo);
  topk_kernel<<<BB, 1024, 0, stream>>>(imp, sel);
  gate1<<<dim3(16, BB), 256, 0, stream>>>(x, partial);
  gate2<<<BB, 256, 0, stream>>>(partial, w_gate, b_gate, fw);

  // main projection: [q_g | q_l | k_l | v_l]
  gemm_tile<1><<<dim3(24, 32), 256, 0, stream>>>(xb, WTx4, QKV4, nullptr, 3072, DD);
  // selected-row K/V projection for global branch (already in gathered order)
  gather_asel<<<dim3(KPAD, BB), 192, 0, stream>>>(xb, sel, A_sel);
  gemm_tile<1><<<dim3(12, 7), 256, 0, stream>>>(A_sel, WTkv, KVg, nullptr, 1536, DD);
  // temporal: Q full, K/V only at the 16 temporal positions
  gemm_tile<1><<<dim3(6, 32), 256, 0, stream>>>(xpb, WTqt, Qt, nullptr, 768, DD);
  build_at8<<<128, 192, 0, stream>>>(xpb, A_t8);
  gemm_tile<1><<<dim3(12, 1), 256, 0, stream>>>(A_t8, WTtkv, T8, nullptr, 1536, DD);
  reformat_t8<<<dim3(3, BB), 256, 0, stream>>>(T8, K8, Vt8);

  gather_vt<<<dim3(28, 12, BB), 256, 0, stream>>>(KVg, Vt);
  transpose_vl<<<dim3(128, 12, BB), 256, 0, stream>>>(QKV4, Vtl);

  attn_global_flash<<<dim3(32, BB * HH), 256, 0, stream>>>(QKV4, KVg, Vt, gout);
  attn_win_mfma<0><<<dim3(32, BB * HH), 256, 0, stream>>>(QKV4, nullptr, Vtl, lout);
  attn_win_mfma<1><<<dim3(32, BB * HH), 256, 0, stream>>>(Qt, K8, Vt8, tout);

  ln_gate_concat<<<NTOK, 256, 0, stream>>>(gout, lout, tout, g_gamma, g_beta,
                                           l_gamma, l_beta, t_gamma, t_beta, fw, comb);
  gemm_tile<0><<<dim3(6, 32), 256, 0, stream>>>(comb, WTo, outp, b_out, 768, 2304);
}

// Round 9
// 233.890 us; speedup vs baseline: 1.2012x; 1.2012x over previous
//
#include <hip/hip_runtime.h>
#include <cstdint>

// Problem constants
constexpr int BB   = 2;
constexpr int SS   = 2048;
constexpr int DD   = 768;
constexpr int HH   = 12;
constexpr int NTOK = BB * SS;          // 4096
constexpr int KSEL = 409;              // int((1-0.8)*2048)
constexpr int KPAD = 448;              // 7 kv-tiles of 64
constexpr int NKT  = 7;                // kv tiles of 64 keys

typedef __bf16 bf16x8 __attribute__((ext_vector_type(8)));
typedef float  f32x4  __attribute__((ext_vector_type(4)));

__device__ __forceinline__ float b2f(unsigned short u) {
  return __uint_as_float(((unsigned)u) << 16);
}
__device__ __forceinline__ unsigned short f2b(float f) {
  unsigned u = __float_as_uint(f);
  u += 0x7fffu + ((u >> 16) & 1u);   // RNE
  return (unsigned short)(u >> 16);
}

__device__ __forceinline__ void gload_lds16(const void* gsrc, void* ldst) {
  __builtin_amdgcn_global_load_lds(
      (__attribute__((address_space(1))) void*)(gsrc),
      (__attribute__((address_space(3))) void*)(ldst), 16, 0, 0);
}

// -------- fused prep: xb, xpb (=x+PE), importance = x @ w_sparse + b --------
__global__ __launch_bounds__(256) void prep_imp(const float* __restrict__ x,
                                                const float* __restrict__ wsp,
                                                const float* __restrict__ bsp,
                                                unsigned short* __restrict__ xb,
                                                unsigned short* __restrict__ xpb,
                                                float* __restrict__ imp) {
  int row = blockIdx.x;                 // 0..4095
  int srow = row & (SS - 1);
  int tid = threadIdx.x;
  const float* xr = x + (long)row * DD;
  float acc = 0.f;
#pragma unroll
  for (int k = 0; k < 3; ++k) {
    int c = tid + k * 256;
    float xv = xr[c];
    xb[(long)row * DD + c] = f2b(xv);
    int j2 = c & ~1;
    float freq = __expf((float)j2 * -0.011992630692677323f);  // exp(-j2*ln(1e4)/768)
    float ang = (float)srow * freq;
    float pe = (c & 1) ? cosf(ang) : sinf(ang);
    xpb[(long)row * DD + c] = f2b(xv + pe);
    acc += xv * wsp[c];
  }
#pragma unroll
  for (int m = 1; m < 64; m <<= 1) acc += __shfl_xor(acc, m, 64);
  __shared__ float red[4];
  int wv = tid >> 6, lane = tid & 63;
  if (lane == 0) red[wv] = acc;
  __syncthreads();
  if (tid == 0) imp[row] = red[0] + red[1] + red[2] + red[3] + bsp[0];
}

// ---------------- transpose all weights to bf16 B^T (N x K) -----------------
__global__ void transpose_all(const float* w0, const float* w1, const float* w2,
                              const float* w3, const float* w4, const float* w5,
                              const float* w6, const float* w7, const float* w8,
                              const float* w9,
                              unsigned short* WTx4, unsigned short* WTkv,
                              unsigned short* WTqt, unsigned short* WTtkv,
                              unsigned short* WTo) {
  __shared__ float tile[32][33];
  int z = blockIdx.z;
  const float* srcs[10] = {w0, w1, w2, w3, w4, w5, w6, w7, w8, w9};
  const float* src = srcs[z];
  unsigned short* dst;
  int R = DD;
  switch (z) {
    case 0: dst = WTx4;                       break;  // wgq
    case 1: dst = WTkv;                       break;  // wgk
    case 2: dst = WTkv + (long)DD * DD;       break;  // wgv
    case 3: dst = WTx4 + (long)DD * DD;       break;  // wlq
    case 4: dst = WTx4 + (long)2 * DD * DD;   break;  // wlk
    case 5: dst = WTx4 + (long)3 * DD * DD;   break;  // wlv
    case 6: dst = WTqt;                       break;  // wtq
    case 7: dst = WTtkv;                      break;  // wtk
    case 8: dst = WTtkv + (long)DD * DD;      break;  // wtv
    default: dst = WTo; R = 2304;             break;  // w_out
  }
  int r0 = blockIdx.y * 32;
  if (r0 >= R) return;
  int c0 = blockIdx.x * 32;
  int tx = threadIdx.x, ty = threadIdx.y;
  for (int i = ty; i < 32; i += 8) tile[i][tx] = src[(long)(r0 + i) * DD + c0 + tx];
  __syncthreads();
  for (int i = ty; i < 32; i += 8) dst[(long)(c0 + i) * R + r0 + tx] = f2b(tile[tx][i]);
}

// ---------------- top-k via bitonic sort (value desc, index asc) ------------
__global__ __launch_bounds__(1024) void topk_kernel(const float* __restrict__ imp,
                                                    int* __restrict__ sel) {
  __shared__ unsigned long long keys[SS];
  int b = blockIdx.x, tid = threadIdx.x;
  for (int i = tid; i < SS; i += 1024) {
    float v = imp[b * SS + i];
    unsigned u = __float_as_uint(v);
    u = (u & 0x80000000u) ? ~u : (u | 0x80000000u);   // ascending-order map
    unsigned du = ~u;                                  // descending
    keys[i] = ((unsigned long long)du << 32) | (unsigned)i;
  }
  __syncthreads();
  for (int k = 2; k <= SS; k <<= 1) {
    for (int j = k >> 1; j > 0; j >>= 1) {
      for (int i = tid; i < SS; i += 1024) {
        int p = i ^ j;
        if (p > i) {
          unsigned long long a = keys[i], bb = keys[p];
          bool up = ((i & k) == 0);
          if ((a > bb) == up) { keys[i] = bb; keys[p] = a; }
        }
      }
      __syncthreads();
    }
  }
  for (int i = tid; i < KSEL; i += 1024) sel[b * KSEL + i] = (int)(keys[i] & 0xffffffffu);
}

// ---------------- gate: mean over s, then softmax(mean @ w_gate + b) --------
__global__ __launch_bounds__(256) void gate1(const float* __restrict__ x,
                                             float* __restrict__ partial) {
  int b = blockIdx.y, chunk = blockIdx.x, tid = threadIdx.x;
  for (int c = tid; c < DD; c += 256) {
    const float* xp = x + ((long)(b * SS + chunk * 128)) * DD + c;
    float acc = 0.f;
    for (int s2 = 0; s2 < 128; ++s2) acc += xp[(long)s2 * DD];
    partial[(long)(b * 16 + chunk) * DD + c] = acc;
  }
}

__global__ __launch_bounds__(256) void gate2(const float* __restrict__ partial,
                                             const float* __restrict__ w_gate,
                                             const float* __restrict__ b_gate,
                                             float* __restrict__ fw) {
  int b = blockIdx.x, tid = threadIdx.x;
  __shared__ float meanbuf[DD];
  __shared__ float lg[3];
  for (int c = tid; c < DD; c += 256) {
    float acc = 0.f;
    for (int p = 0; p < 16; ++p) acc += partial[(long)(b * 16 + p) * DD + c];
    meanbuf[c] = acc * (1.0f / (float)SS);
  }
  __syncthreads();
  if (tid < 3) {
    float acc = b_gate[tid];
    for (int d = 0; d < DD; ++d) acc += meanbuf[d] * w_gate[d * 3 + tid];
    lg[tid] = acc;
  }
  __syncthreads();
  if (tid == 0) {
    float mx = fmaxf(lg[0], fmaxf(lg[1], lg[2]));
    float e0 = expf(lg[0] - mx), e1 = expf(lg[1] - mx), e2 = expf(lg[2] - mx);
    float inv = 1.f / (e0 + e1 + e2);
    fw[b * 3 + 0] = e0 * inv; fw[b * 3 + 1] = e1 * inv; fw[b * 3 + 2] = e2 * inv;
  }
}

// -------- merged gather: A_sel rows (topk) + A_t8 temporal rows -------------
__global__ __launch_bounds__(192) void gather_pre(const unsigned short* __restrict__ xb,
                                                  const unsigned short* __restrict__ xpb,
                                                  const int* __restrict__ sel,
                                                  unsigned short* __restrict__ A_sel,
                                                  unsigned short* __restrict__ A_t8) {
  int id = blockIdx.x;
  int tid = threadIdx.x;
  if (id < BB * KPAD) {
    int b = id / KPAD, j = id % KPAD;
    uint2* dst = (uint2*)(A_sel + (long)id * DD);
    if (j < KSEL) {
      const uint2* src = (const uint2*)(xb + (long)(b * SS + sel[b * KSEL + j]) * DD);
      dst[tid] = src[tid];
    } else {
      dst[tid] = uint2{0u, 0u};
    }
  } else {
    int r = id - BB * KPAD;     // 0..127
    uint2* dst = (uint2*)(A_t8 + (long)r * DD);
    if (r < 16) {
      int b = r >> 3, j = (r & 7) * 256;
      const uint2* src = (const uint2*)(xpb + (long)(b * SS + j) * DD);
      dst[tid] = src[tid];
    } else {
      dst[tid] = uint2{0u, 0u};
    }
  }
}

// ---------------- fused projection GEMMs (all K=768, 128x128 tiles) ---------
// tiles: QKV4 768 | KVg 84 | Qt 192 | T8 12  => 1056 total (8*132, bijective swz)
__global__ __launch_bounds__(256) void gemm_multi(
    const unsigned short* __restrict__ xb,    const unsigned short* __restrict__ WTx4,
    unsigned short* __restrict__ QKV4,
    const unsigned short* __restrict__ A_sel, const unsigned short* __restrict__ WTkv,
    unsigned short* __restrict__ KVg,
    const unsigned short* __restrict__ xpb,   const unsigned short* __restrict__ WTqt,
    unsigned short* __restrict__ Qt,
    const unsigned short* __restrict__ A_t8,  const unsigned short* __restrict__ WTtkv,
    unsigned short* __restrict__ T8) {
  __shared__ unsigned short As[2][128 * 32];
  __shared__ unsigned short Bs[2][128 * 32];
  constexpr int K = DD;
  const int tid = threadIdx.x;
  const int lane = tid & 63;
  const int wv = tid >> 6;
  const int wr = wv >> 1, wc = wv & 1;

  int lin = blockIdx.x;
  int swz = (lin & 7) * 132 + (lin >> 3);
  const unsigned short *A, *BT;
  unsigned short* C;
  int N, ntx, tile;
  if (swz < 768)       { A = xb;    BT = WTx4;  C = QKV4; N = 3072; ntx = 24; tile = swz; }
  else if (swz < 852)  { A = A_sel; BT = WTkv;  C = KVg;  N = 1536; ntx = 12; tile = swz - 768; }
  else if (swz < 1044) { A = xpb;   BT = WTqt;  C = Qt;   N = 768;  ntx = 6;  tile = swz - 852; }
  else                 { A = A_t8;  BT = WTtkv; C = T8;   N = 1536; ntx = 12; tile = swz - 1044; }
  const long rowBase = (long)(tile / ntx) * 128;
  const long colBase = (long)(tile % ntx) * 128;

  f32x4 acc[4][4];
#pragma unroll
  for (int i = 0; i < 4; ++i)
#pragma unroll
    for (int j = 0; j < 4; ++j)
#pragma unroll
      for (int r = 0; r < 4; ++r) acc[i][j][r] = 0.f;

  const int g0 = tid, g1 = tid + 256;
  const int r0 = g0 >> 2, k80 = (g0 & 3) ^ ((r0 >> 1) & 3);
  const int r1 = g1 >> 2, k81 = (g1 & 3) ^ ((r1 >> 1) & 3);
  const unsigned short* ga0 = A + (rowBase + r0) * (long)K + k80 * 8;
  const unsigned short* ga1 = A + (rowBase + r1) * (long)K + k81 * 8;
  const unsigned short* gb0 = BT + (colBase + r0) * (long)K + k80 * 8;
  const unsigned short* gb1 = BT + (colBase + r1) * (long)K + k81 * 8;

  const int k8 = lane >> 4;
  const int fr = lane & 15;
  int aoff[4], boff[4];
#pragma unroll
  for (int i = 0; i < 4; ++i) {
    int rowA = wr * 64 + i * 16 + fr;
    aoff[i] = (rowA * 4 + (k8 ^ ((rowA >> 1) & 3))) * 8;
    int rowB = wc * 64 + i * 16 + fr;
    boff[i] = (rowB * 4 + (k8 ^ ((rowB >> 1) & 3))) * 8;
  }

  auto stage = [&](int buf, int t) {
    int ko = t * 32;
    gload_lds16(ga0 + ko, &As[buf][g0 * 8]);
    gload_lds16(ga1 + ko, &As[buf][g1 * 8]);
    gload_lds16(gb0 + ko, &Bs[buf][g0 * 8]);
    gload_lds16(gb1 + ko, &Bs[buf][g1 * 8]);
  };

  constexpr int nk = K >> 5;   // 24
  stage(0, 0);
  __syncthreads();
  for (int t = 0; t < nk; ++t) {
    int cur = t & 1;
    if (t + 1 < nk) stage(cur ^ 1, t + 1);
    bf16x8 af[4], bfr[4];
#pragma unroll
    for (int i = 0; i < 4; ++i) af[i] = *(const bf16x8*)(&As[cur][aoff[i]]);
#pragma unroll
    for (int i = 0; i < 4; ++i) bfr[i] = *(const bf16x8*)(&Bs[cur][boff[i]]);
#pragma unroll
    for (int mi = 0; mi < 4; ++mi)
#pragma unroll
      for (int ni = 0; ni < 4; ++ni)
        acc[mi][ni] = __builtin_amdgcn_mfma_f32_16x16x32_bf16(af[mi], bfr[ni], acc[mi][ni], 0, 0, 0);
    __syncthreads();
  }

  const int orow0 = (lane >> 4) * 4;
#pragma unroll
  for (int mi = 0; mi < 4; ++mi) {
    long gr = rowBase + wr * 64 + mi * 16 + orow0;
#pragma unroll
    for (int ni = 0; ni < 4; ++ni) {
      long gc = colBase + wc * 64 + ni * 16 + fr;
#pragma unroll
      for (int r = 0; r < 4; ++r)
        C[(gr + r) * (long)N + gc] = f2b(acc[mi][ni][r]);
    }
  }
}

// ---------------- final GEMM, split-K=3 into f32 partials -------------------
// C = comb(4096x2304) @ WTo^T(768x2304); chunk z covers K in [z*768,(z+1)*768)
__global__ __launch_bounds__(256) void gemm_final_sk(const unsigned short* __restrict__ A,
                                                     const unsigned short* __restrict__ BT,
                                                     float* __restrict__ Cpart) {
  __shared__ unsigned short As[2][128 * 32];
  __shared__ unsigned short Bs[2][128 * 32];
  constexpr int N = 768, K = 2304, CK = 768;
  const int tid = threadIdx.x;
  const int lane = tid & 63;
  const int wv = tid >> 6;
  const int wr = wv >> 1, wc = wv & 1;
  const int z = blockIdx.z;

  int lin = blockIdx.y * gridDim.x + blockIdx.x;   // 192 blocks/plane
  int swz = (lin & 7) * 24 + (lin >> 3);
  const long rowBase = (long)(swz / 6) * 128;
  const long colBase = (long)(swz % 6) * 128;

  f32x4 acc[4][4];
#pragma unroll
  for (int i = 0; i < 4; ++i)
#pragma unroll
    for (int j = 0; j < 4; ++j)
#pragma unroll
      for (int r = 0; r < 4; ++r) acc[i][j][r] = 0.f;

  const int g0 = tid, g1 = tid + 256;
  const int r0 = g0 >> 2, k80 = (g0 & 3) ^ ((r0 >> 1) & 3);
  const int r1 = g1 >> 2, k81 = (g1 & 3) ^ ((r1 >> 1) & 3);
  const unsigned short* ga0 = A + (rowBase + r0) * (long)K + z * CK + k80 * 8;
  const unsigned short* ga1 = A + (rowBase + r1) * (long)K + z * CK + k81 * 8;
  const unsigned short* gb0 = BT + (colBase + r0) * (long)K + z * CK + k80 * 8;
  const unsigned short* gb1 = BT + (colBase + r1) * (long)K + z * CK + k81 * 8;

  const int k8 = lane >> 4;
  const int fr = lane & 15;
  int aoff[4], boff[4];
#pragma unroll
  for (int i = 0; i < 4; ++i) {
    int rowA = wr * 64 + i * 16 + fr;
    aoff[i] = (rowA * 4 + (k8 ^ ((rowA >> 1) & 3))) * 8;
    int rowB = wc * 64 + i * 16 + fr;
    boff[i] = (rowB * 4 + (k8 ^ ((rowB >> 1) & 3))) * 8;
  }

  auto stage = [&](int buf, int t) {
    int ko = t * 32;
    gload_lds16(ga0 + ko, &As[buf][g0 * 8]);
    gload_lds16(ga1 + ko, &As[buf][g1 * 8]);
    gload_lds16(gb0 + ko, &Bs[buf][g0 * 8]);
    gload_lds16(gb1 + ko, &Bs[buf][g1 * 8]);
  };

  constexpr int nk = CK >> 5;   // 24
  stage(0, 0);
  __syncthreads();
  for (int t = 0; t < nk; ++t) {
    int cur = t & 1;
    if (t + 1 < nk) stage(cur ^ 1, t + 1);
    bf16x8 af[4], bfr[4];
#pragma unroll
    for (int i = 0; i < 4; ++i) af[i] = *(const bf16x8*)(&As[cur][aoff[i]]);
#pragma unroll
    for (int i = 0; i < 4; ++i) bfr[i] = *(const bf16x8*)(&Bs[cur][boff[i]]);
#pragma unroll
    for (int mi = 0; mi < 4; ++mi)
#pragma unroll
      for (int ni = 0; ni < 4; ++ni)
        acc[mi][ni] = __builtin_amdgcn_mfma_f32_16x16x32_bf16(af[mi], bfr[ni], acc[mi][ni], 0, 0, 0);
    __syncthreads();
  }

  float* Cz = Cpart + (long)z * NTOK * DD;
  const int orow0 = (lane >> 4) * 4;
#pragma unroll
  for (int mi = 0; mi < 4; ++mi) {
    long gr = rowBase + wr * 64 + mi * 16 + orow0;
#pragma unroll
    for (int ni = 0; ni < 4; ++ni) {
      long gc = colBase + wc * 64 + ni * 16 + fr;
#pragma unroll
      for (int r = 0; r < 4; ++r)
        Cz[(gr + r) * (long)N + gc] = acc[mi][ni][r];
    }
  }
}

// ---------------- reduce split-K partials + bias -> d_out -------------------
__global__ __launch_bounds__(256) void reduce_out(const float* __restrict__ P,
                                                  const float* __restrict__ bias,
                                                  float* __restrict__ out) {
  long i = (long)blockIdx.x * 256 + threadIdx.x;   // over NTOK*DD/4 f32x4
  const f32x4* p0 = (const f32x4*)P;
  const f32x4* p1 = (const f32x4*)(P + (long)NTOK * DD);
  const f32x4* p2 = (const f32x4*)(P + 2L * NTOK * DD);
  f32x4 v = p0[i];
  v += p1[i];
  v += p2[i];
  int c4 = (int)(i % (DD / 4));
  v += *(const f32x4*)(bias + c4 * 4);
  ((f32x4*)out)[i] = v;
}

// ---------------- reformat T8 [128][1536] -> K8 [b][16][768], Vt8 [b][768][32]
__global__ __launch_bounds__(256) void reformat_t8(const unsigned short* __restrict__ T8,
                                                   unsigned short* __restrict__ K8,
                                                   unsigned short* __restrict__ Vt8) {
  int b = blockIdx.y;
  int c = blockIdx.x * 256 + threadIdx.x;   // grid.x = 3 -> c in [0,768)
#pragma unroll
  for (int j = 0; j < 8; ++j) {
    const unsigned short* src = T8 + (long)(b * 8 + j) * 1536;
    K8[((long)b * 16 + j) * DD + c]  = src[c];
    Vt8[((long)b * DD + c) * 32 + j] = src[768 + c];
  }
#pragma unroll
  for (int j = 8; j < 16; ++j) K8[((long)b * 16 + j) * DD + c] = 0;
#pragma unroll
  for (int j = 8; j < 32; ++j) Vt8[((long)b * DD + c) * 32 + j] = 0;
}

// -------- gather V transposed from compact KVg: Vt[b][c][j] -----------------
__global__ __launch_bounds__(256) void gather_vt(const unsigned short* __restrict__ KVg,
                                                 unsigned short* __restrict__ Vt) {
  __shared__ unsigned short tile[16][68];
  int jt = blockIdx.x, ct = blockIdx.y, b = blockIdx.z;   // 28, 12, 2
  int tid = threadIdx.x;
  int jj = tid & 15, cl = tid >> 4;                        // cl 0..15, 4 c each
  int j = jt * 16 + jj;
  const unsigned short* src = KVg + ((long)b * KPAD + j) * 1536 + 768 + ct * 64;
  *(uint2*)&tile[jj][cl * 4] = *(const uint2*)&src[cl * 4];
  __syncthreads();
  int c = tid >> 2;             // 0..63
  int jl = (tid & 3) * 4;       // 0,4,8,12
  unsigned v0 = tile[jl + 0][c], v1 = tile[jl + 1][c];
  unsigned v2 = tile[jl + 2][c], v3 = tile[jl + 3][c];
  unsigned short* dst = Vt + ((long)b * DD + ct * 64 + c) * KPAD + jt * 16 + jl;
  *(uint2*)dst = uint2{v0 | (v1 << 16), v2 | (v3 << 16)};
}

// ---------------- full V transpose for local branch: Vtl[b][c][s] -----------
__global__ __launch_bounds__(256) void transpose_vl(const unsigned short* __restrict__ QKV4,
                                                    unsigned short* __restrict__ Vtl) {
  __shared__ unsigned short tile[16][68];
  int jt = blockIdx.x, ct = blockIdx.y, b = blockIdx.z;   // 128, 12, 2
  int tid = threadIdx.x;
  int jj = tid & 15, cl = tid >> 4;
  const unsigned short* src = QKV4 + ((long)b * SS + jt * 16 + jj) * 3072 + 2304 + ct * 64;
  *(uint2*)&tile[jj][cl * 4] = *(const uint2*)&src[cl * 4];
  __syncthreads();
  int c = tid >> 2;
  int jl = (tid & 3) * 4;
  unsigned v0 = tile[jl + 0][c], v1 = tile[jl + 1][c];
  unsigned v2 = tile[jl + 2][c], v3 = tile[jl + 3][c];
  unsigned short* dst = Vtl + ((long)b * DD + ct * 64 + c) * (long)SS + jt * 16 + jl;
  *(uint2*)dst = uint2{v0 | (v1 << 16), v2 | (v3 << 16)};
}

// ---------------- global-branch flash MFMA attention ------------------------
__global__ __launch_bounds__(256) void attn_global_flash(
    const unsigned short* __restrict__ QKV4,  // [4096][3072]
    const unsigned short* __restrict__ KVg,   // [b*448][1536]
    const unsigned short* __restrict__ Vt,    // [b][768][448]
    float* __restrict__ Outp) {               // [b*2048+q][768]
  __shared__ unsigned short Kl[2][64 * 64];
  __shared__ unsigned short Vl[2][64 * 64];
  __shared__ unsigned short Pl[4][16 * 68];
  int tid = threadIdx.x, w = tid >> 6, lane = tid & 63;
  int fr = lane & 15, g = lane >> 4;
  int b = blockIdx.y / HH, h = blockIdx.y % HH, hoff = h * 64;
  int qbase = blockIdx.x * 64 + w * 16;
  long qrow = (long)b * SS + qbase + fr;

  const unsigned short* qptr = QKV4 + qrow * 3072 + hoff + g * 8;
  bf16x8 bq0 = *(const bf16x8*)(qptr);
  bf16x8 bq1 = *(const bf16x8*)(qptr + 32);

  const int s0 = tid, s1 = tid + 256;
  const int r0 = s0 >> 3, c0 = (s0 & 7) ^ (r0 & 7);
  const int r1 = s1 >> 3, c1 = (s1 & 7) ^ (r1 & 7);
  const unsigned short* kg_b = KVg + (long)b * KPAD * 1536 + hoff;
  const unsigned short* vt_b = Vt + ((long)b * DD + hoff) * KPAD;

  auto stage = [&](int buf, int t0) {
    gload_lds16(kg_b + (long)(t0 * 64 + r0) * 1536 + c0 * 8, &Kl[buf][s0 * 8]);
    gload_lds16(kg_b + (long)(t0 * 64 + r1) * 1536 + c1 * 8, &Kl[buf][s1 * 8]);
    gload_lds16(vt_b + (long)r0 * KPAD + t0 * 64 + c0 * 8, &Vl[buf][s0 * 8]);
    gload_lds16(vt_b + (long)r1 * KPAD + t0 * 64 + c1 * 8, &Vl[buf][s1 * 8]);
  };

  f32x4 oacc[4];
#pragma unroll
  for (int mf = 0; mf < 4; ++mf)
#pragma unroll
    for (int r = 0; r < 4; ++r) oacc[mf][r] = 0.f;
  float m = -3.0e38f, l = 0.f;

  stage(0, 0);
  asm volatile("s_waitcnt vmcnt(0)" ::: "memory");
  __syncthreads();

  for (int t = 0; t < NKT; ++t) {
    int cur = t & 1;
    if (t + 1 < NKT) stage(cur ^ 1, t + 1);

    f32x4 st[4];
#pragma unroll
    for (int kt = 0; kt < 4; ++kt) {
      int row = kt * 16 + fr;
      bf16x8 a0 = *(const bf16x8*)(&Kl[cur][(row * 8 + (g ^ (row & 7))) * 8]);
      bf16x8 a1 = *(const bf16x8*)(&Kl[cur][(row * 8 + ((4 + g) ^ (row & 7))) * 8]);
      f32x4 z = {0.f, 0.f, 0.f, 0.f};
      z = __builtin_amdgcn_mfma_f32_16x16x32_bf16(a0, bq0, z, 0, 0, 0);
      st[kt] = __builtin_amdgcn_mfma_f32_16x16x32_bf16(a1, bq1, z, 0, 0, 0);
    }

    float tm = -3.0e38f;
#pragma unroll
    for (int kt = 0; kt < 4; ++kt)
#pragma unroll
      for (int r = 0; r < 4; ++r) {
        int key = t * 64 + kt * 16 + g * 4 + r;
        float s = (key < KSEL) ? st[kt][r] * 0.125f : -1.0e30f;
        st[kt][r] = s;
        tm = fmaxf(tm, s);
      }
    tm = fmaxf(tm, __shfl_xor(tm, 16, 64));
    tm = fmaxf(tm, __shfl_xor(tm, 32, 64));
    float newm = fmaxf(m, tm);
    float f = __expf(m - newm);
    float tsum = 0.f;
#pragma unroll
    for (int kt = 0; kt < 4; ++kt)
#pragma unroll
      for (int r = 0; r < 4; ++r) {
        float e = __expf(st[kt][r] - newm);
        st[kt][r] = e;
        tsum += e;
      }
    tsum += __shfl_xor(tsum, 16, 64);
    tsum += __shfl_xor(tsum, 32, 64);
    l = l * f + tsum;
    m = newm;
#pragma unroll
    for (int mf = 0; mf < 4; ++mf)
#pragma unroll
      for (int r = 0; r < 4; ++r) oacc[mf][r] *= f;

    unsigned short* pw = &Pl[w][fr * 68 + g * 4];
#pragma unroll
    for (int kt = 0; kt < 4; ++kt) {
      uint2 pk;
      pk.x = (unsigned)f2b(st[kt][0]) | ((unsigned)f2b(st[kt][1]) << 16);
      pk.y = (unsigned)f2b(st[kt][2]) | ((unsigned)f2b(st[kt][3]) << 16);
      *(uint2*)(pw + kt * 16) = pk;
    }

    const unsigned short* prd = &Pl[w][fr * 68];
#pragma unroll
    for (int ks2 = 0; ks2 < 2; ++ks2) {
      bf16x8 pf = *(const bf16x8*)(prd + ks2 * 32 + g * 8);
#pragma unroll
      for (int mf = 0; mf < 4; ++mf) {
        int vr = mf * 16 + fr;
        int vc = ks2 * 4 + g;
        bf16x8 vf = *(const bf16x8*)(&Vl[cur][(vr * 8 + (vc ^ (vr & 7))) * 8]);
        oacc[mf] = __builtin_amdgcn_mfma_f32_16x16x32_bf16(vf, pf, oacc[mf], 0, 0, 0);
      }
    }

    asm volatile("s_waitcnt vmcnt(0)" ::: "memory");
    __syncthreads();
  }

  float inv = 1.f / l;
  float* orow = Outp + qrow * DD + hoff;
#pragma unroll
  for (int mf = 0; mf < 4; ++mf) {
    f32x4 ov;
#pragma unroll
    for (int r = 0; r < 4; ++r) ov[r] = oacc[mf][r] * inv;
    *(f32x4*)(orow + mf * 16 + g * 4) = ov;
  }
}

// ---------------- window MFMA attention (local / temporal) ------------------
template <int MODE>
__global__ __launch_bounds__(256) void attn_win_mfma(
    const unsigned short* __restrict__ QKV,
    const unsigned short* __restrict__ K8,    // MODE1 only: [b][16][768]
    const unsigned short* __restrict__ Vt,    // MODE0: [b][768][2048]; MODE1: [b][768][32]
    float* __restrict__ Outp) {
  constexpr int LD   = (MODE == 0) ? 3072 : 768;
  constexpr int QO   = (MODE == 0) ? 768 : 0;
  constexpr int KO   = 1536;
  constexpr long VSTR = (MODE == 0) ? SS : 32;
  __shared__ unsigned short P_lds[4][16 * 40];
  int tid = threadIdx.x, w = tid >> 6, lane = tid & 63;
  int fr = lane & 15, g = lane >> 4;
  int b = blockIdx.y / HH, h = blockIdx.y % HH, hoff = h * 64;
  int qbase = blockIdx.x * 64 + w * 16;
  long qrow = (long)b * SS + qbase + fr;

  const unsigned short* qptr = QKV + qrow * LD + QO + hoff + g * 8;
  bf16x8 bq0 = *(const bf16x8*)(qptr);
  bf16x8 bq1 = *(const bf16x8*)(qptr + 32);

  int kstart = qbase - 8;
  if (kstart < 0) kstart = 0;
  if (kstart > SS - 32) kstart = SS - 32;

  f32x4 st[2];
  if (MODE == 0) {
#pragma unroll
    for (int kt = 0; kt < 2; ++kt) {
      const unsigned short* kp =
          QKV + ((long)b * SS + kstart + kt * 16 + fr) * LD + KO + hoff + g * 8;
      bf16x8 a0 = *(const bf16x8*)(kp);
      bf16x8 a1 = *(const bf16x8*)(kp + 32);
      f32x4 z = {0.f, 0.f, 0.f, 0.f};
      z = __builtin_amdgcn_mfma_f32_16x16x32_bf16(a0, bq0, z, 0, 0, 0);
      st[kt] = __builtin_amdgcn_mfma_f32_16x16x32_bf16(a1, bq1, z, 0, 0, 0);
    }
  } else {
    const unsigned short* kp = K8 + ((long)b * 16 + fr) * DD + hoff + g * 8;
    bf16x8 a0 = *(const bf16x8*)(kp);
    bf16x8 a1 = *(const bf16x8*)(kp + 32);
    f32x4 z = {0.f, 0.f, 0.f, 0.f};
    z = __builtin_amdgcn_mfma_f32_16x16x32_bf16(a0, bq0, z, 0, 0, 0);
    st[0] = __builtin_amdgcn_mfma_f32_16x16x32_bf16(a1, bq1, z, 0, 0, 0);
    st[1] = f32x4{0.f, 0.f, 0.f, 0.f};
  }

  float m = -3.0e38f;
#pragma unroll
  for (int kt = 0; kt < 2; ++kt)
#pragma unroll
    for (int r = 0; r < 4; ++r) {
      int idx = kt * 16 + g * 4 + r;
      bool valid;
      if (MODE == 0) {
        int rel = kstart + idx - qbase - fr;
        valid = (rel >= -8) && (rel <= 8);
      } else {
        valid = (idx < 8);
      }
      float s = valid ? st[kt][r] * 0.125f : -1.0e30f;
      st[kt][r] = s;
      m = fmaxf(m, s);
    }
  m = fmaxf(m, __shfl_xor(m, 16, 64));
  m = fmaxf(m, __shfl_xor(m, 32, 64));

  float lsum = 0.f;
#pragma unroll
  for (int kt = 0; kt < 2; ++kt)
#pragma unroll
    for (int r = 0; r < 4; ++r) {
      float e = __expf(st[kt][r] - m);
      st[kt][r] = e;
      lsum += e;
    }
  lsum += __shfl_xor(lsum, 16, 64);
  lsum += __shfl_xor(lsum, 32, 64);

  unsigned short* pl = &P_lds[w][fr * 40 + g * 4];
#pragma unroll
  for (int kt = 0; kt < 2; ++kt) {
    uint2 pk;
    pk.x = (unsigned)f2b(st[kt][0]) | ((unsigned)f2b(st[kt][1]) << 16);
    pk.y = (unsigned)f2b(st[kt][2]) | ((unsigned)f2b(st[kt][3]) << 16);
    *(uint2*)(pl + kt * 16) = pk;
  }

  f32x4 oacc[4];
#pragma unroll
  for (int mf = 0; mf < 4; ++mf)
#pragma unroll
    for (int r = 0; r < 4; ++r) oacc[mf][r] = 0.f;

  const unsigned short* pr = &P_lds[w][fr * 40 + g * 8];
  bf16x8 pf = *(const bf16x8*)(pr);
  long kb2 = (MODE == 0) ? kstart : 0;
#pragma unroll
  for (int mf = 0; mf < 4; ++mf) {
    const unsigned short* vp =
        Vt + ((long)b * DD + hoff + mf * 16 + fr) * VSTR + kb2 + g * 8;
    bf16x8 vf = *(const bf16x8*)(vp);
    oacc[mf] = __builtin_amdgcn_mfma_f32_16x16x32_bf16(vf, pf, oacc[mf], 0, 0, 0);
  }

  float inv = 1.f / lsum;
  float* orow = Outp + qrow * DD + hoff;
#pragma unroll
  for (int mf = 0; mf < 4; ++mf) {
    f32x4 ov;
#pragma unroll
    for (int r = 0; r < 4; ++r) ov[r] = oacc[mf][r] * inv;
    *(f32x4*)(orow + mf * 16 + g * 4) = ov;
  }
}

// ---------------- layernorm + gate scale + concat to bf16 -------------------
__global__ __launch_bounds__(256) void ln_gate_concat(
    const float* __restrict__ gsrc, const float* __restrict__ lsrc, const float* __restrict__ tsrc,
    const float* __restrict__ gg, const float* __restrict__ gb,
    const float* __restrict__ lgam, const float* __restrict__ lbet,
    const float* __restrict__ tg, const float* __restrict__ tb,
    const float* __restrict__ fw, unsigned short* __restrict__ comb) {
  int row = blockIdx.x;
  int b = row >> 11;
  int tid = threadIdx.x;
  __shared__ float red[8];
  const float* srcs[3] = {gsrc, lsrc, tsrc};
  const float* gams[3] = {gg, lgam, tg};
  const float* bets[3] = {gb, lbet, tb};
#pragma unroll
  for (int br = 0; br < 3; ++br) {
    const float* src = srcs[br] + (long)row * DD;
    float x0 = src[tid], x1 = src[tid + 256], x2 = src[tid + 512];
    float s = x0 + x1 + x2;
    float ss = x0 * x0 + x1 * x1 + x2 * x2;
#pragma unroll
    for (int msk = 1; msk < 64; msk <<= 1) {
      s += __shfl_xor(s, msk, 64);
      ss += __shfl_xor(ss, msk, 64);
    }
    int wv = tid >> 6, lane = tid & 63;
    if (lane == 0) { red[wv] = s; red[4 + wv] = ss; }
    __syncthreads();
    float S4 = red[0] + red[1] + red[2] + red[3];
    float SQ = red[4] + red[5] + red[6] + red[7];
    float mean = S4 * (1.f / (float)DD);
    float var = SQ * (1.f / (float)DD) - mean * mean;
    float rs = rsqrtf(var + 1e-5f);
    float gate = fw[b * 3 + br];
    const float* gam = gams[br];
    const float* bet = bets[br];
    unsigned short* dst = comb + (long)row * 2304 + br * DD;
    dst[tid]       = f2b(((x0 - mean) * rs * gam[tid]       + bet[tid])       * gate);
    dst[tid + 256] = f2b(((x1 - mean) * rs * gam[tid + 256] + bet[tid + 256]) * gate);
    dst[tid + 512] = f2b(((x2 - mean) * rs * gam[tid + 512] + bet[tid + 512]) * gate);
    __syncthreads();
  }
}

// ---------------- launcher ---------------------------------------------------
extern "C" void kernel_launch(void* const* d_in, const int* in_sizes, int n_in,
                              void* d_out, int out_size, void* d_ws, size_t ws_size,
                              hipStream_t stream) {
  const float* x        = (const float*)d_in[0];
  const float* wgq      = (const float*)d_in[1];
  const float* wgk      = (const float*)d_in[2];
  const float* wgv      = (const float*)d_in[3];
  const float* wlq      = (const float*)d_in[4];
  const float* wlk      = (const float*)d_in[5];
  const float* wlv      = (const float*)d_in[6];
  const float* wtq      = (const float*)d_in[7];
  const float* wtk      = (const float*)d_in[8];
  const float* wtv      = (const float*)d_in[9];
  const float* w_out    = (const float*)d_in[10];
  const float* b_out    = (const float*)d_in[11];
  const float* w_gate   = (const float*)d_in[12];
  const float* b_gate   = (const float*)d_in[13];
  const float* w_sparse = (const float*)d_in[14];
  const float* b_sparse = (const float*)d_in[15];
  const float* g_gamma  = (const float*)d_in[16];
  const float* g_beta   = (const float*)d_in[17];
  const float* l_gamma  = (const float*)d_in[18];
  const float* l_beta   = (const float*)d_in[19];
  const float* t_gamma  = (const float*)d_in[20];
  const float* t_beta   = (const float*)d_in[21];
  float* outp = (float*)d_out;

  unsigned short* xb    = (unsigned short*)d_ws;
  unsigned short* xpb   = xb    + (long)NTOK * DD;
  unsigned short* WTx4  = xpb   + (long)NTOK * DD;        // [3072][768]
  unsigned short* WTkv  = WTx4  + (long)3072 * DD;        // [1536][768]
  unsigned short* WTqt  = WTkv  + (long)1536 * DD;        // [768][768]
  unsigned short* WTtkv = WTqt  + (long)DD * DD;          // [1536][768]
  unsigned short* WTo   = WTtkv + (long)1536 * DD;        // [768][2304]
  unsigned short* QKV4  = WTo   + (long)DD * 2304;        // [4096][3072]
  unsigned short* Qt    = QKV4  + (long)NTOK * 3072;      // [4096][768]
  unsigned short* A_sel = Qt    + (long)NTOK * DD;        // [896][768]
  unsigned short* KVg   = A_sel + (long)BB * KPAD * DD;   // [896][1536]
  unsigned short* A_t8  = KVg   + (long)BB * KPAD * 1536; // [128][768]
  unsigned short* T8    = A_t8  + (long)128 * DD;         // [128][1536]
  unsigned short* K8    = T8    + (long)128 * 1536;       // [2][16][768]
  unsigned short* Vt8   = K8    + (long)BB * 16 * DD;     // [2][768][32]
  unsigned short* Vt    = Vt8   + (long)BB * DD * 32;     // [2][768][448]
  unsigned short* comb  = Vt    + (long)BB * DD * KPAD;   // [4096][2304]
  float* gout    = (float*)(comb + (long)NTOK * 2304);
  float* lout    = gout + (long)NTOK * DD;
  float* tout    = lout + (long)NTOK * DD;
  float* imp     = tout + (long)NTOK * DD;
  float* partial = imp + NTOK;
  float* fw      = partial + 32 * DD;
  int*   sel     = (int*)(fw + 8);
  // reuse: Vtl overlays xpb (dead after gemm_multi); Cpart overlays
  // gout/lout/tout (dead after ln_gate_concat; exactly 3 slabs of NTOK*DD f32)
  unsigned short* Vtl   = xpb;                            // [2][768][2048]
  float*          Cpart = gout;                           // [3][4096][768]

  prep_imp<<<NTOK, 256, 0, stream>>>(x, w_sparse, b_sparse, xb, xpb, imp);
  transpose_all<<<dim3(24, 72, 10), dim3(32, 8), 0, stream>>>(
      wgq, wgk, wgv, wlq, wlk, wlv, wtq, wtk, wtv, w_out,
      WTx4, WTkv, WTqt, WTtkv, WTo);
  topk_kernel<<<BB, 1024, 0, stream>>>(imp, sel);
  gate1<<<dim3(16, BB), 256, 0, stream>>>(x, partial);
  gate2<<<BB, 256, 0, stream>>>(partial, w_gate, b_gate, fw);

  gather_pre<<<BB * KPAD + 128, 192, 0, stream>>>(xb, xpb, sel, A_sel, A_t8);
  gemm_multi<<<1056, 256, 0, stream>>>(xb, WTx4, QKV4, A_sel, WTkv, KVg,
                                       xpb, WTqt, Qt, A_t8, WTtkv, T8);
  reformat_t8<<<dim3(3, BB), 256, 0, stream>>>(T8, K8, Vt8);
  gather_vt<<<dim3(28, 12, BB), 256, 0, stream>>>(KVg, Vt);
  transpose_vl<<<dim3(128, 12, BB), 256, 0, stream>>>(QKV4, Vtl);

  attn_global_flash<<<dim3(32, BB * HH), 256, 0, stream>>>(QKV4, KVg, Vt, gout);
  attn_win_mfma<0><<<dim3(32, BB * HH), 256, 0, stream>>>(QKV4, nullptr, Vtl, lout);
  attn_win_mfma<1><<<dim3(32, BB * HH), 256, 0, stream>>>(Qt, K8, Vt8, tout);

  ln_gate_concat<<<NTOK, 256, 0, stream>>>(gout, lout, tout, g_gamma, g_beta,
                                           l_gamma, l_beta, t_gamma, t_beta, fw, comb);
  gemm_final_sk<<<dim3(6, 32, 3), 256, 0, stream>>>(comb, WTo, Cpart);
  reduce_out<<<NTOK * DD / 4 / 256, 256, 0, stream>>>(Cpart, b_out, outp);
}

// Round 10
// 209.567 us; speedup vs baseline: 1.3407x; 1.1161x over previous
//
#include <hip/hip_runtime.h>
#include <cstdint>

// Problem constants
constexpr int BB   = 2;
constexpr int SS   = 2048;
constexpr int DD   = 768;
constexpr int HH   = 12;
constexpr int NTOK = BB * SS;          // 4096
constexpr int KSEL = 409;              // int((1-0.8)*2048)
constexpr int KPAD = 448;              // 7 kv-tiles of 64
constexpr int NKT  = 7;                // kv tiles of 64 keys

typedef __bf16 bf16x8 __attribute__((ext_vector_type(8)));
typedef float  f32x4  __attribute__((ext_vector_type(4)));

__device__ __forceinline__ float b2f(unsigned short u) {
  return __uint_as_float(((unsigned)u) << 16);
}
__device__ __forceinline__ unsigned short f2b(float f) {
  unsigned u = __float_as_uint(f);
  u += 0x7fffu + ((u >> 16) & 1u);   // RNE
  return (unsigned short)(u >> 16);
}
__device__ __forceinline__ unsigned long long shfl_xor_u64(unsigned long long v, int m) {
  unsigned lo = (unsigned)v, hi = (unsigned)(v >> 32);
  lo = __shfl_xor(lo, m, 64);
  hi = __shfl_xor(hi, m, 64);
  return ((unsigned long long)hi << 32) | lo;
}

__device__ __forceinline__ void gload_lds16(const void* gsrc, void* ldst) {
  __builtin_amdgcn_global_load_lds(
      (__attribute__((address_space(1))) void*)(gsrc),
      (__attribute__((address_space(3))) void*)(ldst), 16, 0, 0);
}

// -------- fused prep: xb, xpb (=x+PE), importance; one block per srow -------
// PE depends only on (srow, c): compute trig once, apply to both batches.
__global__ __launch_bounds__(256) void prep_imp(const float* __restrict__ x,
                                                const float* __restrict__ wsp,
                                                const float* __restrict__ bsp,
                                                unsigned short* __restrict__ xb,
                                                unsigned short* __restrict__ xpb,
                                                float* __restrict__ imp) {
  int srow = blockIdx.x;                // 0..2047
  int tid = threadIdx.x;
  const float* xr0 = x + (long)srow * DD;
  const float* xr1 = x + (long)(SS + srow) * DD;
  float acc0 = 0.f, acc1 = 0.f;
#pragma unroll
  for (int k = 0; k < 3; ++k) {
    int c = tid + k * 256;
    int j2 = c & ~1;
    float freq = __expf((float)j2 * -0.011992630692677323f);  // exp(-j2*ln(1e4)/768)
    float ang = (float)srow * freq;
    float pe = (c & 1) ? cosf(ang) : sinf(ang);
    float w = wsp[c];
    float x0 = xr0[c], x1 = xr1[c];
    xb[(long)srow * DD + c]        = f2b(x0);
    xb[(long)(SS + srow) * DD + c] = f2b(x1);
    xpb[(long)srow * DD + c]        = f2b(x0 + pe);
    xpb[(long)(SS + srow) * DD + c] = f2b(x1 + pe);
    acc0 += x0 * w;
    acc1 += x1 * w;
  }
#pragma unroll
  for (int m = 1; m < 64; m <<= 1) {
    acc0 += __shfl_xor(acc0, m, 64);
    acc1 += __shfl_xor(acc1, m, 64);
  }
  __shared__ float red[8];
  int wv = tid >> 6, lane = tid & 63;
  if (lane == 0) { red[wv] = acc0; red[4 + wv] = acc1; }
  __syncthreads();
  if (tid == 0) {
    imp[srow]      = red[0] + red[1] + red[2] + red[3] + bsp[0];
    imp[SS + srow] = red[4] + red[5] + red[6] + red[7] + bsp[0];
  }
}

// ---------------- transpose all weights to bf16 B^T (N x K) -----------------
__global__ void transpose_all(const float* w0, const float* w1, const float* w2,
                              const float* w3, const float* w4, const float* w5,
                              const float* w6, const float* w7, const float* w8,
                              const float* w9,
                              unsigned short* WTx4, unsigned short* WTkv,
                              unsigned short* WTqt, unsigned short* WTtkv,
                              unsigned short* WTo) {
  __shared__ float tile[32][33];
  int z = blockIdx.z;
  const float* srcs[10] = {w0, w1, w2, w3, w4, w5, w6, w7, w8, w9};
  const float* src = srcs[z];
  unsigned short* dst;
  int R = DD;
  switch (z) {
    case 0: dst = WTx4;                       break;  // wgq
    case 1: dst = WTkv;                       break;  // wgk
    case 2: dst = WTkv + (long)DD * DD;       break;  // wgv
    case 3: dst = WTx4 + (long)DD * DD;       break;  // wlq
    case 4: dst = WTx4 + (long)2 * DD * DD;   break;  // wlk
    case 5: dst = WTx4 + (long)3 * DD * DD;   break;  // wlv
    case 6: dst = WTqt;                       break;  // wtq
    case 7: dst = WTtkv;                      break;  // wtk
    case 8: dst = WTtkv + (long)DD * DD;      break;  // wtv
    default: dst = WTo; R = 2304;             break;  // w_out
  }
  int r0 = blockIdx.y * 32;
  if (r0 >= R) return;
  int c0 = blockIdx.x * 32;
  int tx = threadIdx.x, ty = threadIdx.y;
  for (int i = ty; i < 32; i += 8) tile[i][tx] = src[(long)(r0 + i) * DD + c0 + tx];
  __syncthreads();
  for (int i = ty; i < 32; i += 8) dst[(long)(c0 + i) * R + r0 + tx] = f2b(tile[tx][i]);
}

// ------- top-k via hybrid bitonic sort (value desc, index asc) --------------
// j>=64 stages in LDS with barriers; j<=32 stages in registers via shfl_xor
// (partner lane = lane^j stays in-wave; (i&k) direction bit identical for
// both partners since j < k).
__global__ __launch_bounds__(1024) void topk_kernel(const float* __restrict__ imp,
                                                    int* __restrict__ sel) {
  __shared__ unsigned long long keys[SS];
  int b = blockIdx.x, tid = threadIdx.x;
  for (int i = tid; i < SS; i += 1024) {
    float v = imp[b * SS + i];
    unsigned u = __float_as_uint(v);
    u = (u & 0x80000000u) ? ~u : (u | 0x80000000u);   // ascending-order map
    unsigned du = ~u;                                  // descending
    keys[i] = ((unsigned long long)du << 32) | (unsigned)i;
  }
  __syncthreads();
  for (int k = 2; k <= SS; k <<= 1) {
    for (int j = k >> 1; j >= 64; j >>= 1) {
      for (int i = tid; i < SS; i += 1024) {
        int p = i ^ j;
        if (p > i) {
          unsigned long long a = keys[i], bb = keys[p];
          bool up = ((i & k) == 0);
          if ((a > bb) == up) { keys[i] = bb; keys[p] = a; }
        }
      }
      __syncthreads();
    }
    // register phase: j = min(k/2,32) .. 1
    unsigned long long k0 = keys[tid], k1 = keys[tid + 1024];
    bool up0 = ((tid & k) == 0);
    bool up1 = (((tid + 1024) & k) == 0);
    int j0 = (k >> 1) < 32 ? (k >> 1) : 32;
    for (int j = j0; j >= 1; j >>= 1) {
      bool low = ((tid & j) == 0);   // same bit for tid and tid+1024 (j<=32)
      unsigned long long p0 = shfl_xor_u64(k0, j);
      k0 = ((low == up0) == (k0 < p0)) ? k0 : p0;
      unsigned long long p1 = shfl_xor_u64(k1, j);
      k1 = ((low == up1) == (k1 < p1)) ? k1 : p1;
    }
    keys[tid] = k0; keys[tid + 1024] = k1;
    __syncthreads();
  }
  for (int i = tid; i < KSEL; i += 1024) sel[b * KSEL + i] = (int)(keys[i] & 0xffffffffu);
}

// ---------------- gate: mean over s, then softmax(mean @ w_gate + b) --------
__global__ __launch_bounds__(256) void gate1(const float* __restrict__ x,
                                             float* __restrict__ partial) {
  int b = blockIdx.y, chunk = blockIdx.x, tid = threadIdx.x;
  for (int c = tid; c < DD; c += 256) {
    const float* xp = x + ((long)(b * SS + chunk * 128)) * DD + c;
    float acc = 0.f;
    for (int s2 = 0; s2 < 128; ++s2) acc += xp[(long)s2 * DD];
    partial[(long)(b * 16 + chunk) * DD + c] = acc;
  }
}

__global__ __launch_bounds__(256) void gate2(const float* __restrict__ partial,
                                             const float* __restrict__ w_gate,
                                             const float* __restrict__ b_gate,
                                             float* __restrict__ fw) {
  int b = blockIdx.x, tid = threadIdx.x;
  __shared__ float meanbuf[DD];
  __shared__ float lg[3];
  for (int c = tid; c < DD; c += 256) {
    float acc = 0.f;
    for (int p = 0; p < 16; ++p) acc += partial[(long)(b * 16 + p) * DD + c];
    meanbuf[c] = acc * (1.0f / (float)SS);
  }
  __syncthreads();
  if (tid < 3) {
    float acc = b_gate[tid];
    for (int d = 0; d < DD; ++d) acc += meanbuf[d] * w_gate[d * 3 + tid];
    lg[tid] = acc;
  }
  __syncthreads();
  if (tid == 0) {
    float mx = fmaxf(lg[0], fmaxf(lg[1], lg[2]));
    float e0 = expf(lg[0] - mx), e1 = expf(lg[1] - mx), e2 = expf(lg[2] - mx);
    float inv = 1.f / (e0 + e1 + e2);
    fw[b * 3 + 0] = e0 * inv; fw[b * 3 + 1] = e1 * inv; fw[b * 3 + 2] = e2 * inv;
  }
}

// -------- merged gather: A_sel rows (topk) + A_t8 temporal rows -------------
__global__ __launch_bounds__(192) void gather_pre(const unsigned short* __restrict__ xb,
                                                  const unsigned short* __restrict__ xpb,
                                                  const int* __restrict__ sel,
                                                  unsigned short* __restrict__ A_sel,
                                                  unsigned short* __restrict__ A_t8) {
  int id = blockIdx.x;
  int tid = threadIdx.x;
  if (id < BB * KPAD) {
    int b = id / KPAD, j = id % KPAD;
    uint2* dst = (uint2*)(A_sel + (long)id * DD);
    if (j < KSEL) {
      const uint2* src = (const uint2*)(xb + (long)(b * SS + sel[b * KSEL + j]) * DD);
      dst[tid] = src[tid];
    } else {
      dst[tid] = uint2{0u, 0u};
    }
  } else {
    int r = id - BB * KPAD;     // 0..127
    uint2* dst = (uint2*)(A_t8 + (long)r * DD);
    if (r < 16) {
      int b = r >> 3, j = (r & 7) * 256;
      const uint2* src = (const uint2*)(xpb + (long)(b * SS + j) * DD);
      dst[tid] = src[tid];
    } else {
      dst[tid] = uint2{0u, 0u};
    }
  }
}

// ---------------- fused projection GEMMs (all K=768, 128x128 tiles) ---------
__global__ __launch_bounds__(256) void gemm_multi(
    const unsigned short* __restrict__ xb,    const unsigned short* __restrict__ WTx4,
    unsigned short* __restrict__ QKV4,
    const unsigned short* __restrict__ A_sel, const unsigned short* __restrict__ WTkv,
    unsigned short* __restrict__ KVg,
    const unsigned short* __restrict__ xpb,   const unsigned short* __restrict__ WTqt,
    unsigned short* __restrict__ Qt,
    const unsigned short* __restrict__ A_t8,  const unsigned short* __restrict__ WTtkv,
    unsigned short* __restrict__ T8) {
  __shared__ unsigned short As[2][128 * 32];
  __shared__ unsigned short Bs[2][128 * 32];
  constexpr int K = DD;
  const int tid = threadIdx.x;
  const int lane = tid & 63;
  const int wv = tid >> 6;
  const int wr = wv >> 1, wc = wv & 1;

  int lin = blockIdx.x;
  int swz = (lin & 7) * 132 + (lin >> 3);
  const unsigned short *A, *BT;
  unsigned short* C;
  int N, ntx, tile;
  if (swz < 768)       { A = xb;    BT = WTx4;  C = QKV4; N = 3072; ntx = 24; tile = swz; }
  else if (swz < 852)  { A = A_sel; BT = WTkv;  C = KVg;  N = 1536; ntx = 12; tile = swz - 768; }
  else if (swz < 1044) { A = xpb;   BT = WTqt;  C = Qt;   N = 768;  ntx = 6;  tile = swz - 852; }
  else                 { A = A_t8;  BT = WTtkv; C = T8;   N = 1536; ntx = 12; tile = swz - 1044; }
  const long rowBase = (long)(tile / ntx) * 128;
  const long colBase = (long)(tile % ntx) * 128;

  f32x4 acc[4][4];
#pragma unroll
  for (int i = 0; i < 4; ++i)
#pragma unroll
    for (int j = 0; j < 4; ++j)
#pragma unroll
      for (int r = 0; r < 4; ++r) acc[i][j][r] = 0.f;

  const int g0 = tid, g1 = tid + 256;
  const int r0 = g0 >> 2, k80 = (g0 & 3) ^ ((r0 >> 1) & 3);
  const int r1 = g1 >> 2, k81 = (g1 & 3) ^ ((r1 >> 1) & 3);
  const unsigned short* ga0 = A + (rowBase + r0) * (long)K + k80 * 8;
  const unsigned short* ga1 = A + (rowBase + r1) * (long)K + k81 * 8;
  const unsigned short* gb0 = BT + (colBase + r0) * (long)K + k80 * 8;
  const unsigned short* gb1 = BT + (colBase + r1) * (long)K + k81 * 8;

  const int k8 = lane >> 4;
  const int fr = lane & 15;
  int aoff[4], boff[4];
#pragma unroll
  for (int i = 0; i < 4; ++i) {
    int rowA = wr * 64 + i * 16 + fr;
    aoff[i] = (rowA * 4 + (k8 ^ ((rowA >> 1) & 3))) * 8;
    int rowB = wc * 64 + i * 16 + fr;
    boff[i] = (rowB * 4 + (k8 ^ ((rowB >> 1) & 3))) * 8;
  }

  auto stage = [&](int buf, int t) {
    int ko = t * 32;
    gload_lds16(ga0 + ko, &As[buf][g0 * 8]);
    gload_lds16(ga1 + ko, &As[buf][g1 * 8]);
    gload_lds16(gb0 + ko, &Bs[buf][g0 * 8]);
    gload_lds16(gb1 + ko, &Bs[buf][g1 * 8]);
  };

  constexpr int nk = K >> 5;   // 24
  stage(0, 0);
  __syncthreads();
  for (int t = 0; t < nk; ++t) {
    int cur = t & 1;
    if (t + 1 < nk) stage(cur ^ 1, t + 1);
    bf16x8 af[4], bfr[4];
#pragma unroll
    for (int i = 0; i < 4; ++i) af[i] = *(const bf16x8*)(&As[cur][aoff[i]]);
#pragma unroll
    for (int i = 0; i < 4; ++i) bfr[i] = *(const bf16x8*)(&Bs[cur][boff[i]]);
#pragma unroll
    for (int mi = 0; mi < 4; ++mi)
#pragma unroll
      for (int ni = 0; ni < 4; ++ni)
        acc[mi][ni] = __builtin_amdgcn_mfma_f32_16x16x32_bf16(af[mi], bfr[ni], acc[mi][ni], 0, 0, 0);
    __syncthreads();
  }

  const int orow0 = (lane >> 4) * 4;
#pragma unroll
  for (int mi = 0; mi < 4; ++mi) {
    long gr = rowBase + wr * 64 + mi * 16 + orow0;
#pragma unroll
    for (int ni = 0; ni < 4; ++ni) {
      long gc = colBase + wc * 64 + ni * 16 + fr;
#pragma unroll
      for (int r = 0; r < 4; ++r)
        C[(gr + r) * (long)N + gc] = f2b(acc[mi][ni][r]);
    }
  }
}

// ---------------- final GEMM, split-K=3 into f32 partials -------------------
__global__ __launch_bounds__(256) void gemm_final_sk(const unsigned short* __restrict__ A,
                                                     const unsigned short* __restrict__ BT,
                                                     float* __restrict__ Cpart) {
  __shared__ unsigned short As[2][128 * 32];
  __shared__ unsigned short Bs[2][128 * 32];
  constexpr int N = 768, K = 2304, CK = 768;
  const int tid = threadIdx.x;
  const int lane = tid & 63;
  const int wv = tid >> 6;
  const int wr = wv >> 1, wc = wv & 1;
  const int z = blockIdx.z;

  int lin = blockIdx.y * gridDim.x + blockIdx.x;   // 192 blocks/plane
  int swz = (lin & 7) * 24 + (lin >> 3);
  const long rowBase = (long)(swz / 6) * 128;
  const long colBase = (long)(swz % 6) * 128;

  f32x4 acc[4][4];
#pragma unroll
  for (int i = 0; i < 4; ++i)
#pragma unroll
    for (int j = 0; j < 4; ++j)
#pragma unroll
      for (int r = 0; r < 4; ++r) acc[i][j][r] = 0.f;

  const int g0 = tid, g1 = tid + 256;
  const int r0 = g0 >> 2, k80 = (g0 & 3) ^ ((r0 >> 1) & 3);
  const int r1 = g1 >> 2, k81 = (g1 & 3) ^ ((r1 >> 1) & 3);
  const unsigned short* ga0 = A + (rowBase + r0) * (long)K + z * CK + k80 * 8;
  const unsigned short* ga1 = A + (rowBase + r1) * (long)K + z * CK + k81 * 8;
  const unsigned short* gb0 = BT + (colBase + r0) * (long)K + z * CK + k80 * 8;
  const unsigned short* gb1 = BT + (colBase + r1) * (long)K + z * CK + k81 * 8;

  const int k8 = lane >> 4;
  const int fr = lane & 15;
  int aoff[4], boff[4];
#pragma unroll
  for (int i = 0; i < 4; ++i) {
    int rowA = wr * 64 + i * 16 + fr;
    aoff[i] = (rowA * 4 + (k8 ^ ((rowA >> 1) & 3))) * 8;
    int rowB = wc * 64 + i * 16 + fr;
    boff[i] = (rowB * 4 + (k8 ^ ((rowB >> 1) & 3))) * 8;
  }

  auto stage = [&](int buf, int t) {
    int ko = t * 32;
    gload_lds16(ga0 + ko, &As[buf][g0 * 8]);
    gload_lds16(ga1 + ko, &As[buf][g1 * 8]);
    gload_lds16(gb0 + ko, &Bs[buf][g0 * 8]);
    gload_lds16(gb1 + ko, &Bs[buf][g1 * 8]);
  };

  constexpr int nk = CK >> 5;   // 24
  stage(0, 0);
  __syncthreads();
  for (int t = 0; t < nk; ++t) {
    int cur = t & 1;
    if (t + 1 < nk) stage(cur ^ 1, t + 1);
    bf16x8 af[4], bfr[4];
#pragma unroll
    for (int i = 0; i < 4; ++i) af[i] = *(const bf16x8*)(&As[cur][aoff[i]]);
#pragma unroll
    for (int i = 0; i < 4; ++i) bfr[i] = *(const bf16x8*)(&Bs[cur][boff[i]]);
#pragma unroll
    for (int mi = 0; mi < 4; ++mi)
#pragma unroll
      for (int ni = 0; ni < 4; ++ni)
        acc[mi][ni] = __builtin_amdgcn_mfma_f32_16x16x32_bf16(af[mi], bfr[ni], acc[mi][ni], 0, 0, 0);
    __syncthreads();
  }

  float* Cz = Cpart + (long)z * NTOK * DD;
  const int orow0 = (lane >> 4) * 4;
#pragma unroll
  for (int mi = 0; mi < 4; ++mi) {
    long gr = rowBase + wr * 64 + mi * 16 + orow0;
#pragma unroll
    for (int ni = 0; ni < 4; ++ni) {
      long gc = colBase + wc * 64 + ni * 16 + fr;
#pragma unroll
      for (int r = 0; r < 4; ++r)
        Cz[(gr + r) * (long)N + gc] = acc[mi][ni][r];
    }
  }
}

// ---------------- reduce split-K partials + bias -> d_out -------------------
__global__ __launch_bounds__(256) void reduce_out(const float* __restrict__ P,
                                                  const float* __restrict__ bias,
                                                  float* __restrict__ out) {
  long i = (long)blockIdx.x * 256 + threadIdx.x;   // over NTOK*DD/4 f32x4
  const f32x4* p0 = (const f32x4*)P;
  const f32x4* p1 = (const f32x4*)(P + (long)NTOK * DD);
  const f32x4* p2 = (const f32x4*)(P + 2L * NTOK * DD);
  f32x4 v = p0[i];
  v += p1[i];
  v += p2[i];
  int c4 = (int)(i % (DD / 4));
  v += *(const f32x4*)(bias + c4 * 4);
  ((f32x4*)out)[i] = v;
}

// ------- merged shuffles: reformat_t8 (6) | gather_vt (672) | transpose_vl (3072)
__global__ __launch_bounds__(256) void shuffle_all(
    const unsigned short* __restrict__ T8, unsigned short* __restrict__ K8,
    unsigned short* __restrict__ Vt8,
    const unsigned short* __restrict__ KVg, unsigned short* __restrict__ Vt,
    const unsigned short* __restrict__ QKV4, unsigned short* __restrict__ Vtl) {
  __shared__ unsigned short tile[16][68];
  int id = blockIdx.x;
  int tid = threadIdx.x;
  if (id < 6) {
    // reformat T8 [128][1536] -> K8 [b][16][768], Vt8 [b][768][32]
    int cb = id % 3, b = id / 3;
    int c = cb * 256 + tid;
#pragma unroll
    for (int j = 0; j < 8; ++j) {
      const unsigned short* src = T8 + (long)(b * 8 + j) * 1536;
      K8[((long)b * 16 + j) * DD + c]  = src[c];
      Vt8[((long)b * DD + c) * 32 + j] = src[768 + c];
    }
#pragma unroll
    for (int j = 8; j < 16; ++j) K8[((long)b * 16 + j) * DD + c] = 0;
#pragma unroll
    for (int j = 8; j < 32; ++j) Vt8[((long)b * DD + c) * 32 + j] = 0;
  } else if (id < 6 + 672) {
    // gather V transposed from compact KVg: Vt[b][c][j]
    int idx = id - 6;
    int jt = idx % 28, rest = idx / 28;
    int ct = rest % 12, b = rest / 12;
    int jj = tid & 15, cl = tid >> 4;
    int j = jt * 16 + jj;
    const unsigned short* src = KVg + ((long)b * KPAD + j) * 1536 + 768 + ct * 64;
    *(uint2*)&tile[jj][cl * 4] = *(const uint2*)&src[cl * 4];
    __syncthreads();
    int c = tid >> 2;
    int jl = (tid & 3) * 4;
    unsigned v0 = tile[jl + 0][c], v1 = tile[jl + 1][c];
    unsigned v2 = tile[jl + 2][c], v3 = tile[jl + 3][c];
    unsigned short* dst = Vt + ((long)b * DD + ct * 64 + c) * KPAD + jt * 16 + jl;
    *(uint2*)dst = uint2{v0 | (v1 << 16), v2 | (v3 << 16)};
  } else {
    // full V transpose for local branch: Vtl[b][c][s]
    int idx = id - 678;
    int jt = idx % 128, rest = idx / 128;
    int ct = rest % 12, b = rest / 12;
    int jj = tid & 15, cl = tid >> 4;
    const unsigned short* src = QKV4 + ((long)b * SS + jt * 16 + jj) * 3072 + 2304 + ct * 64;
    *(uint2*)&tile[jj][cl * 4] = *(const uint2*)&src[cl * 4];
    __syncthreads();
    int c = tid >> 2;
    int jl = (tid & 3) * 4;
    unsigned v0 = tile[jl + 0][c], v1 = tile[jl + 1][c];
    unsigned v2 = tile[jl + 2][c], v3 = tile[jl + 3][c];
    unsigned short* dst = Vtl + ((long)b * DD + ct * 64 + c) * (long)SS + jt * 16 + jl;
    *(uint2*)dst = uint2{v0 | (v1 << 16), v2 | (v3 << 16)};
  }
}

// ---------------- attention bodies ------------------------------------------
__device__ __forceinline__ void attn_flash_body(
    const unsigned short* __restrict__ QKV4,  // [4096][3072]
    const unsigned short* __restrict__ KVg,   // [b*448][1536]
    const unsigned short* __restrict__ Vt,    // [b][768][448]
    float* __restrict__ Outp,
    unsigned short* smem) {
  unsigned short* Kl = smem;            // [2][64*64]
  unsigned short* Vl = smem + 8192;     // [2][64*64]
  unsigned short* Pl = smem + 16384;    // [4][16*68]
  int tid = threadIdx.x, w = tid >> 6, lane = tid & 63;
  int fr = lane & 15, g = lane >> 4;
  int b = blockIdx.y / HH, h = blockIdx.y % HH, hoff = h * 64;
  int qbase = blockIdx.x * 64 + w * 16;
  long qrow = (long)b * SS + qbase + fr;

  const unsigned short* qptr = QKV4 + qrow * 3072 + hoff + g * 8;
  bf16x8 bq0 = *(const bf16x8*)(qptr);
  bf16x8 bq1 = *(const bf16x8*)(qptr + 32);

  const int s0 = tid, s1 = tid + 256;
  const int r0 = s0 >> 3, c0 = (s0 & 7) ^ (r0 & 7);
  const int r1 = s1 >> 3, c1 = (s1 & 7) ^ (r1 & 7);
  const unsigned short* kg_b = KVg + (long)b * KPAD * 1536 + hoff;
  const unsigned short* vt_b = Vt + ((long)b * DD + hoff) * KPAD;

  auto stage = [&](int buf, int t0) {
    gload_lds16(kg_b + (long)(t0 * 64 + r0) * 1536 + c0 * 8, &Kl[buf * 4096 + s0 * 8]);
    gload_lds16(kg_b + (long)(t0 * 64 + r1) * 1536 + c1 * 8, &Kl[buf * 4096 + s1 * 8]);
    gload_lds16(vt_b + (long)r0 * KPAD + t0 * 64 + c0 * 8, &Vl[buf * 4096 + s0 * 8]);
    gload_lds16(vt_b + (long)r1 * KPAD + t0 * 64 + c1 * 8, &Vl[buf * 4096 + s1 * 8]);
  };

  f32x4 oacc[4];
#pragma unroll
  for (int mf = 0; mf < 4; ++mf)
#pragma unroll
    for (int r = 0; r < 4; ++r) oacc[mf][r] = 0.f;
  float m = -3.0e38f, l = 0.f;

  stage(0, 0);
  asm volatile("s_waitcnt vmcnt(0)" ::: "memory");
  __syncthreads();

  for (int t = 0; t < NKT; ++t) {
    int cur = t & 1;
    if (t + 1 < NKT) stage(cur ^ 1, t + 1);

    f32x4 st[4];
#pragma unroll
    for (int kt = 0; kt < 4; ++kt) {
      int row = kt * 16 + fr;
      bf16x8 a0 = *(const bf16x8*)(&Kl[cur * 4096 + (row * 8 + (g ^ (row & 7))) * 8]);
      bf16x8 a1 = *(const bf16x8*)(&Kl[cur * 4096 + (row * 8 + ((4 + g) ^ (row & 7))) * 8]);
      f32x4 z = {0.f, 0.f, 0.f, 0.f};
      z = __builtin_amdgcn_mfma_f32_16x16x32_bf16(a0, bq0, z, 0, 0, 0);
      st[kt] = __builtin_amdgcn_mfma_f32_16x16x32_bf16(a1, bq1, z, 0, 0, 0);
    }

    float tm = -3.0e38f;
#pragma unroll
    for (int kt = 0; kt < 4; ++kt)
#pragma unroll
      for (int r = 0; r < 4; ++r) {
        int key = t * 64 + kt * 16 + g * 4 + r;
        float s = (key < KSEL) ? st[kt][r] * 0.125f : -1.0e30f;
        st[kt][r] = s;
        tm = fmaxf(tm, s);
      }
    tm = fmaxf(tm, __shfl_xor(tm, 16, 64));
    tm = fmaxf(tm, __shfl_xor(tm, 32, 64));
    float newm = fmaxf(m, tm);
    float f = __expf(m - newm);
    float tsum = 0.f;
#pragma unroll
    for (int kt = 0; kt < 4; ++kt)
#pragma unroll
      for (int r = 0; r < 4; ++r) {
        float e = __expf(st[kt][r] - newm);
        st[kt][r] = e;
        tsum += e;
      }
    tsum += __shfl_xor(tsum, 16, 64);
    tsum += __shfl_xor(tsum, 32, 64);
    l = l * f + tsum;
    m = newm;
#pragma unroll
    for (int mf = 0; mf < 4; ++mf)
#pragma unroll
      for (int r = 0; r < 4; ++r) oacc[mf][r] *= f;

    unsigned short* pw = &Pl[w * 1088 + fr * 68 + g * 4];
#pragma unroll
    for (int kt = 0; kt < 4; ++kt) {
      uint2 pk;
      pk.x = (unsigned)f2b(st[kt][0]) | ((unsigned)f2b(st[kt][1]) << 16);
      pk.y = (unsigned)f2b(st[kt][2]) | ((unsigned)f2b(st[kt][3]) << 16);
      *(uint2*)(pw + kt * 16) = pk;
    }

    const unsigned short* prd = &Pl[w * 1088 + fr * 68];
#pragma unroll
    for (int ks2 = 0; ks2 < 2; ++ks2) {
      bf16x8 pf = *(const bf16x8*)(prd + ks2 * 32 + g * 8);
#pragma unroll
      for (int mf = 0; mf < 4; ++mf) {
        int vr = mf * 16 + fr;
        int vc = ks2 * 4 + g;
        bf16x8 vf = *(const bf16x8*)(&Vl[cur * 4096 + (vr * 8 + (vc ^ (vr & 7))) * 8]);
        oacc[mf] = __builtin_amdgcn_mfma_f32_16x16x32_bf16(vf, pf, oacc[mf], 0, 0, 0);
      }
    }

    asm volatile("s_waitcnt vmcnt(0)" ::: "memory");
    __syncthreads();
  }

  float inv = 1.f / l;
  float* orow = Outp + qrow * DD + hoff;
#pragma unroll
  for (int mf = 0; mf < 4; ++mf) {
    f32x4 ov;
#pragma unroll
    for (int r = 0; r < 4; ++r) ov[r] = oacc[mf][r] * inv;
    *(f32x4*)(orow + mf * 16 + g * 4) = ov;
  }
}

__device__ __forceinline__ void attn_win_body(
    const unsigned short* __restrict__ QKV,
    const unsigned short* __restrict__ K8,
    const unsigned short* __restrict__ Vt,
    float* __restrict__ Outp,
    int LD, int QO, long VSTR, bool local,
    unsigned short* smem) {
  // per-wave P tile: smem + w*640 ([16*40])
  int tid = threadIdx.x, w = tid >> 6, lane = tid & 63;
  int fr = lane & 15, g = lane >> 4;
  int b = blockIdx.y / HH, h = blockIdx.y % HH, hoff = h * 64;
  int qbase = blockIdx.x * 64 + w * 16;
  long qrow = (long)b * SS + qbase + fr;

  const unsigned short* qptr = QKV + qrow * LD + QO + hoff + g * 8;
  bf16x8 bq0 = *(const bf16x8*)(qptr);
  bf16x8 bq1 = *(const bf16x8*)(qptr + 32);

  int kstart = qbase - 8;
  if (kstart < 0) kstart = 0;
  if (kstart > SS - 32) kstart = SS - 32;

  f32x4 st[2];
  if (local) {
#pragma unroll
    for (int kt = 0; kt < 2; ++kt) {
      const unsigned short* kp =
          QKV + ((long)b * SS + kstart + kt * 16 + fr) * LD + 1536 + hoff + g * 8;
      bf16x8 a0 = *(const bf16x8*)(kp);
      bf16x8 a1 = *(const bf16x8*)(kp + 32);
      f32x4 z = {0.f, 0.f, 0.f, 0.f};
      z = __builtin_amdgcn_mfma_f32_16x16x32_bf16(a0, bq0, z, 0, 0, 0);
      st[kt] = __builtin_amdgcn_mfma_f32_16x16x32_bf16(a1, bq1, z, 0, 0, 0);
    }
  } else {
    const unsigned short* kp = K8 + ((long)b * 16 + fr) * DD + hoff + g * 8;
    bf16x8 a0 = *(const bf16x8*)(kp);
    bf16x8 a1 = *(const bf16x8*)(kp + 32);
    f32x4 z = {0.f, 0.f, 0.f, 0.f};
    z = __builtin_amdgcn_mfma_f32_16x16x32_bf16(a0, bq0, z, 0, 0, 0);
    st[0] = __builtin_amdgcn_mfma_f32_16x16x32_bf16(a1, bq1, z, 0, 0, 0);
    st[1] = f32x4{0.f, 0.f, 0.f, 0.f};
  }

  float m = -3.0e38f;
#pragma unroll
  for (int kt = 0; kt < 2; ++kt)
#pragma unroll
    for (int r = 0; r < 4; ++r) {
      int idx = kt * 16 + g * 4 + r;
      bool valid;
      if (local) {
        int rel = kstart + idx - qbase - fr;
        valid = (rel >= -8) && (rel <= 8);
      } else {
        valid = (idx < 8);
      }
      float s = valid ? st[kt][r] * 0.125f : -1.0e30f;
      st[kt][r] = s;
      m = fmaxf(m, s);
    }
  m = fmaxf(m, __shfl_xor(m, 16, 64));
  m = fmaxf(m, __shfl_xor(m, 32, 64));

  float lsum = 0.f;
#pragma unroll
  for (int kt = 0; kt < 2; ++kt)
#pragma unroll
    for (int r = 0; r < 4; ++r) {
      float e = __expf(st[kt][r] - m);
      st[kt][r] = e;
      lsum += e;
    }
  lsum += __shfl_xor(lsum, 16, 64);
  lsum += __shfl_xor(lsum, 32, 64);

  unsigned short* pl = smem + w * 640 + fr * 40 + g * 4;
#pragma unroll
  for (int kt = 0; kt < 2; ++kt) {
    uint2 pk;
    pk.x = (unsigned)f2b(st[kt][0]) | ((unsigned)f2b(st[kt][1]) << 16);
    pk.y = (unsigned)f2b(st[kt][2]) | ((unsigned)f2b(st[kt][3]) << 16);
    *(uint2*)(pl + kt * 16) = pk;
  }

  f32x4 oacc[4];
#pragma unroll
  for (int mf = 0; mf < 4; ++mf)
#pragma unroll
    for (int r = 0; r < 4; ++r) oacc[mf][r] = 0.f;

  const unsigned short* pr = smem + w * 640 + fr * 40 + g * 8;
  bf16x8 pf = *(const bf16x8*)(pr);
  long kb2 = local ? kstart : 0;
#pragma unroll
  for (int mf = 0; mf < 4; ++mf) {
    const unsigned short* vp =
        Vt + ((long)b * DD + hoff + mf * 16 + fr) * VSTR + kb2 + g * 8;
    bf16x8 vf = *(const bf16x8*)(vp);
    oacc[mf] = __builtin_amdgcn_mfma_f32_16x16x32_bf16(vf, pf, oacc[mf], 0, 0, 0);
  }

  float inv = 1.f / lsum;
  float* orow = Outp + qrow * DD + hoff;
#pragma unroll
  for (int mf = 0; mf < 4; ++mf) {
    f32x4 ov;
#pragma unroll
    for (int r = 0; r < 4; ++r) ov[r] = oacc[mf][r] * inv;
    *(f32x4*)(orow + mf * 16 + g * 4) = ov;
  }
}

// ---------------- merged attention dispatch (z: 0=global 1=local 2=temporal)
__global__ __launch_bounds__(256) void attn_all(
    const unsigned short* __restrict__ QKV4,  // [4096][3072]
    const unsigned short* __restrict__ KVg,   // [b*448][1536]
    const unsigned short* __restrict__ Vt,    // [b][768][448]
    const unsigned short* __restrict__ Qt,    // [4096][768]
    const unsigned short* __restrict__ K8,    // [b][16][768]
    const unsigned short* __restrict__ Vt8,   // [b][768][32]
    const unsigned short* __restrict__ Vtl,   // [b][768][2048]
    float* __restrict__ gout, float* __restrict__ lout, float* __restrict__ tout) {
  __shared__ unsigned short smem[20736];      // flash: 2x4096 K + 2x4096 V + 4x1088 P
  int z = blockIdx.z;
  if (z == 0) {
    attn_flash_body(QKV4, KVg, Vt, gout, smem);
  } else if (z == 1) {
    attn_win_body(QKV4, nullptr, Vtl, lout, 3072, 768, SS, true, smem);
  } else {
    attn_win_body(Qt, K8, Vt8, tout, 768, 0, 32, false, smem);
  }
}

// ---------------- layernorm + gate scale + concat to bf16 -------------------
__global__ __launch_bounds__(256) void ln_gate_concat(
    const float* __restrict__ gsrc, const float* __restrict__ lsrc, const float* __restrict__ tsrc,
    const float* __restrict__ gg, const float* __restrict__ gb,
    const float* __restrict__ lgam, const float* __restrict__ lbet,
    const float* __restrict__ tg, const float* __restrict__ tb,
    const float* __restrict__ fw, unsigned short* __restrict__ comb) {
  int row = blockIdx.x;
  int b = row >> 11;
  int tid = threadIdx.x;
  __shared__ float red[8];
  const float* srcs[3] = {gsrc, lsrc, tsrc};
  const float* gams[3] = {gg, lgam, tg};
  const float* bets[3] = {gb, lbet, tb};
#pragma unroll
  for (int br = 0; br < 3; ++br) {
    const float* src = srcs[br] + (long)row * DD;
    float x0 = src[tid], x1 = src[tid + 256], x2 = src[tid + 512];
    float s = x0 + x1 + x2;
    float ss = x0 * x0 + x1 * x1 + x2 * x2;
#pragma unroll
    for (int msk = 1; msk < 64; msk <<= 1) {
      s += __shfl_xor(s, msk, 64);
      ss += __shfl_xor(ss, msk, 64);
    }
    int wv = tid >> 6, lane = tid & 63;
    if (lane == 0) { red[wv] = s; red[4 + wv] = ss; }
    __syncthreads();
    float S4 = red[0] + red[1] + red[2] + red[3];
    float SQ = red[4] + red[5] + red[6] + red[7];
    float mean = S4 * (1.f / (float)DD);
    float var = SQ * (1.f / (float)DD) - mean * mean;
    float rs = rsqrtf(var + 1e-5f);
    float gate = fw[b * 3 + br];
    const float* gam = gams[br];
    const float* bet = bets[br];
    unsigned short* dst = comb + (long)row * 2304 + br * DD;
    dst[tid]       = f2b(((x0 - mean) * rs * gam[tid]       + bet[tid])       * gate);
    dst[tid + 256] = f2b(((x1 - mean) * rs * gam[tid + 256] + bet[tid + 256]) * gate);
    dst[tid + 512] = f2b(((x2 - mean) * rs * gam[tid + 512] + bet[tid + 512]) * gate);
    __syncthreads();
  }
}

// ---------------- launcher ---------------------------------------------------
extern "C" void kernel_launch(void* const* d_in, const int* in_sizes, int n_in,
                              void* d_out, int out_size, void* d_ws, size_t ws_size,
                              hipStream_t stream) {
  const float* x        = (const float*)d_in[0];
  const float* wgq      = (const float*)d_in[1];
  const float* wgk      = (const float*)d_in[2];
  const float* wgv      = (const float*)d_in[3];
  const float* wlq      = (const float*)d_in[4];
  const float* wlk      = (const float*)d_in[5];
  const float* wlv      = (const float*)d_in[6];
  const float* wtq      = (const float*)d_in[7];
  const float* wtk      = (const float*)d_in[8];
  const float* wtv      = (const float*)d_in[9];
  const float* w_out    = (const float*)d_in[10];
  const float* b_out    = (const float*)d_in[11];
  const float* w_gate   = (const float*)d_in[12];
  const float* b_gate   = (const float*)d_in[13];
  const float* w_sparse = (const float*)d_in[14];
  const float* b_sparse = (const float*)d_in[15];
  const float* g_gamma  = (const float*)d_in[16];
  const float* g_beta   = (const float*)d_in[17];
  const float* l_gamma  = (const float*)d_in[18];
  const float* l_beta   = (const float*)d_in[19];
  const float* t_gamma  = (const float*)d_in[20];
  const float* t_beta   = (const float*)d_in[21];
  float* outp = (float*)d_out;

  unsigned short* xb    = (unsigned short*)d_ws;
  unsigned short* xpb   = xb    + (long)NTOK * DD;
  unsigned short* WTx4  = xpb   + (long)NTOK * DD;        // [3072][768]
  unsigned short* WTkv  = WTx4  + (long)3072 * DD;        // [1536][768]
  unsigned short* WTqt  = WTkv  + (long)1536 * DD;        // [768][768]
  unsigned short* WTtkv = WTqt  + (long)DD * DD;          // [1536][768]
  unsigned short* WTo   = WTtkv + (long)1536 * DD;        // [768][2304]
  unsigned short* QKV4  = WTo   + (long)DD * 2304;        // [4096][3072]
  unsigned short* Qt    = QKV4  + (long)NTOK * 3072;      // [4096][768]
  unsigned short* A_sel = Qt    + (long)NTOK * DD;        // [896][768]
  unsigned short* KVg   = A_sel + (long)BB * KPAD * DD;   // [896][1536]
  unsigned short* A_t8  = KVg   + (long)BB * KPAD * 1536; // [128][768]
  unsigned short* T8    = A_t8  + (long)128 * DD;         // [128][1536]
  unsigned short* K8    = T8    + (long)128 * 1536;       // [2][16][768]
  unsigned short* Vt8   = K8    + (long)BB * 16 * DD;     // [2][768][32]
  unsigned short* Vt    = Vt8   + (long)BB * DD * 32;     // [2][768][448]
  unsigned short* comb  = Vt    + (long)BB * DD * KPAD;   // [4096][2304]
  float* gout    = (float*)(comb + (long)NTOK * 2304);
  float* lout    = gout + (long)NTOK * DD;
  float* tout    = lout + (long)NTOK * DD;
  float* imp     = tout + (long)NTOK * DD;
  float* partial = imp + NTOK;
  float* fw      = partial + 32 * DD;
  int*   sel     = (int*)(fw + 8);
  // reuse: Vtl overlays xpb (dead after gemm_multi); Cpart overlays
  // gout/lout/tout (dead after ln_gate_concat; exactly 3 slabs of NTOK*DD f32)
  unsigned short* Vtl   = xpb;                            // [2][768][2048]
  float*          Cpart = gout;                           // [3][4096][768]

  prep_imp<<<SS, 256, 0, stream>>>(x, w_sparse, b_sparse, xb, xpb, imp);
  transpose_all<<<dim3(24, 72, 10), dim3(32, 8), 0, stream>>>(
      wgq, wgk, wgv, wlq, wlk, wlv, wtq, wtk, wtv, w_out,
      WTx4, WTkv, WTqt, WTtkv, WTo);
  topk_kernel<<<BB, 1024, 0, stream>>>(imp, sel);
  gate1<<<dim3(16, BB), 256, 0, stream>>>(x, partial);
  gate2<<<BB, 256, 0, stream>>>(partial, w_gate, b_gate, fw);

  gather_pre<<<BB * KPAD + 128, 192, 0, stream>>>(xb, xpb, sel, A_sel, A_t8);
  gemm_multi<<<1056, 256, 0, stream>>>(xb, WTx4, QKV4, A_sel, WTkv, KVg,
                                       xpb, WTqt, Qt, A_t8, WTtkv, T8);
  shuffle_all<<<3750, 256, 0, stream>>>(T8, K8, Vt8, KVg, Vt, QKV4, Vtl);

  attn_all<<<dim3(32, BB * HH, 3), 256, 0, stream>>>(QKV4, KVg, Vt, Qt, K8, Vt8,
                                                     Vtl, gout, lout, tout);

  ln_gate_concat<<<NTOK, 256, 0, stream>>>(gout, lout, tout, g_gamma, g_beta,
                                           l_gamma, l_beta, t_gamma, t_beta, fw, comb);
  gemm_final_sk<<<dim3(6, 32, 3), 256, 0, stream>>>(comb, WTo, Cpart);
  reduce_out<<<NTOK * DD / 4 / 256, 256, 0, stream>>>(Cpart, b_out, outp);
}

// Round 11
// 205.535 us; speedup vs baseline: 1.3670x; 1.0196x over previous
//
#include <hip/hip_runtime.h>
#include <cstdint>

// Problem constants
constexpr int BB   = 2;
constexpr int SS   = 2048;
constexpr int DD   = 768;
constexpr int HH   = 12;
constexpr int NTOK = BB * SS;          // 4096
constexpr int KSEL = 409;              // int((1-0.8)*2048)
constexpr int KPAD = 448;              // 7 kv-tiles of 64
constexpr int NKT  = 7;                // kv tiles of 64 keys

typedef __bf16 bf16x8 __attribute__((ext_vector_type(8)));
typedef float  f32x4  __attribute__((ext_vector_type(4)));

__device__ __forceinline__ float b2f(unsigned short u) {
  return __uint_as_float(((unsigned)u) << 16);
}
__device__ __forceinline__ unsigned short f2b(float f) {
  unsigned u = __float_as_uint(f);
  u += 0x7fffu + ((u >> 16) & 1u);   // RNE
  return (unsigned short)(u >> 16);
}
__device__ __forceinline__ unsigned long long shfl_xor_u64(unsigned long long v, int m) {
  unsigned lo = (unsigned)v, hi = (unsigned)(v >> 32);
  lo = __shfl_xor(lo, m, 64);
  hi = __shfl_xor(hi, m, 64);
  return ((unsigned long long)hi << 32) | lo;
}

__device__ __forceinline__ void gload_lds16(const void* gsrc, void* ldst) {
  __builtin_amdgcn_global_load_lds(
      (__attribute__((address_space(1))) void*)(gsrc),
      (__attribute__((address_space(3))) void*)(ldst), 16, 0, 0);
}

// -------- fused prep: xb, xpb (=x+PE), importance; one block per srow -------
__global__ __launch_bounds__(256) void prep_imp(const float* __restrict__ x,
                                                const float* __restrict__ wsp,
                                                const float* __restrict__ bsp,
                                                unsigned short* __restrict__ xb,
                                                unsigned short* __restrict__ xpb,
                                                float* __restrict__ imp) {
  int srow = blockIdx.x;                // 0..2047
  int tid = threadIdx.x;
  const float* xr0 = x + (long)srow * DD;
  const float* xr1 = x + (long)(SS + srow) * DD;
  float acc0 = 0.f, acc1 = 0.f;
#pragma unroll
  for (int k = 0; k < 3; ++k) {
    int c = tid + k * 256;
    int j2 = c & ~1;
    float freq = __expf((float)j2 * -0.011992630692677323f);  // exp(-j2*ln(1e4)/768)
    float ang = (float)srow * freq;
    float pe = (c & 1) ? cosf(ang) : sinf(ang);
    float w = wsp[c];
    float x0 = xr0[c], x1 = xr1[c];
    xb[(long)srow * DD + c]        = f2b(x0);
    xb[(long)(SS + srow) * DD + c] = f2b(x1);
    xpb[(long)srow * DD + c]        = f2b(x0 + pe);
    xpb[(long)(SS + srow) * DD + c] = f2b(x1 + pe);
    acc0 += x0 * w;
    acc1 += x1 * w;
  }
#pragma unroll
  for (int m = 1; m < 64; m <<= 1) {
    acc0 += __shfl_xor(acc0, m, 64);
    acc1 += __shfl_xor(acc1, m, 64);
  }
  __shared__ float red[8];
  int wv = tid >> 6, lane = tid & 63;
  if (lane == 0) { red[wv] = acc0; red[4 + wv] = acc1; }
  __syncthreads();
  if (tid == 0) {
    imp[srow]      = red[0] + red[1] + red[2] + red[3] + bsp[0];
    imp[SS + srow] = red[4] + red[5] + red[6] + red[7] + bsp[0];
  }
}

// ---------------- transpose all weights to bf16 B^T (flattened grid) --------
__global__ void transpose_all(const float* w0, const float* w1, const float* w2,
                              const float* w3, const float* w4, const float* w5,
                              const float* w6, const float* w7, const float* w8,
                              const float* w9,
                              unsigned short* WTx4, unsigned short* WTkv,
                              unsigned short* WTqt, unsigned short* WTtkv,
                              unsigned short* WTo) {
  __shared__ float tile[32][33];
  int id = blockIdx.x;                  // 0..6911
  int z, bx, by;
  if (id < 5184) { z = id / 576; int rem = id % 576; by = rem / 24; bx = rem % 24; }
  else           { z = 9; int rem = id - 5184; by = rem / 24; bx = rem % 24; }
  const float* srcs[10] = {w0, w1, w2, w3, w4, w5, w6, w7, w8, w9};
  const float* src = srcs[z];
  unsigned short* dst;
  int R = DD;
  switch (z) {
    case 0: dst = WTx4;                       break;  // wgq
    case 1: dst = WTkv;                       break;  // wgk
    case 2: dst = WTkv + (long)DD * DD;       break;  // wgv
    case 3: dst = WTx4 + (long)DD * DD;       break;  // wlq
    case 4: dst = WTx4 + (long)2 * DD * DD;   break;  // wlk
    case 5: dst = WTx4 + (long)3 * DD * DD;   break;  // wlv
    case 6: dst = WTqt;                       break;  // wtq
    case 7: dst = WTtkv;                      break;  // wtk
    case 8: dst = WTtkv + (long)DD * DD;      break;  // wtv
    default: dst = WTo; R = 2304;             break;  // w_out
  }
  int r0 = by * 32;
  int c0 = bx * 32;
  int tx = threadIdx.x, ty = threadIdx.y;
  for (int i = ty; i < 32; i += 8) tile[i][tx] = src[(long)(r0 + i) * DD + c0 + tx];
  __syncthreads();
  for (int i = ty; i < 32; i += 8) dst[(long)(c0 + i) * R + r0 + tx] = f2b(tile[tx][i]);
}

// ------- top-k via hybrid bitonic sort (value desc, index asc) --------------
__global__ __launch_bounds__(1024) void topk_kernel(const float* __restrict__ imp,
                                                    int* __restrict__ sel) {
  __shared__ unsigned long long keys[SS];
  int b = blockIdx.x, tid = threadIdx.x;
  for (int i = tid; i < SS; i += 1024) {
    float v = imp[b * SS + i];
    unsigned u = __float_as_uint(v);
    u = (u & 0x80000000u) ? ~u : (u | 0x80000000u);   // ascending-order map
    unsigned du = ~u;                                  // descending
    keys[i] = ((unsigned long long)du << 32) | (unsigned)i;
  }
  __syncthreads();
  for (int k = 2; k <= SS; k <<= 1) {
    for (int j = k >> 1; j >= 64; j >>= 1) {
      for (int i = tid; i < SS; i += 1024) {
        int p = i ^ j;
        if (p > i) {
          unsigned long long a = keys[i], bb = keys[p];
          bool up = ((i & k) == 0);
          if ((a > bb) == up) { keys[i] = bb; keys[p] = a; }
        }
      }
      __syncthreads();
    }
    // register phase: j = min(k/2,32) .. 1
    unsigned long long k0 = keys[tid], k1 = keys[tid + 1024];
    bool up0 = ((tid & k) == 0);
    bool up1 = (((tid + 1024) & k) == 0);
    int j0 = (k >> 1) < 32 ? (k >> 1) : 32;
    for (int j = j0; j >= 1; j >>= 1) {
      bool low = ((tid & j) == 0);   // same bit for tid and tid+1024 (j<=32)
      unsigned long long p0 = shfl_xor_u64(k0, j);
      k0 = ((low == up0) == (k0 < p0)) ? k0 : p0;
      unsigned long long p1 = shfl_xor_u64(k1, j);
      k1 = ((low == up1) == (k1 < p1)) ? k1 : p1;
    }
    keys[tid] = k0; keys[tid + 1024] = k1;
    __syncthreads();
  }
  for (int i = tid; i < KSEL; i += 1024) sel[b * KSEL + i] = (int)(keys[i] & 0xffffffffu);
}

// ---------------- gate: mean over s, then softmax(mean @ w_gate + b) --------
__global__ __launch_bounds__(256) void gate1(const float* __restrict__ x,
                                             float* __restrict__ partial) {
  int b = blockIdx.y, chunk = blockIdx.x, tid = threadIdx.x;
  for (int c = tid; c < DD; c += 256) {
    const float* xp = x + ((long)(b * SS + chunk * 128)) * DD + c;
    float acc = 0.f;
    for (int s2 = 0; s2 < 128; ++s2) acc += xp[(long)s2 * DD];
    partial[(long)(b * 16 + chunk) * DD + c] = acc;
  }
}

__global__ __launch_bounds__(256) void gate2(const float* __restrict__ partial,
                                             const float* __restrict__ w_gate,
                                             const float* __restrict__ b_gate,
                                             float* __restrict__ fw) {
  int b = blockIdx.x, tid = threadIdx.x;
  __shared__ float meanbuf[DD];
  __shared__ float lg[3];
  for (int c = tid; c < DD; c += 256) {
    float acc = 0.f;
    for (int p = 0; p < 16; ++p) acc += partial[(long)(b * 16 + p) * DD + c];
    meanbuf[c] = acc * (1.0f / (float)SS);
  }
  __syncthreads();
  if (tid < 3) {
    float acc = b_gate[tid];
    for (int d = 0; d < DD; ++d) acc += meanbuf[d] * w_gate[d * 3 + tid];
    lg[tid] = acc;
  }
  __syncthreads();
  if (tid == 0) {
    float mx = fmaxf(lg[0], fmaxf(lg[1], lg[2]));
    float e0 = expf(lg[0] - mx), e1 = expf(lg[1] - mx), e2 = expf(lg[2] - mx);
    float inv = 1.f / (e0 + e1 + e2);
    fw[b * 3 + 0] = e0 * inv; fw[b * 3 + 1] = e1 * inv; fw[b * 3 + 2] = e2 * inv;
  }
}

// -------- merged gather: A_sel rows (topk) + A_t8 temporal rows -------------
__global__ __launch_bounds__(192) void gather_pre(const unsigned short* __restrict__ xb,
                                                  const unsigned short* __restrict__ xpb,
                                                  const int* __restrict__ sel,
                                                  unsigned short* __restrict__ A_sel,
                                                  unsigned short* __restrict__ A_t8) {
  int id = blockIdx.x;
  int tid = threadIdx.x;
  if (id < BB * KPAD) {
    int b = id / KPAD, j = id % KPAD;
    uint2* dst = (uint2*)(A_sel + (long)id * DD);
    if (j < KSEL) {
      const uint2* src = (const uint2*)(xb + (long)(b * SS + sel[b * KSEL + j]) * DD);
      dst[tid] = src[tid];
    } else {
      dst[tid] = uint2{0u, 0u};
    }
  } else {
    int r = id - BB * KPAD;     // 0..127
    uint2* dst = (uint2*)(A_t8 + (long)r * DD);
    if (r < 16) {
      int b = r >> 3, j = (r & 7) * 256;
      const uint2* src = (const uint2*)(xpb + (long)(b * SS + j) * DD);
      dst[tid] = src[tid];
    } else {
      dst[tid] = uint2{0u, 0u};
    }
  }
}

// ---------------- fused projection GEMMs (all K=768, 128x128 tiles) ---------
// tiles: QKV4 768 | KVg 84 | Qt 192 | T8 12 => 1056 (8*132, bijective swz).
// V-region tiles (mode>0) stage C in LDS and write the TRANSPOSED consumer
// buffers (Vtl/Vt/Vt8/K8) directly; their row-major C is never materialized.
__global__ __launch_bounds__(256) void gemm_multi(
    const unsigned short* __restrict__ xb,    const unsigned short* __restrict__ WTx4,
    unsigned short* __restrict__ QKV4,
    const unsigned short* __restrict__ A_sel, const unsigned short* __restrict__ WTkv,
    unsigned short* __restrict__ KVg,
    const unsigned short* __restrict__ xpb,   const unsigned short* __restrict__ WTqt,
    unsigned short* __restrict__ Qt,
    const unsigned short* __restrict__ A_t8,  const unsigned short* __restrict__ WTtkv,
    unsigned short* __restrict__ K8, unsigned short* __restrict__ Vt8,
    unsigned short* __restrict__ Vt, unsigned short* __restrict__ Vtl) {
  __shared__ unsigned short smem[16512];      // As/Bs during k-loop; Ct[128][129] after
  unsigned short* AsB = smem;                 // [buf*4096 + idx]
  unsigned short* BsB = smem + 8192;
  constexpr int K = DD;
  const int tid = threadIdx.x;
  const int lane = tid & 63;
  const int wv = tid >> 6;
  const int wr = wv >> 1, wc = wv & 1;

  int lin = blockIdx.x;
  int swz = (lin & 7) * 132 + (lin >> 3);
  const unsigned short *A, *BT;
  unsigned short* C;
  int N, ntx, tile, mode;
  if (swz < 768)       { A = xb;    BT = WTx4;  C = QKV4; N = 3072; ntx = 24; tile = swz;
                         mode = ((tile % 24) >= 18) ? 1 : 0; }
  else if (swz < 852)  { A = A_sel; BT = WTkv;  C = KVg;  N = 1536; ntx = 12; tile = swz - 768;
                         mode = ((tile % 12) >= 6) ? 2 : 0; }
  else if (swz < 1044) { A = xpb;   BT = WTqt;  C = Qt;   N = 768;  ntx = 6;  tile = swz - 852;
                         mode = 0; }
  else                 { A = A_t8;  BT = WTtkv; C = nullptr; N = 1536; ntx = 12; tile = swz - 1044;
                         mode = ((tile % 12) >= 6) ? 4 : 3; }
  const long rowBase = (long)(tile / ntx) * 128;
  const long colBase = (long)(tile % ntx) * 128;
  const int vcol0 = (mode == 1) ? (int)colBase - 2304
                  : (mode == 2 || mode == 4) ? (int)colBase - 768 : 0;

  f32x4 acc[4][4];
#pragma unroll
  for (int i = 0; i < 4; ++i)
#pragma unroll
    for (int j = 0; j < 4; ++j)
#pragma unroll
      for (int r = 0; r < 4; ++r) acc[i][j][r] = 0.f;

  const int g0 = tid, g1 = tid + 256;
  const int r0 = g0 >> 2, k80 = (g0 & 3) ^ ((r0 >> 1) & 3);
  const int r1 = g1 >> 2, k81 = (g1 & 3) ^ ((r1 >> 1) & 3);
  const unsigned short* ga0 = A + (rowBase + r0) * (long)K + k80 * 8;
  const unsigned short* ga1 = A + (rowBase + r1) * (long)K + k81 * 8;
  const unsigned short* gb0 = BT + (colBase + r0) * (long)K + k80 * 8;
  const unsigned short* gb1 = BT + (colBase + r1) * (long)K + k81 * 8;

  const int k8 = lane >> 4;
  const int fr = lane & 15;
  int aoff[4], boff[4];
#pragma unroll
  for (int i = 0; i < 4; ++i) {
    int rowA = wr * 64 + i * 16 + fr;
    aoff[i] = (rowA * 4 + (k8 ^ ((rowA >> 1) & 3))) * 8;
    int rowB = wc * 64 + i * 16 + fr;
    boff[i] = (rowB * 4 + (k8 ^ ((rowB >> 1) & 3))) * 8;
  }

  auto stage = [&](int buf, int t) {
    int ko = t * 32;
    gload_lds16(ga0 + ko, &AsB[buf * 4096 + g0 * 8]);
    gload_lds16(ga1 + ko, &AsB[buf * 4096 + g1 * 8]);
    gload_lds16(gb0 + ko, &BsB[buf * 4096 + g0 * 8]);
    gload_lds16(gb1 + ko, &BsB[buf * 4096 + g1 * 8]);
  };

  constexpr int nk = K >> 5;   // 24
  stage(0, 0);
  __syncthreads();
  for (int t = 0; t < nk; ++t) {
    int cur = t & 1;
    if (t + 1 < nk) stage(cur ^ 1, t + 1);
    bf16x8 af[4], bfr[4];
#pragma unroll
    for (int i = 0; i < 4; ++i) af[i] = *(const bf16x8*)(&AsB[cur * 4096 + aoff[i]]);
#pragma unroll
    for (int i = 0; i < 4; ++i) bfr[i] = *(const bf16x8*)(&BsB[cur * 4096 + boff[i]]);
#pragma unroll
    for (int mi = 0; mi < 4; ++mi)
#pragma unroll
      for (int ni = 0; ni < 4; ++ni)
        acc[mi][ni] = __builtin_amdgcn_mfma_f32_16x16x32_bf16(af[mi], bfr[ni], acc[mi][ni], 0, 0, 0);
    __syncthreads();
  }

  const int orow0 = (lane >> 4) * 4;
  if (mode == 0) {
#pragma unroll
    for (int mi = 0; mi < 4; ++mi) {
      long gr = rowBase + wr * 64 + mi * 16 + orow0;
#pragma unroll
      for (int ni = 0; ni < 4; ++ni) {
        long gc = colBase + wc * 64 + ni * 16 + fr;
#pragma unroll
        for (int r = 0; r < 4; ++r)
          C[(gr + r) * (long)N + gc] = f2b(acc[mi][ni][r]);
      }
    }
  } else {
    unsigned short* Ct = smem;  // [128][129]
#pragma unroll
    for (int mi = 0; mi < 4; ++mi) {
      int lr = wr * 64 + mi * 16 + orow0;
#pragma unroll
      for (int ni = 0; ni < 4; ++ni) {
        int lc = wc * 64 + ni * 16 + fr;
#pragma unroll
        for (int r = 0; r < 4; ++r)
          Ct[(lr + r) * 129 + lc] = f2b(acc[mi][ni][r]);
      }
    }
    __syncthreads();
    if (mode == 1) {            // QKV4 v_l -> Vtl[b][c][s]
#pragma unroll
      for (int e = 0; e < 8; ++e) {
        int id = tid + e * 256;
        int c = id >> 4, sc = id & 15;
        int grow = (int)rowBase + sc * 8;
        int bb2 = grow >> 11, s = grow & (SS - 1);
        union { unsigned short s8[8]; uint4 v; } u;
#pragma unroll
        for (int k2 = 0; k2 < 8; ++k2) u.s8[k2] = Ct[(sc * 8 + k2) * 129 + c];
        *(uint4*)(Vtl + ((long)bb2 * DD + vcol0 + c) * SS + s) = u.v;
      }
    } else if (mode == 2) {     // KVg v -> Vt[b][c][j]
#pragma unroll
      for (int e = 0; e < 8; ++e) {
        int id = tid + e * 256;
        int c = id >> 4, sc = id & 15;
        int grow = (int)rowBase + sc * 8;
        int bb2 = grow / KPAD, j = grow % KPAD;
        union { unsigned short s8[8]; uint4 v; } u;
#pragma unroll
        for (int k2 = 0; k2 < 8; ++k2) u.s8[k2] = Ct[(sc * 8 + k2) * 129 + c];
        *(uint4*)(Vt + ((long)bb2 * DD + vcol0 + c) * KPAD + j) = u.v;
      }
    } else if (mode == 3) {     // T8 k -> K8[b][16][768] (rows 8..15 zero)
#pragma unroll
      for (int e = 0; e < 2; ++e) {
        int id = tid + e * 256;            // 0..511
        int row = id >> 4;                 // 0..31
        int bb2 = row >> 4, jj = row & 15;
        int c8 = id & 15;
        int srcrow = (jj < 8) ? bb2 * 8 + jj : 16 + jj;   // rows>=16 are zero
        union { unsigned short s8[8]; uint4 v; } u;
#pragma unroll
        for (int k2 = 0; k2 < 8; ++k2) u.s8[k2] = Ct[srcrow * 129 + c8 * 8 + k2];
        *(uint4*)(K8 + ((long)bb2 * 16 + jj) * DD + colBase + c8 * 8) = u.v;
      }
    } else {                    // mode 4: T8 v -> Vt8[b][c][32] (j>=8 zero)
#pragma unroll
      for (int e = 0; e < 4; ++e) {
        int id = tid + e * 256;            // 0..1023
        int bb2 = id >> 9;
        int rem = id & 511;
        int c = rem >> 2, jc = rem & 3;
        union { unsigned short s8[8]; uint4 v; } u;
        if (jc == 0) {
#pragma unroll
          for (int k2 = 0; k2 < 8; ++k2) u.s8[k2] = Ct[(bb2 * 8 + k2) * 129 + c];
        } else {
#pragma unroll
          for (int k2 = 0; k2 < 8; ++k2) u.s8[k2] = 0;
        }
        *(uint4*)(Vt8 + ((long)bb2 * DD + vcol0 + c) * 32 + jc * 8) = u.v;
      }
    }
  }
}

// ---------------- final GEMM, split-K=3 into f32 partials -------------------
__global__ __launch_bounds__(256) void gemm_final_sk(const unsigned short* __restrict__ A,
                                                     const unsigned short* __restrict__ BT,
                                                     float* __restrict__ Cpart) {
  __shared__ unsigned short As[2][128 * 32];
  __shared__ unsigned short Bs[2][128 * 32];
  constexpr int N = 768, K = 2304, CK = 768;
  const int tid = threadIdx.x;
  const int lane = tid & 63;
  const int wv = tid >> 6;
  const int wr = wv >> 1, wc = wv & 1;
  const int z = blockIdx.z;

  int lin = blockIdx.y * gridDim.x + blockIdx.x;   // 192 blocks/plane
  int swz = (lin & 7) * 24 + (lin >> 3);
  const long rowBase = (long)(swz / 6) * 128;
  const long colBase = (long)(swz % 6) * 128;

  f32x4 acc[4][4];
#pragma unroll
  for (int i = 0; i < 4; ++i)
#pragma unroll
    for (int j = 0; j < 4; ++j)
#pragma unroll
      for (int r = 0; r < 4; ++r) acc[i][j][r] = 0.f;

  const int g0 = tid, g1 = tid + 256;
  const int r0 = g0 >> 2, k80 = (g0 & 3) ^ ((r0 >> 1) & 3);
  const int r1 = g1 >> 2, k81 = (g1 & 3) ^ ((r1 >> 1) & 3);
  const unsigned short* ga0 = A + (rowBase + r0) * (long)K + z * CK + k80 * 8;
  const unsigned short* ga1 = A + (rowBase + r1) * (long)K + z * CK + k81 * 8;
  const unsigned short* gb0 = BT + (colBase + r0) * (long)K + z * CK + k80 * 8;
  const unsigned short* gb1 = BT + (colBase + r1) * (long)K + z * CK + k81 * 8;

  const int k8 = lane >> 4;
  const int fr = lane & 15;
  int aoff[4], boff[4];
#pragma unroll
  for (int i = 0; i < 4; ++i) {
    int rowA = wr * 64 + i * 16 + fr;
    aoff[i] = (rowA * 4 + (k8 ^ ((rowA >> 1) & 3))) * 8;
    int rowB = wc * 64 + i * 16 + fr;
    boff[i] = (rowB * 4 + (k8 ^ ((rowB >> 1) & 3))) * 8;
  }

  auto stage = [&](int buf, int t) {
    int ko = t * 32;
    gload_lds16(ga0 + ko, &As[buf][g0 * 8]);
    gload_lds16(ga1 + ko, &As[buf][g1 * 8]);
    gload_lds16(gb0 + ko, &Bs[buf][g0 * 8]);
    gload_lds16(gb1 + ko, &Bs[buf][g1 * 8]);
  };

  constexpr int nk = CK >> 5;   // 24
  stage(0, 0);
  __syncthreads();
  for (int t = 0; t < nk; ++t) {
    int cur = t & 1;
    if (t + 1 < nk) stage(cur ^ 1, t + 1);
    bf16x8 af[4], bfr[4];
#pragma unroll
    for (int i = 0; i < 4; ++i) af[i] = *(const bf16x8*)(&As[cur][aoff[i]]);
#pragma unroll
    for (int i = 0; i < 4; ++i) bfr[i] = *(const bf16x8*)(&Bs[cur][boff[i]]);
#pragma unroll
    for (int mi = 0; mi < 4; ++mi)
#pragma unroll
      for (int ni = 0; ni < 4; ++ni)
        acc[mi][ni] = __builtin_amdgcn_mfma_f32_16x16x32_bf16(af[mi], bfr[ni], acc[mi][ni], 0, 0, 0);
    __syncthreads();
  }

  float* Cz = Cpart + (long)z * NTOK * DD;
  const int orow0 = (lane >> 4) * 4;
#pragma unroll
  for (int mi = 0; mi < 4; ++mi) {
    long gr = rowBase + wr * 64 + mi * 16 + orow0;
#pragma unroll
    for (int ni = 0; ni < 4; ++ni) {
      long gc = colBase + wc * 64 + ni * 16 + fr;
#pragma unroll
      for (int r = 0; r < 4; ++r)
        Cz[(gr + r) * (long)N + gc] = acc[mi][ni][r];
    }
  }
}

// ---------------- reduce split-K partials + bias -> d_out -------------------
__global__ __launch_bounds__(256) void reduce_out(const float* __restrict__ P,
                                                  const float* __restrict__ bias,
                                                  float* __restrict__ out) {
  long i = (long)blockIdx.x * 256 + threadIdx.x;   // over NTOK*DD/4 f32x4
  const f32x4* p0 = (const f32x4*)P;
  const f32x4* p1 = (const f32x4*)(P + (long)NTOK * DD);
  const f32x4* p2 = (const f32x4*)(P + 2L * NTOK * DD);
  f32x4 v = p0[i];
  v += p1[i];
  v += p2[i];
  int c4 = (int)(i % (DD / 4));
  v += *(const f32x4*)(bias + c4 * 4);
  ((f32x4*)out)[i] = v;
}

// ---------------- attention bodies ------------------------------------------
__device__ __forceinline__ void attn_flash_body(
    const unsigned short* __restrict__ QKV4,  // [4096][3072]
    const unsigned short* __restrict__ KVg,   // [b*448][1536]
    const unsigned short* __restrict__ Vt,    // [b][768][448]
    float* __restrict__ Outp,
    unsigned short* smem) {
  unsigned short* Kl = smem;            // [2][64*64]
  unsigned short* Vl = smem + 8192;     // [2][64*64]
  unsigned short* Pl = smem + 16384;    // [4][16*68]
  int tid = threadIdx.x, w = tid >> 6, lane = tid & 63;
  int fr = lane & 15, g = lane >> 4;
  int b = blockIdx.y / HH, h = blockIdx.y % HH, hoff = h * 64;
  int qbase = blockIdx.x * 64 + w * 16;
  long qrow = (long)b * SS + qbase + fr;

  const unsigned short* qptr = QKV4 + qrow * 3072 + hoff + g * 8;
  bf16x8 bq0 = *(const bf16x8*)(qptr);
  bf16x8 bq1 = *(const bf16x8*)(qptr + 32);

  const int s0 = tid, s1 = tid + 256;
  const int r0 = s0 >> 3, c0 = (s0 & 7) ^ (r0 & 7);
  const int r1 = s1 >> 3, c1 = (s1 & 7) ^ (r1 & 7);
  const unsigned short* kg_b = KVg + (long)b * KPAD * 1536 + hoff;
  const unsigned short* vt_b = Vt + ((long)b * DD + hoff) * KPAD;

  auto stage = [&](int buf, int t0) {
    gload_lds16(kg_b + (long)(t0 * 64 + r0) * 1536 + c0 * 8, &Kl[buf * 4096 + s0 * 8]);
    gload_lds16(kg_b + (long)(t0 * 64 + r1) * 1536 + c1 * 8, &Kl[buf * 4096 + s1 * 8]);
    gload_lds16(vt_b + (long)r0 * KPAD + t0 * 64 + c0 * 8, &Vl[buf * 4096 + s0 * 8]);
    gload_lds16(vt_b + (long)r1 * KPAD + t0 * 64 + c1 * 8, &Vl[buf * 4096 + s1 * 8]);
  };

  f32x4 oacc[4];
#pragma unroll
  for (int mf = 0; mf < 4; ++mf)
#pragma unroll
    for (int r = 0; r < 4; ++r) oacc[mf][r] = 0.f;
  float m = -3.0e38f, l = 0.f;

  stage(0, 0);
  asm volatile("s_waitcnt vmcnt(0)" ::: "memory");
  __syncthreads();

  for (int t = 0; t < NKT; ++t) {
    int cur = t & 1;
    if (t + 1 < NKT) stage(cur ^ 1, t + 1);

    f32x4 st[4];
#pragma unroll
    for (int kt = 0; kt < 4; ++kt) {
      int row = kt * 16 + fr;
      bf16x8 a0 = *(const bf16x8*)(&Kl[cur * 4096 + (row * 8 + (g ^ (row & 7))) * 8]);
      bf16x8 a1 = *(const bf16x8*)(&Kl[cur * 4096 + (row * 8 + ((4 + g) ^ (row & 7))) * 8]);
      f32x4 z = {0.f, 0.f, 0.f, 0.f};
      z = __builtin_amdgcn_mfma_f32_16x16x32_bf16(a0, bq0, z, 0, 0, 0);
      st[kt] = __builtin_amdgcn_mfma_f32_16x16x32_bf16(a1, bq1, z, 0, 0, 0);
    }

    float tm = -3.0e38f;
#pragma unroll
    for (int kt = 0; kt < 4; ++kt)
#pragma unroll
      for (int r = 0; r < 4; ++r) {
        int key = t * 64 + kt * 16 + g * 4 + r;
        float s = (key < KSEL) ? st[kt][r] * 0.125f : -1.0e30f;
        st[kt][r] = s;
        tm = fmaxf(tm, s);
      }
    tm = fmaxf(tm, __shfl_xor(tm, 16, 64));
    tm = fmaxf(tm, __shfl_xor(tm, 32, 64));
    float newm = fmaxf(m, tm);
    float f = __expf(m - newm);
    float tsum = 0.f;
#pragma unroll
    for (int kt = 0; kt < 4; ++kt)
#pragma unroll
      for (int r = 0; r < 4; ++r) {
        float e = __expf(st[kt][r] - newm);
        st[kt][r] = e;
        tsum += e;
      }
    tsum += __shfl_xor(tsum, 16, 64);
    tsum += __shfl_xor(tsum, 32, 64);
    l = l * f + tsum;
    m = newm;
#pragma unroll
    for (int mf = 0; mf < 4; ++mf)
#pragma unroll
      for (int r = 0; r < 4; ++r) oacc[mf][r] *= f;

    unsigned short* pw = &Pl[w * 1088 + fr * 68 + g * 4];
#pragma unroll
    for (int kt = 0; kt < 4; ++kt) {
      uint2 pk;
      pk.x = (unsigned)f2b(st[kt][0]) | ((unsigned)f2b(st[kt][1]) << 16);
      pk.y = (unsigned)f2b(st[kt][2]) | ((unsigned)f2b(st[kt][3]) << 16);
      *(uint2*)(pw + kt * 16) = pk;
    }

    const unsigned short* prd = &Pl[w * 1088 + fr * 68];
#pragma unroll
    for (int ks2 = 0; ks2 < 2; ++ks2) {
      bf16x8 pf = *(const bf16x8*)(prd + ks2 * 32 + g * 8);
#pragma unroll
      for (int mf = 0; mf < 4; ++mf) {
        int vr = mf * 16 + fr;
        int vc = ks2 * 4 + g;
        bf16x8 vf = *(const bf16x8*)(&Vl[cur * 4096 + (vr * 8 + (vc ^ (vr & 7))) * 8]);
        oacc[mf] = __builtin_amdgcn_mfma_f32_16x16x32_bf16(vf, pf, oacc[mf], 0, 0, 0);
      }
    }

    asm volatile("s_waitcnt vmcnt(0)" ::: "memory");
    __syncthreads();
  }

  float inv = 1.f / l;
  float* orow = Outp + qrow * DD + hoff;
#pragma unroll
  for (int mf = 0; mf < 4; ++mf) {
    f32x4 ov;
#pragma unroll
    for (int r = 0; r < 4; ++r) ov[r] = oacc[mf][r] * inv;
    *(f32x4*)(orow + mf * 16 + g * 4) = ov;
  }
}

__device__ __forceinline__ void attn_win_body(
    const unsigned short* __restrict__ QKV,
    const unsigned short* __restrict__ K8,
    const unsigned short* __restrict__ Vt,
    float* __restrict__ Outp,
    int LD, int QO, long VSTR, bool local,
    unsigned short* smem) {
  int tid = threadIdx.x, w = tid >> 6, lane = tid & 63;
  int fr = lane & 15, g = lane >> 4;
  int b = blockIdx.y / HH, h = blockIdx.y % HH, hoff = h * 64;
  int qbase = blockIdx.x * 64 + w * 16;
  long qrow = (long)b * SS + qbase + fr;

  const unsigned short* qptr = QKV + qrow * LD + QO + hoff + g * 8;
  bf16x8 bq0 = *(const bf16x8*)(qptr);
  bf16x8 bq1 = *(const bf16x8*)(qptr + 32);

  int kstart = qbase - 8;
  if (kstart < 0) kstart = 0;
  if (kstart > SS - 32) kstart = SS - 32;

  f32x4 st[2];
  if (local) {
#pragma unroll
    for (int kt = 0; kt < 2; ++kt) {
      const unsigned short* kp =
          QKV + ((long)b * SS + kstart + kt * 16 + fr) * LD + 1536 + hoff + g * 8;
      bf16x8 a0 = *(const bf16x8*)(kp);
      bf16x8 a1 = *(const bf16x8*)(kp + 32);
      f32x4 z = {0.f, 0.f, 0.f, 0.f};
      z = __builtin_amdgcn_mfma_f32_16x16x32_bf16(a0, bq0, z, 0, 0, 0);
      st[kt] = __builtin_amdgcn_mfma_f32_16x16x32_bf16(a1, bq1, z, 0, 0, 0);
    }
  } else {
    const unsigned short* kp = K8 + ((long)b * 16 + fr) * DD + hoff + g * 8;
    bf16x8 a0 = *(const bf16x8*)(kp);
    bf16x8 a1 = *(const bf16x8*)(kp + 32);
    f32x4 z = {0.f, 0.f, 0.f, 0.f};
    z = __builtin_amdgcn_mfma_f32_16x16x32_bf16(a0, bq0, z, 0, 0, 0);
    st[0] = __builtin_amdgcn_mfma_f32_16x16x32_bf16(a1, bq1, z, 0, 0, 0);
    st[1] = f32x4{0.f, 0.f, 0.f, 0.f};
  }

  float m = -3.0e38f;
#pragma unroll
  for (int kt = 0; kt < 2; ++kt)
#pragma unroll
    for (int r = 0; r < 4; ++r) {
      int idx = kt * 16 + g * 4 + r;
      bool valid;
      if (local) {
        int rel = kstart + idx - qbase - fr;
        valid = (rel >= -8) && (rel <= 8);
      } else {
        valid = (idx < 8);
      }
      float s = valid ? st[kt][r] * 0.125f : -1.0e30f;
      st[kt][r] = s;
      m = fmaxf(m, s);
    }
  m = fmaxf(m, __shfl_xor(m, 16, 64));
  m = fmaxf(m, __shfl_xor(m, 32, 64));

  float lsum = 0.f;
#pragma unroll
  for (int kt = 0; kt < 2; ++kt)
#pragma unroll
    for (int r = 0; r < 4; ++r) {
      float e = __expf(st[kt][r] - m);
      st[kt][r] = e;
      lsum += e;
    }
  lsum += __shfl_xor(lsum, 16, 64);
  lsum += __shfl_xor(lsum, 32, 64);

  unsigned short* pl = smem + w * 640 + fr * 40 + g * 4;
#pragma unroll
  for (int kt = 0; kt < 2; ++kt) {
    uint2 pk;
    pk.x = (unsigned)f2b(st[kt][0]) | ((unsigned)f2b(st[kt][1]) << 16);
    pk.y = (unsigned)f2b(st[kt][2]) | ((unsigned)f2b(st[kt][3]) << 16);
    *(uint2*)(pl + kt * 16) = pk;
  }

  f32x4 oacc[4];
#pragma unroll
  for (int mf = 0; mf < 4; ++mf)
#pragma unroll
    for (int r = 0; r < 4; ++r) oacc[mf][r] = 0.f;

  const unsigned short* pr = smem + w * 640 + fr * 40 + g * 8;
  bf16x8 pf = *(const bf16x8*)(pr);
  long kb2 = local ? kstart : 0;
#pragma unroll
  for (int mf = 0; mf < 4; ++mf) {
    const unsigned short* vp =
        Vt + ((long)b * DD + hoff + mf * 16 + fr) * VSTR + kb2 + g * 8;
    bf16x8 vf = *(const bf16x8*)(vp);
    oacc[mf] = __builtin_amdgcn_mfma_f32_16x16x32_bf16(vf, pf, oacc[mf], 0, 0, 0);
  }

  float inv = 1.f / lsum;
  float* orow = Outp + qrow * DD + hoff;
#pragma unroll
  for (int mf = 0; mf < 4; ++mf) {
    f32x4 ov;
#pragma unroll
    for (int r = 0; r < 4; ++r) ov[r] = oacc[mf][r] * inv;
    *(f32x4*)(orow + mf * 16 + g * 4) = ov;
  }
}

// ---------------- merged attention dispatch (z: 0=global 1=local 2=temporal)
__global__ __launch_bounds__(256) void attn_all(
    const unsigned short* __restrict__ QKV4,
    const unsigned short* __restrict__ KVg,
    const unsigned short* __restrict__ Vt,
    const unsigned short* __restrict__ Qt,
    const unsigned short* __restrict__ K8,
    const unsigned short* __restrict__ Vt8,
    const unsigned short* __restrict__ Vtl,
    float* __restrict__ gout, float* __restrict__ lout, float* __restrict__ tout) {
  __shared__ unsigned short smem[20736];
  int z = blockIdx.z;
  if (z == 0) {
    attn_flash_body(QKV4, KVg, Vt, gout, smem);
  } else if (z == 1) {
    attn_win_body(QKV4, nullptr, Vtl, lout, 3072, 768, SS, true, smem);
  } else {
    attn_win_body(Qt, K8, Vt8, tout, 768, 0, 32, false, smem);
  }
}

// ---------------- layernorm + gate scale + concat to bf16 -------------------
__global__ __launch_bounds__(256) void ln_gate_concat(
    const float* __restrict__ gsrc, const float* __restrict__ lsrc, const float* __restrict__ tsrc,
    const float* __restrict__ gg, const float* __restrict__ gb,
    const float* __restrict__ lgam, const float* __restrict__ lbet,
    const float* __restrict__ tg, const float* __restrict__ tb,
    const float* __restrict__ fw, unsigned short* __restrict__ comb) {
  int row = blockIdx.x;
  int b = row >> 11;
  int tid = threadIdx.x;
  __shared__ float red[8];
  const float* srcs[3] = {gsrc, lsrc, tsrc};
  const float* gams[3] = {gg, lgam, tg};
  const float* bets[3] = {gb, lbet, tb};
#pragma unroll
  for (int br = 0; br < 3; ++br) {
    const float* src = srcs[br] + (long)row * DD;
    float x0 = src[tid], x1 = src[tid + 256], x2 = src[tid + 512];
    float s = x0 + x1 + x2;
    float ss = x0 * x0 + x1 * x1 + x2 * x2;
#pragma unroll
    for (int msk = 1; msk < 64; msk <<= 1) {
      s += __shfl_xor(s, msk, 64);
      ss += __shfl_xor(ss, msk, 64);
    }
    int wv = tid >> 6, lane = tid & 63;
    if (lane == 0) { red[wv] = s; red[4 + wv] = ss; }
    __syncthreads();
    float S4 = red[0] + red[1] + red[2] + red[3];
    float SQ = red[4] + red[5] + red[6] + red[7];
    float mean = S4 * (1.f / (float)DD);
    float var = SQ * (1.f / (float)DD) - mean * mean;
    float rs = rsqrtf(var + 1e-5f);
    float gate = fw[b * 3 + br];
    const float* gam = gams[br];
    const float* bet = bets[br];
    unsigned short* dst = comb + (long)row * 2304 + br * DD;
    dst[tid]       = f2b(((x0 - mean) * rs * gam[tid]       + bet[tid])       * gate);
    dst[tid + 256] = f2b(((x1 - mean) * rs * gam[tid + 256] + bet[tid + 256]) * gate);
    dst[tid + 512] = f2b(((x2 - mean) * rs * gam[tid + 512] + bet[tid + 512]) * gate);
    __syncthreads();
  }
}

// ---------------- launcher ---------------------------------------------------
extern "C" void kernel_launch(void* const* d_in, const int* in_sizes, int n_in,
                              void* d_out, int out_size, void* d_ws, size_t ws_size,
                              hipStream_t stream) {
  const float* x        = (const float*)d_in[0];
  const float* wgq      = (const float*)d_in[1];
  const float* wgk      = (const float*)d_in[2];
  const float* wgv      = (const float*)d_in[3];
  const float* wlq      = (const float*)d_in[4];
  const float* wlk      = (const float*)d_in[5];
  const float* wlv      = (const float*)d_in[6];
  const float* wtq      = (const float*)d_in[7];
  const float* wtk      = (const float*)d_in[8];
  const float* wtv      = (const float*)d_in[9];
  const float* w_out    = (const float*)d_in[10];
  const float* b_out    = (const float*)d_in[11];
  const float* w_gate   = (const float*)d_in[12];
  const float* b_gate   = (const float*)d_in[13];
  const float* w_sparse = (const float*)d_in[14];
  const float* b_sparse = (const float*)d_in[15];
  const float* g_gamma  = (const float*)d_in[16];
  const float* g_beta   = (const float*)d_in[17];
  const float* l_gamma  = (const float*)d_in[18];
  const float* l_beta   = (const float*)d_in[19];
  const float* t_gamma  = (const float*)d_in[20];
  const float* t_beta   = (const float*)d_in[21];
  float* outp = (float*)d_out;

  unsigned short* xb    = (unsigned short*)d_ws;
  unsigned short* xpb   = xb    + (long)NTOK * DD;
  unsigned short* WTx4  = xpb   + (long)NTOK * DD;        // [3072][768]
  unsigned short* WTkv  = WTx4  + (long)3072 * DD;        // [1536][768]
  unsigned short* WTqt  = WTkv  + (long)1536 * DD;        // [768][768]
  unsigned short* WTtkv = WTqt  + (long)DD * DD;          // [1536][768]
  unsigned short* WTo   = WTtkv + (long)1536 * DD;        // [768][2304]
  unsigned short* QKV4  = WTo   + (long)DD * 2304;        // [4096][3072]
  unsigned short* Qt    = QKV4  + (long)NTOK * 3072;      // [4096][768]
  unsigned short* A_sel = Qt    + (long)NTOK * DD;        // [896][768]
  unsigned short* KVg   = A_sel + (long)BB * KPAD * DD;   // [896][1536]
  unsigned short* A_t8  = KVg   + (long)BB * KPAD * 1536; // [128][768]
  unsigned short* K8    = A_t8  + (long)128 * DD;         // [2][16][768]
  unsigned short* Vt8   = K8    + (long)BB * 16 * DD;     // [2][768][32]
  unsigned short* Vt    = Vt8   + (long)BB * DD * 32;     // [2][768][448]
  unsigned short* Vtl   = Vt    + (long)BB * DD * KPAD;   // [2][768][2048]
  unsigned short* comb  = Vtl   + (long)BB * DD * SS;     // [4096][2304]
  float* gout    = (float*)(comb + (long)NTOK * 2304);
  float* lout    = gout + (long)NTOK * DD;
  float* tout    = lout + (long)NTOK * DD;
  float* imp     = tout + (long)NTOK * DD;
  float* partial = imp + NTOK;
  float* fw      = partial + 32 * DD;
  int*   sel     = (int*)(fw + 8);
  // Cpart overlays gout/lout/tout (dead after ln_gate_concat)
  float* Cpart = gout;                                    // [3][4096][768]

  prep_imp<<<SS, 256, 0, stream>>>(x, w_sparse, b_sparse, xb, xpb, imp);
  transpose_all<<<6912, dim3(32, 8), 0, stream>>>(
      wgq, wgk, wgv, wlq, wlk, wlv, wtq, wtk, wtv, w_out,
      WTx4, WTkv, WTqt, WTtkv, WTo);
  topk_kernel<<<BB, 1024, 0, stream>>>(imp, sel);
  gate1<<<dim3(16, BB), 256, 0, stream>>>(x, partial);
  gate2<<<BB, 256, 0, stream>>>(partial, w_gate, b_gate, fw);

  gather_pre<<<BB * KPAD + 128, 192, 0, stream>>>(xb, xpb, sel, A_sel, A_t8);
  gemm_multi<<<1056, 256, 0, stream>>>(xb, WTx4, QKV4, A_sel, WTkv, KVg,
                                       xpb, WTqt, Qt, A_t8, WTtkv,
                                       K8, Vt8, Vt, Vtl);

  attn_all<<<dim3(32, BB * HH, 3), 256, 0, stream>>>(QKV4, KVg, Vt, Qt, K8, Vt8,
                                                     Vtl, gout, lout, tout);

  ln_gate_concat<<<NTOK, 256, 0, stream>>>(gout, lout, tout, g_gamma, g_beta,
                                           l_gamma, l_beta, t_gamma, t_beta, fw, comb);
  gemm_final_sk<<<dim3(6, 32, 3), 256, 0, stream>>>(comb, WTo, Cpart);
  reduce_out<<<NTOK * DD / 4 / 256, 256, 0, stream>>>(Cpart, b_out, outp);
}

// Round 12
// 203.453 us; speedup vs baseline: 1.3809x; 1.0102x over previous
//
#include <hip/hip_runtime.h>
#include <cstdint>

// Problem constants
constexpr int BB   = 2;
constexpr int SS   = 2048;
constexpr int DD   = 768;
constexpr int HH   = 12;
constexpr int NTOK = BB * SS;          // 4096
constexpr int KSEL = 409;              // int((1-0.8)*2048)
constexpr int KPAD = 448;              // 7 kv-tiles of 64
constexpr int NKT  = 7;                // kv tiles of 64 keys

typedef __bf16 bf16x8 __attribute__((ext_vector_type(8)));
typedef float  f32x4  __attribute__((ext_vector_type(4)));

__device__ __forceinline__ float b2f(unsigned short u) {
  return __uint_as_float(((unsigned)u) << 16);
}
__device__ __forceinline__ unsigned short f2b(float f) {
  unsigned u = __float_as_uint(f);
  u += 0x7fffu + ((u >> 16) & 1u);   // RNE
  return (unsigned short)(u >> 16);
}
__device__ __forceinline__ unsigned long long shfl_xor_u64(unsigned long long v, int m) {
  unsigned lo = (unsigned)v, hi = (unsigned)(v >> 32);
  lo = __shfl_xor(lo, m, 64);
  hi = __shfl_xor(hi, m, 64);
  return ((unsigned long long)hi << 32) | lo;
}

__device__ __forceinline__ void gload_lds16(const void* gsrc, void* ldst) {
  __builtin_amdgcn_global_load_lds(
      (__attribute__((address_space(1))) void*)(gsrc),
      (__attribute__((address_space(3))) void*)(ldst), 16, 0, 0);
}

// -------- fused prep: xb, xpb (=x+PE), importance; one block per srow -------
__global__ __launch_bounds__(256) void prep_imp(const float* __restrict__ x,
                                                const float* __restrict__ wsp,
                                                const float* __restrict__ bsp,
                                                unsigned short* __restrict__ xb,
                                                unsigned short* __restrict__ xpb,
                                                float* __restrict__ imp) {
  int srow = blockIdx.x;                // 0..2047
  int tid = threadIdx.x;
  const float* xr0 = x + (long)srow * DD;
  const float* xr1 = x + (long)(SS + srow) * DD;
  float acc0 = 0.f, acc1 = 0.f;
#pragma unroll
  for (int k = 0; k < 3; ++k) {
    int c = tid + k * 256;
    int j2 = c & ~1;
    float freq = __expf((float)j2 * -0.011992630692677323f);  // exp(-j2*ln(1e4)/768)
    float ang = (float)srow * freq;
    float pe = (c & 1) ? cosf(ang) : sinf(ang);
    float w = wsp[c];
    float x0 = xr0[c], x1 = xr1[c];
    xb[(long)srow * DD + c]        = f2b(x0);
    xb[(long)(SS + srow) * DD + c] = f2b(x1);
    xpb[(long)srow * DD + c]        = f2b(x0 + pe);
    xpb[(long)(SS + srow) * DD + c] = f2b(x1 + pe);
    acc0 += x0 * w;
    acc1 += x1 * w;
  }
#pragma unroll
  for (int m = 1; m < 64; m <<= 1) {
    acc0 += __shfl_xor(acc0, m, 64);
    acc1 += __shfl_xor(acc1, m, 64);
  }
  __shared__ float red[8];
  int wv = tid >> 6, lane = tid & 63;
  if (lane == 0) { red[wv] = acc0; red[4 + wv] = acc1; }
  __syncthreads();
  if (tid == 0) {
    imp[srow]      = red[0] + red[1] + red[2] + red[3] + bsp[0];
    imp[SS + srow] = red[4] + red[5] + red[6] + red[7] + bsp[0];
  }
}

// ---------------- transpose all weights to bf16 B^T (flattened grid) --------
__global__ void transpose_all(const float* w0, const float* w1, const float* w2,
                              const float* w3, const float* w4, const float* w5,
                              const float* w6, const float* w7, const float* w8,
                              const float* w9,
                              unsigned short* WTx4, unsigned short* WTkv,
                              unsigned short* WTqt, unsigned short* WTtkv,
                              unsigned short* WTo) {
  __shared__ float tile[32][33];
  int id = blockIdx.x;                  // 0..6911
  int z, bx, by;
  if (id < 5184) { z = id / 576; int rem = id % 576; by = rem / 24; bx = rem % 24; }
  else           { z = 9; int rem = id - 5184; by = rem / 24; bx = rem % 24; }
  const float* srcs[10] = {w0, w1, w2, w3, w4, w5, w6, w7, w8, w9};
  const float* src = srcs[z];
  unsigned short* dst;
  int R = DD;
  switch (z) {
    case 0: dst = WTx4;                       break;  // wgq
    case 1: dst = WTkv;                       break;  // wgk
    case 2: dst = WTkv + (long)DD * DD;       break;  // wgv
    case 3: dst = WTx4 + (long)DD * DD;       break;  // wlq
    case 4: dst = WTx4 + (long)2 * DD * DD;   break;  // wlk
    case 5: dst = WTx4 + (long)3 * DD * DD;   break;  // wlv
    case 6: dst = WTqt;                       break;  // wtq
    case 7: dst = WTtkv;                      break;  // wtk
    case 8: dst = WTtkv + (long)DD * DD;      break;  // wtv
    default: dst = WTo; R = 2304;             break;  // w_out
  }
  int r0 = by * 32;
  int c0 = bx * 32;
  int tx = threadIdx.x, ty = threadIdx.y;
  for (int i = ty; i < 32; i += 8) tile[i][tx] = src[(long)(r0 + i) * DD + c0 + tx];
  __syncthreads();
  for (int i = ty; i < 32; i += 8) dst[(long)(c0 + i) * R + r0 + tx] = f2b(tile[tx][i]);
}

// ------- top-k via hybrid bitonic sort (value desc, index asc) --------------
__global__ __launch_bounds__(1024) void topk_kernel(const float* __restrict__ imp,
                                                    int* __restrict__ sel) {
  __shared__ unsigned long long keys[SS];
  int b = blockIdx.x, tid = threadIdx.x;
  for (int i = tid; i < SS; i += 1024) {
    float v = imp[b * SS + i];
    unsigned u = __float_as_uint(v);
    u = (u & 0x80000000u) ? ~u : (u | 0x80000000u);   // ascending-order map
    unsigned du = ~u;                                  // descending
    keys[i] = ((unsigned long long)du << 32) | (unsigned)i;
  }
  __syncthreads();
  for (int k = 2; k <= SS; k <<= 1) {
    for (int j = k >> 1; j >= 64; j >>= 1) {
      for (int i = tid; i < SS; i += 1024) {
        int p = i ^ j;
        if (p > i) {
          unsigned long long a = keys[i], bb = keys[p];
          bool up = ((i & k) == 0);
          if ((a > bb) == up) { keys[i] = bb; keys[p] = a; }
        }
      }
      __syncthreads();
    }
    // register phase: j = min(k/2,32) .. 1
    unsigned long long k0 = keys[tid], k1 = keys[tid + 1024];
    bool up0 = ((tid & k) == 0);
    bool up1 = (((tid + 1024) & k) == 0);
    int j0 = (k >> 1) < 32 ? (k >> 1) : 32;
    for (int j = j0; j >= 1; j >>= 1) {
      bool low = ((tid & j) == 0);   // same bit for tid and tid+1024 (j<=32)
      unsigned long long p0 = shfl_xor_u64(k0, j);
      k0 = ((low == up0) == (k0 < p0)) ? k0 : p0;
      unsigned long long p1 = shfl_xor_u64(k1, j);
      k1 = ((low == up1) == (k1 < p1)) ? k1 : p1;
    }
    keys[tid] = k0; keys[tid + 1024] = k1;
    __syncthreads();
  }
  for (int i = tid; i < KSEL; i += 1024) sel[b * KSEL + i] = (int)(keys[i] & 0xffffffffu);
}

// ---------------- gate: mean over s (bf16 input), then softmax --------------
__global__ __launch_bounds__(256) void gate1(const unsigned short* __restrict__ xb,
                                             float* __restrict__ partial) {
  int b = blockIdx.y, chunk = blockIdx.x, tid = threadIdx.x;
  for (int c = tid; c < DD; c += 256) {
    const unsigned short* xp = xb + ((long)(b * SS + chunk * 128)) * DD + c;
    float acc = 0.f;
    for (int s2 = 0; s2 < 128; ++s2) acc += b2f(xp[(long)s2 * DD]);
    partial[(long)(b * 16 + chunk) * DD + c] = acc;
  }
}

__global__ __launch_bounds__(256) void gate2(const float* __restrict__ partial,
                                             const float* __restrict__ w_gate,
                                             const float* __restrict__ b_gate,
                                             float* __restrict__ fw) {
  int b = blockIdx.x, tid = threadIdx.x;
  __shared__ float meanbuf[DD];
  __shared__ float lg[3];
  for (int c = tid; c < DD; c += 256) {
    float acc = 0.f;
    for (int p = 0; p < 16; ++p) acc += partial[(long)(b * 16 + p) * DD + c];
    meanbuf[c] = acc * (1.0f / (float)SS);
  }
  __syncthreads();
  if (tid < 3) {
    float acc = b_gate[tid];
    for (int d = 0; d < DD; ++d) acc += meanbuf[d] * w_gate[d * 3 + tid];
    lg[tid] = acc;
  }
  __syncthreads();
  if (tid == 0) {
    float mx = fmaxf(lg[0], fmaxf(lg[1], lg[2]));
    float e0 = expf(lg[0] - mx), e1 = expf(lg[1] - mx), e2 = expf(lg[2] - mx);
    float inv = 1.f / (e0 + e1 + e2);
    fw[b * 3 + 0] = e0 * inv; fw[b * 3 + 1] = e1 * inv; fw[b * 3 + 2] = e2 * inv;
  }
}

// -------- merged gather: A_sel rows (topk) + A_t8 temporal rows -------------
__global__ __launch_bounds__(192) void gather_pre(const unsigned short* __restrict__ xb,
                                                  const unsigned short* __restrict__ xpb,
                                                  const int* __restrict__ sel,
                                                  unsigned short* __restrict__ A_sel,
                                                  unsigned short* __restrict__ A_t8) {
  int id = blockIdx.x;
  int tid = threadIdx.x;
  if (id < BB * KPAD) {
    int b = id / KPAD, j = id % KPAD;
    uint2* dst = (uint2*)(A_sel + (long)id * DD);
    if (j < KSEL) {
      const uint2* src = (const uint2*)(xb + (long)(b * SS + sel[b * KSEL + j]) * DD);
      dst[tid] = src[tid];
    } else {
      dst[tid] = uint2{0u, 0u};
    }
  } else {
    int r = id - BB * KPAD;     // 0..127
    uint2* dst = (uint2*)(A_t8 + (long)r * DD);
    if (r < 16) {
      int b = r >> 3, j = (r & 7) * 256;
      const uint2* src = (const uint2*)(xpb + (long)(b * SS + j) * DD);
      dst[tid] = src[tid];
    } else {
      dst[tid] = uint2{0u, 0u};
    }
  }
}

// ---------------- fused projection GEMMs (all K=768, 128x128 tiles) ---------
// tiles: QKV4 768 | KVg 84 | Qt 192 | T8 12 => 1056 (8*132, bijective swz).
// V-region tiles write transposed consumer buffers DIRECTLY from acc
// (thread's 4 acc rows = 4 consecutive transposed-dest elements = uint2 store).
__global__ __launch_bounds__(256) void gemm_multi(
    const unsigned short* __restrict__ xb,    const unsigned short* __restrict__ WTx4,
    unsigned short* __restrict__ QKV4,
    const unsigned short* __restrict__ A_sel, const unsigned short* __restrict__ WTkv,
    unsigned short* __restrict__ KVg,
    const unsigned short* __restrict__ xpb,   const unsigned short* __restrict__ WTqt,
    unsigned short* __restrict__ Qt,
    const unsigned short* __restrict__ A_t8,  const unsigned short* __restrict__ WTtkv,
    unsigned short* __restrict__ K8, unsigned short* __restrict__ Vt8,
    unsigned short* __restrict__ Vt, unsigned short* __restrict__ Vtl) {
  __shared__ unsigned short AsB[2][4096];
  __shared__ unsigned short BsB[2][4096];
  constexpr int K = DD;
  const int tid = threadIdx.x;
  const int lane = tid & 63;
  const int wv = tid >> 6;
  const int wr = wv >> 1, wc = wv & 1;

  int lin = blockIdx.x;
  int swz = (lin & 7) * 132 + (lin >> 3);
  const unsigned short *A, *BT;
  int ntx, tile;
  if (swz < 768)       { A = xb;    BT = WTx4;  ntx = 24; tile = swz; }
  else if (swz < 852)  { A = A_sel; BT = WTkv;  ntx = 12; tile = swz - 768; }
  else if (swz < 1044) { A = xpb;   BT = WTqt;  ntx = 6;  tile = swz - 852; }
  else                 { A = A_t8;  BT = WTtkv; ntx = 12; tile = swz - 1044; }
  const long rowBase = (long)(tile / ntx) * 128;
  const long colBase = (long)(tile % ntx) * 128;

  f32x4 acc[4][4];
#pragma unroll
  for (int i = 0; i < 4; ++i)
#pragma unroll
    for (int j = 0; j < 4; ++j)
#pragma unroll
      for (int r = 0; r < 4; ++r) acc[i][j][r] = 0.f;

  const int g0 = tid, g1 = tid + 256;
  const int r0 = g0 >> 2, k80 = (g0 & 3) ^ ((r0 >> 1) & 3);
  const int r1 = g1 >> 2, k81 = (g1 & 3) ^ ((r1 >> 1) & 3);
  const unsigned short* ga0 = A + (rowBase + r0) * (long)K + k80 * 8;
  const unsigned short* ga1 = A + (rowBase + r1) * (long)K + k81 * 8;
  const unsigned short* gb0 = BT + (colBase + r0) * (long)K + k80 * 8;
  const unsigned short* gb1 = BT + (colBase + r1) * (long)K + k81 * 8;

  const int k8 = lane >> 4;
  const int fr = lane & 15;
  int aoff[4], boff[4];
#pragma unroll
  for (int i = 0; i < 4; ++i) {
    int rowA = wr * 64 + i * 16 + fr;
    aoff[i] = (rowA * 4 + (k8 ^ ((rowA >> 1) & 3))) * 8;
    int rowB = wc * 64 + i * 16 + fr;
    boff[i] = (rowB * 4 + (k8 ^ ((rowB >> 1) & 3))) * 8;
  }

  auto stage = [&](int buf, int t) {
    int ko = t * 32;
    gload_lds16(ga0 + ko, &AsB[buf][g0 * 8]);
    gload_lds16(ga1 + ko, &AsB[buf][g1 * 8]);
    gload_lds16(gb0 + ko, &BsB[buf][g0 * 8]);
    gload_lds16(gb1 + ko, &BsB[buf][g1 * 8]);
  };

  constexpr int nk = K >> 5;   // 24
  stage(0, 0);
  __syncthreads();
  for (int t = 0; t < nk; ++t) {
    int cur = t & 1;
    if (t + 1 < nk) stage(cur ^ 1, t + 1);
    bf16x8 af[4], bfr[4];
#pragma unroll
    for (int i = 0; i < 4; ++i) af[i] = *(const bf16x8*)(&AsB[cur][aoff[i]]);
#pragma unroll
    for (int i = 0; i < 4; ++i) bfr[i] = *(const bf16x8*)(&BsB[cur][boff[i]]);
#pragma unroll
    for (int mi = 0; mi < 4; ++mi)
#pragma unroll
      for (int ni = 0; ni < 4; ++ni)
        acc[mi][ni] = __builtin_amdgcn_mfma_f32_16x16x32_bf16(af[mi], bfr[ni], acc[mi][ni], 0, 0, 0);
    __syncthreads();
  }

  // epilogue: recompute mode/dest from swz (keeps k-loop register state lean)
  int mode, vcol0 = 0, N = 0;
  unsigned short* C = nullptr;
  if (swz < 768)       { mode = (colBase >= 2304) ? 1 : 0; C = QKV4; N = 3072;
                         vcol0 = (int)colBase - 2304; }
  else if (swz < 852)  { mode = (colBase >= 768) ? 2 : 0;  C = KVg;  N = 1536;
                         vcol0 = (int)colBase - 768; }
  else if (swz < 1044) { mode = 0; C = Qt; N = 768; }
  else                 { mode = (colBase >= 768) ? 4 : 3;
                         vcol0 = (int)colBase - 768; }

  const int orow0 = (lane >> 4) * 4;
  if (mode == 0) {
#pragma unroll
    for (int mi = 0; mi < 4; ++mi) {
      long gr = rowBase + wr * 64 + mi * 16 + orow0;
#pragma unroll
      for (int ni = 0; ni < 4; ++ni) {
        long gc = colBase + wc * 64 + ni * 16 + fr;
#pragma unroll
        for (int r = 0; r < 4; ++r)
          C[(gr + r) * (long)N + gc] = f2b(acc[mi][ni][r]);
      }
    }
  } else {
#pragma unroll
    for (int mi = 0; mi < 4; ++mi) {
      int lr = wr * 64 + mi * 16 + orow0;
      int grow = (int)rowBase + lr;            // 4-aligned; runs never cross b
#pragma unroll
      for (int ni = 0; ni < 4; ++ni) {
        int lc = wc * 64 + ni * 16 + fr;
        uint2 pk;
        pk.x = (unsigned)f2b(acc[mi][ni][0]) | ((unsigned)f2b(acc[mi][ni][1]) << 16);
        pk.y = (unsigned)f2b(acc[mi][ni][2]) | ((unsigned)f2b(acc[mi][ni][3]) << 16);
        if (mode == 1) {         // QKV4 v_l -> Vtl[b][c][s]
          int bb2 = grow >> 11, s = grow & (SS - 1);
          *(uint2*)(Vtl + ((long)bb2 * DD + vcol0 + lc) * SS + s) = pk;
        } else if (mode == 2) {  // KVg v -> Vt[b][c][j]
          int bb2 = grow / KPAD, j = grow - bb2 * KPAD;
          *(uint2*)(Vt + ((long)bb2 * DD + vcol0 + lc) * KPAD + j) = pk;
        } else if (mode == 3) {  // T8 k -> K8[b][16][768] rows 0..7 per b
          if (grow < 16) {
#pragma unroll
            for (int r = 0; r < 4; ++r) {
              int g2 = grow + r;
              K8[((long)(g2 >> 3) * 16 + (g2 & 7)) * DD + colBase + lc] =
                  f2b(acc[mi][ni][r]);
            }
          }
        } else {                 // mode 4: T8 v -> Vt8[b][c][32] j 0..7
          if (grow < 16) {
            *(uint2*)(Vt8 + ((long)(grow >> 3) * DD + vcol0 + lc) * 32 + (grow & 7)) = pk;
          }
        }
      }
    }
    if (mode == 3) {             // zero K8 rows jj=8..15, both b
      int row16 = tid >> 4, cg = tid & 15;
      int bb2 = row16 >> 3, jj = 8 + (row16 & 7);
      uint4 z4 = {0u, 0u, 0u, 0u};
      *(uint4*)(K8 + ((long)bb2 * 16 + jj) * DD + colBase + cg * 8) = z4;
    }
    if (mode == 4) {             // zero Vt8 j=8..31, both b
#pragma unroll
      for (int e = 0; e < 6; ++e) {
        int id = tid + e * 256;            // 0..1535
        int bb2 = id / 768, rem = id % 768;
        int c = rem / 6, ch = rem % 6;
        *(uint2*)(Vt8 + ((long)bb2 * DD + vcol0 + c) * 32 + 8 + ch * 4) = uint2{0u, 0u};
      }
    }
  }
}

// ---------------- final GEMM, split-K=3 into f32 partials -------------------
__global__ __launch_bounds__(256) void gemm_final_sk(const unsigned short* __restrict__ A,
                                                     const unsigned short* __restrict__ BT,
                                                     float* __restrict__ Cpart) {
  __shared__ unsigned short As[2][128 * 32];
  __shared__ unsigned short Bs[2][128 * 32];
  constexpr int N = 768, K = 2304, CK = 768;
  const int tid = threadIdx.x;
  const int lane = tid & 63;
  const int wv = tid >> 6;
  const int wr = wv >> 1, wc = wv & 1;
  const int z = blockIdx.z;

  int lin = blockIdx.y * gridDim.x + blockIdx.x;   // 192 blocks/plane
  int swz = (lin & 7) * 24 + (lin >> 3);
  const long rowBase = (long)(swz / 6) * 128;
  const long colBase = (long)(swz % 6) * 128;

  f32x4 acc[4][4];
#pragma unroll
  for (int i = 0; i < 4; ++i)
#pragma unroll
    for (int j = 0; j < 4; ++j)
#pragma unroll
      for (int r = 0; r < 4; ++r) acc[i][j][r] = 0.f;

  const int g0 = tid, g1 = tid + 256;
  const int r0 = g0 >> 2, k80 = (g0 & 3) ^ ((r0 >> 1) & 3);
  const int r1 = g1 >> 2, k81 = (g1 & 3) ^ ((r1 >> 1) & 3);
  const unsigned short* ga0 = A + (rowBase + r0) * (long)K + z * CK + k80 * 8;
  const unsigned short* ga1 = A + (rowBase + r1) * (long)K + z * CK + k81 * 8;
  const unsigned short* gb0 = BT + (colBase + r0) * (long)K + z * CK + k80 * 8;
  const unsigned short* gb1 = BT + (colBase + r1) * (long)K + z * CK + k81 * 8;

  const int k8 = lane >> 4;
  const int fr = lane & 15;
  int aoff[4], boff[4];
#pragma unroll
  for (int i = 0; i < 4; ++i) {
    int rowA = wr * 64 + i * 16 + fr;
    aoff[i] = (rowA * 4 + (k8 ^ ((rowA >> 1) & 3))) * 8;
    int rowB = wc * 64 + i * 16 + fr;
    boff[i] = (rowB * 4 + (k8 ^ ((rowB >> 1) & 3))) * 8;
  }

  auto stage = [&](int buf, int t) {
    int ko = t * 32;
    gload_lds16(ga0 + ko, &As[buf][g0 * 8]);
    gload_lds16(ga1 + ko, &As[buf][g1 * 8]);
    gload_lds16(gb0 + ko, &Bs[buf][g0 * 8]);
    gload_lds16(gb1 + ko, &Bs[buf][g1 * 8]);
  };

  constexpr int nk = CK >> 5;   // 24
  stage(0, 0);
  __syncthreads();
  for (int t = 0; t < nk; ++t) {
    int cur = t & 1;
    if (t + 1 < nk) stage(cur ^ 1, t + 1);
    bf16x8 af[4], bfr[4];
#pragma unroll
    for (int i = 0; i < 4; ++i) af[i] = *(const bf16x8*)(&As[cur][aoff[i]]);
#pragma unroll
    for (int i = 0; i < 4; ++i) bfr[i] = *(const bf16x8*)(&Bs[cur][boff[i]]);
#pragma unroll
    for (int mi = 0; mi < 4; ++mi)
#pragma unroll
      for (int ni = 0; ni < 4; ++ni)
        acc[mi][ni] = __builtin_amdgcn_mfma_f32_16x16x32_bf16(af[mi], bfr[ni], acc[mi][ni], 0, 0, 0);
    __syncthreads();
  }

  float* Cz = Cpart + (long)z * NTOK * DD;
  const int orow0 = (lane >> 4) * 4;
#pragma unroll
  for (int mi = 0; mi < 4; ++mi) {
    long gr = rowBase + wr * 64 + mi * 16 + orow0;
#pragma unroll
    for (int ni = 0; ni < 4; ++ni) {
      long gc = colBase + wc * 64 + ni * 16 + fr;
#pragma unroll
      for (int r = 0; r < 4; ++r)
        Cz[(gr + r) * (long)N + gc] = acc[mi][ni][r];
    }
  }
}

// ---------------- reduce split-K partials + bias -> d_out -------------------
__global__ __launch_bounds__(256) void reduce_out(const float* __restrict__ P,
                                                  const float* __restrict__ bias,
                                                  float* __restrict__ out) {
  long i = (long)blockIdx.x * 256 + threadIdx.x;   // over NTOK*DD/4 f32x4
  const f32x4* p0 = (const f32x4*)P;
  const f32x4* p1 = (const f32x4*)(P + (long)NTOK * DD);
  const f32x4* p2 = (const f32x4*)(P + 2L * NTOK * DD);
  f32x4 v = p0[i];
  v += p1[i];
  v += p2[i];
  int c4 = (int)(i % (DD / 4));
  v += *(const f32x4*)(bias + c4 * 4);
  ((f32x4*)out)[i] = v;
}

// ---------------- attention bodies (bf16 output into comb layout) -----------
__device__ __forceinline__ void attn_flash_body(
    const unsigned short* __restrict__ QKV4,  // [4096][3072]
    const unsigned short* __restrict__ KVg,   // [b*448][1536]
    const unsigned short* __restrict__ Vt,    // [b][768][448]
    unsigned short* __restrict__ comb,        // [4096][2304], br 0
    unsigned short* smem) {
  unsigned short* Kl = smem;            // [2][64*64]
  unsigned short* Vl = smem + 8192;     // [2][64*64]
  unsigned short* Pl = smem + 16384;    // [4][16*68]
  int tid = threadIdx.x, w = tid >> 6, lane = tid & 63;
  int fr = lane & 15, g = lane >> 4;
  int b = blockIdx.y / HH, h = blockIdx.y % HH, hoff = h * 64;
  int qbase = blockIdx.x * 64 + w * 16;
  long qrow = (long)b * SS + qbase + fr;

  const unsigned short* qptr = QKV4 + qrow * 3072 + hoff + g * 8;
  bf16x8 bq0 = *(const bf16x8*)(qptr);
  bf16x8 bq1 = *(const bf16x8*)(qptr + 32);

  const int s0 = tid, s1 = tid + 256;
  const int r0 = s0 >> 3, c0 = (s0 & 7) ^ (r0 & 7);
  const int r1 = s1 >> 3, c1 = (s1 & 7) ^ (r1 & 7);
  const unsigned short* kg_b = KVg + (long)b * KPAD * 1536 + hoff;
  const unsigned short* vt_b = Vt + ((long)b * DD + hoff) * KPAD;

  auto stage = [&](int buf, int t0) {
    gload_lds16(kg_b + (long)(t0 * 64 + r0) * 1536 + c0 * 8, &Kl[buf * 4096 + s0 * 8]);
    gload_lds16(kg_b + (long)(t0 * 64 + r1) * 1536 + c1 * 8, &Kl[buf * 4096 + s1 * 8]);
    gload_lds16(vt_b + (long)r0 * KPAD + t0 * 64 + c0 * 8, &Vl[buf * 4096 + s0 * 8]);
    gload_lds16(vt_b + (long)r1 * KPAD + t0 * 64 + c1 * 8, &Vl[buf * 4096 + s1 * 8]);
  };

  f32x4 oacc[4];
#pragma unroll
  for (int mf = 0; mf < 4; ++mf)
#pragma unroll
    for (int r = 0; r < 4; ++r) oacc[mf][r] = 0.f;
  float m = -3.0e38f, l = 0.f;

  stage(0, 0);
  asm volatile("s_waitcnt vmcnt(0)" ::: "memory");
  __syncthreads();

  for (int t = 0; t < NKT; ++t) {
    int cur = t & 1;
    if (t + 1 < NKT) stage(cur ^ 1, t + 1);

    f32x4 st[4];
#pragma unroll
    for (int kt = 0; kt < 4; ++kt) {
      int row = kt * 16 + fr;
      bf16x8 a0 = *(const bf16x8*)(&Kl[cur * 4096 + (row * 8 + (g ^ (row & 7))) * 8]);
      bf16x8 a1 = *(const bf16x8*)(&Kl[cur * 4096 + (row * 8 + ((4 + g) ^ (row & 7))) * 8]);
      f32x4 z = {0.f, 0.f, 0.f, 0.f};
      z = __builtin_amdgcn_mfma_f32_16x16x32_bf16(a0, bq0, z, 0, 0, 0);
      st[kt] = __builtin_amdgcn_mfma_f32_16x16x32_bf16(a1, bq1, z, 0, 0, 0);
    }

    float tm = -3.0e38f;
#pragma unroll
    for (int kt = 0; kt < 4; ++kt)
#pragma unroll
      for (int r = 0; r < 4; ++r) {
        int key = t * 64 + kt * 16 + g * 4 + r;
        float s = (key < KSEL) ? st[kt][r] * 0.125f : -1.0e30f;
        st[kt][r] = s;
        tm = fmaxf(tm, s);
      }
    tm = fmaxf(tm, __shfl_xor(tm, 16, 64));
    tm = fmaxf(tm, __shfl_xor(tm, 32, 64));
    float newm = fmaxf(m, tm);
    float f = __expf(m - newm);
    float tsum = 0.f;
#pragma unroll
    for (int kt = 0; kt < 4; ++kt)
#pragma unroll
      for (int r = 0; r < 4; ++r) {
        float e = __expf(st[kt][r] - newm);
        st[kt][r] = e;
        tsum += e;
      }
    tsum += __shfl_xor(tsum, 16, 64);
    tsum += __shfl_xor(tsum, 32, 64);
    l = l * f + tsum;
    m = newm;
#pragma unroll
    for (int mf = 0; mf < 4; ++mf)
#pragma unroll
      for (int r = 0; r < 4; ++r) oacc[mf][r] *= f;

    unsigned short* pw = &Pl[w * 1088 + fr * 68 + g * 4];
#pragma unroll
    for (int kt = 0; kt < 4; ++kt) {
      uint2 pk;
      pk.x = (unsigned)f2b(st[kt][0]) | ((unsigned)f2b(st[kt][1]) << 16);
      pk.y = (unsigned)f2b(st[kt][2]) | ((unsigned)f2b(st[kt][3]) << 16);
      *(uint2*)(pw + kt * 16) = pk;
    }

    const unsigned short* prd = &Pl[w * 1088 + fr * 68];
#pragma unroll
    for (int ks2 = 0; ks2 < 2; ++ks2) {
      bf16x8 pf = *(const bf16x8*)(prd + ks2 * 32 + g * 8);
#pragma unroll
      for (int mf = 0; mf < 4; ++mf) {
        int vr = mf * 16 + fr;
        int vc = ks2 * 4 + g;
        bf16x8 vf = *(const bf16x8*)(&Vl[cur * 4096 + (vr * 8 + (vc ^ (vr & 7))) * 8]);
        oacc[mf] = __builtin_amdgcn_mfma_f32_16x16x32_bf16(vf, pf, oacc[mf], 0, 0, 0);
      }
    }

    asm volatile("s_waitcnt vmcnt(0)" ::: "memory");
    __syncthreads();
  }

  float inv = 1.f / l;
  unsigned short* orow = comb + qrow * 2304 + hoff;
#pragma unroll
  for (int mf = 0; mf < 4; ++mf) {
    uint2 pk;
    pk.x = (unsigned)f2b(oacc[mf][0] * inv) | ((unsigned)f2b(oacc[mf][1] * inv) << 16);
    pk.y = (unsigned)f2b(oacc[mf][2] * inv) | ((unsigned)f2b(oacc[mf][3] * inv) << 16);
    *(uint2*)(orow + mf * 16 + g * 4) = pk;
  }
}

__device__ __forceinline__ void attn_win_body(
    const unsigned short* __restrict__ QKV,
    const unsigned short* __restrict__ K8,
    const unsigned short* __restrict__ Vt,
    unsigned short* __restrict__ comb, int brOff,
    int LD, int QO, long VSTR, bool local,
    unsigned short* smem) {
  int tid = threadIdx.x, w = tid >> 6, lane = tid & 63;
  int fr = lane & 15, g = lane >> 4;
  int b = blockIdx.y / HH, h = blockIdx.y % HH, hoff = h * 64;
  int qbase = blockIdx.x * 64 + w * 16;
  long qrow = (long)b * SS + qbase + fr;

  const unsigned short* qptr = QKV + qrow * LD + QO + hoff + g * 8;
  bf16x8 bq0 = *(const bf16x8*)(qptr);
  bf16x8 bq1 = *(const bf16x8*)(qptr + 32);

  int kstart = qbase - 8;
  if (kstart < 0) kstart = 0;
  if (kstart > SS - 32) kstart = SS - 32;

  f32x4 st[2];
  if (local) {
#pragma unroll
    for (int kt = 0; kt < 2; ++kt) {
      const unsigned short* kp =
          QKV + ((long)b * SS + kstart + kt * 16 + fr) * LD + 1536 + hoff + g * 8;
      bf16x8 a0 = *(const bf16x8*)(kp);
      bf16x8 a1 = *(const bf16x8*)(kp + 32);
      f32x4 z = {0.f, 0.f, 0.f, 0.f};
      z = __builtin_amdgcn_mfma_f32_16x16x32_bf16(a0, bq0, z, 0, 0, 0);
      st[kt] = __builtin_amdgcn_mfma_f32_16x16x32_bf16(a1, bq1, z, 0, 0, 0);
    }
  } else {
    const unsigned short* kp = K8 + ((long)b * 16 + fr) * DD + hoff + g * 8;
    bf16x8 a0 = *(const bf16x8*)(kp);
    bf16x8 a1 = *(const bf16x8*)(kp + 32);
    f32x4 z = {0.f, 0.f, 0.f, 0.f};
    z = __builtin_amdgcn_mfma_f32_16x16x32_bf16(a0, bq0, z, 0, 0, 0);
    st[0] = __builtin_amdgcn_mfma_f32_16x16x32_bf16(a1, bq1, z, 0, 0, 0);
    st[1] = f32x4{0.f, 0.f, 0.f, 0.f};
  }

  float m = -3.0e38f;
#pragma unroll
  for (int kt = 0; kt < 2; ++kt)
#pragma unroll
    for (int r = 0; r < 4; ++r) {
      int idx = kt * 16 + g * 4 + r;
      bool valid;
      if (local) {
        int rel = kstart + idx - qbase - fr;
        valid = (rel >= -8) && (rel <= 8);
      } else {
        valid = (idx < 8);
      }
      float s = valid ? st[kt][r] * 0.125f : -1.0e30f;
      st[kt][r] = s;
      m = fmaxf(m, s);
    }
  m = fmaxf(m, __shfl_xor(m, 16, 64));
  m = fmaxf(m, __shfl_xor(m, 32, 64));

  float lsum = 0.f;
#pragma unroll
  for (int kt = 0; kt < 2; ++kt)
#pragma unroll
    for (int r = 0; r < 4; ++r) {
      float e = __expf(st[kt][r] - m);
      st[kt][r] = e;
      lsum += e;
    }
  lsum += __shfl_xor(lsum, 16, 64);
  lsum += __shfl_xor(lsum, 32, 64);

  unsigned short* pl = smem + w * 640 + fr * 40 + g * 4;
#pragma unroll
  for (int kt = 0; kt < 2; ++kt) {
    uint2 pk;
    pk.x = (unsigned)f2b(st[kt][0]) | ((unsigned)f2b(st[kt][1]) << 16);
    pk.y = (unsigned)f2b(st[kt][2]) | ((unsigned)f2b(st[kt][3]) << 16);
    *(uint2*)(pl + kt * 16) = pk;
  }

  f32x4 oacc[4];
#pragma unroll
  for (int mf = 0; mf < 4; ++mf)
#pragma unroll
    for (int r = 0; r < 4; ++r) oacc[mf][r] = 0.f;

  const unsigned short* pr = smem + w * 640 + fr * 40 + g * 8;
  bf16x8 pf = *(const bf16x8*)(pr);
  long kb2 = local ? kstart : 0;
#pragma unroll
  for (int mf = 0; mf < 4; ++mf) {
    const unsigned short* vp =
        Vt + ((long)b * DD + hoff + mf * 16 + fr) * VSTR + kb2 + g * 8;
    bf16x8 vf = *(const bf16x8*)(vp);
    oacc[mf] = __builtin_amdgcn_mfma_f32_16x16x32_bf16(vf, pf, oacc[mf], 0, 0, 0);
  }

  float inv = 1.f / lsum;
  unsigned short* orow = comb + qrow * 2304 + brOff + hoff;
#pragma unroll
  for (int mf = 0; mf < 4; ++mf) {
    uint2 pk;
    pk.x = (unsigned)f2b(oacc[mf][0] * inv) | ((unsigned)f2b(oacc[mf][1] * inv) << 16);
    pk.y = (unsigned)f2b(oacc[mf][2] * inv) | ((unsigned)f2b(oacc[mf][3] * inv) << 16);
    *(uint2*)(orow + mf * 16 + g * 4) = pk;
  }
}

// ---------------- merged attention dispatch (z: 0=global 1=local 2=temporal)
__global__ __launch_bounds__(256) void attn_all(
    const unsigned short* __restrict__ QKV4,
    const unsigned short* __restrict__ KVg,
    const unsigned short* __restrict__ Vt,
    const unsigned short* __restrict__ Qt,
    const unsigned short* __restrict__ K8,
    const unsigned short* __restrict__ Vt8,
    const unsigned short* __restrict__ Vtl,
    unsigned short* __restrict__ comb) {
  __shared__ unsigned short smem[20736];
  int z = blockIdx.z;
  if (z == 0) {
    attn_flash_body(QKV4, KVg, Vt, comb, smem);
  } else if (z == 1) {
    attn_win_body(QKV4, nullptr, Vtl, comb, 768, 3072, 768, SS, true, smem);
  } else {
    attn_win_body(Qt, K8, Vt8, comb, 1536, 768, 0, 32, false, smem);
  }
}

// ---------------- in-place layernorm + gate scale on comb (bf16) ------------
__global__ __launch_bounds__(256) void ln_gate_inplace(
    unsigned short* __restrict__ comb,
    const float* __restrict__ gg, const float* __restrict__ gb,
    const float* __restrict__ lgam, const float* __restrict__ lbet,
    const float* __restrict__ tg, const float* __restrict__ tb,
    const float* __restrict__ fw) {
  int row = blockIdx.x;
  int b = row >> 11;
  int tid = threadIdx.x;
  __shared__ float red[8];
  const float* gams[3] = {gg, lgam, tg};
  const float* bets[3] = {gb, lbet, tb};
#pragma unroll
  for (int br = 0; br < 3; ++br) {
    unsigned short* p = comb + (long)row * 2304 + br * DD;
    float x0 = b2f(p[tid]), x1 = b2f(p[tid + 256]), x2 = b2f(p[tid + 512]);
    float s = x0 + x1 + x2;
    float ss = x0 * x0 + x1 * x1 + x2 * x2;
#pragma unroll
    for (int msk = 1; msk < 64; msk <<= 1) {
      s += __shfl_xor(s, msk, 64);
      ss += __shfl_xor(ss, msk, 64);
    }
    int wv = tid >> 6, lane = tid & 63;
    if (lane == 0) { red[wv] = s; red[4 + wv] = ss; }
    __syncthreads();
    float S4 = red[0] + red[1] + red[2] + red[3];
    float SQ = red[4] + red[5] + red[6] + red[7];
    float mean = S4 * (1.f / (float)DD);
    float var = SQ * (1.f / (float)DD) - mean * mean;
    float rs = rsqrtf(var + 1e-5f);
    float gate = fw[b * 3 + br];
    const float* gam = gams[br];
    const float* bet = bets[br];
    p[tid]       = f2b(((x0 - mean) * rs * gam[tid]       + bet[tid])       * gate);
    p[tid + 256] = f2b(((x1 - mean) * rs * gam[tid + 256] + bet[tid + 256]) * gate);
    p[tid + 512] = f2b(((x2 - mean) * rs * gam[tid + 512] + bet[tid + 512]) * gate);
    __syncthreads();
  }
}

// ---------------- launcher ---------------------------------------------------
extern "C" void kernel_launch(void* const* d_in, const int* in_sizes, int n_in,
                              void* d_out, int out_size, void* d_ws, size_t ws_size,
                              hipStream_t stream) {
  const float* x        = (const float*)d_in[0];
  const float* wgq      = (const float*)d_in[1];
  const float* wgk      = (const float*)d_in[2];
  const float* wgv      = (const float*)d_in[3];
  const float* wlq      = (const float*)d_in[4];
  const float* wlk      = (const float*)d_in[5];
  const float* wlv      = (const float*)d_in[6];
  const float* wtq      = (const float*)d_in[7];
  const float* wtk      = (const float*)d_in[8];
  const float* wtv      = (const float*)d_in[9];
  const float* w_out    = (const float*)d_in[10];
  const float* b_out    = (const float*)d_in[11];
  const float* w_gate   = (const float*)d_in[12];
  const float* b_gate   = (const float*)d_in[13];
  const float* w_sparse = (const float*)d_in[14];
  const float* b_sparse = (const float*)d_in[15];
  const float* g_gamma  = (const float*)d_in[16];
  const float* g_beta   = (const float*)d_in[17];
  const float* l_gamma  = (const float*)d_in[18];
  const float* l_beta   = (const float*)d_in[19];
  const float* t_gamma  = (const float*)d_in[20];
  const float* t_beta   = (const float*)d_in[21];
  float* outp = (float*)d_out;

  unsigned short* xb    = (unsigned short*)d_ws;
  unsigned short* xpb   = xb    + (long)NTOK * DD;
  unsigned short* WTx4  = xpb   + (long)NTOK * DD;        // [3072][768]
  unsigned short* WTkv  = WTx4  + (long)3072 * DD;        // [1536][768]
  unsigned short* WTqt  = WTkv  + (long)1536 * DD;        // [768][768]
  unsigned short* WTtkv = WTqt  + (long)DD * DD;          // [1536][768]
  unsigned short* WTo   = WTtkv + (long)1536 * DD;        // [768][2304]
  unsigned short* QKV4  = WTo   + (long)DD * 2304;        // [4096][3072]
  unsigned short* Qt    = QKV4  + (long)NTOK * 3072;      // [4096][768]
  unsigned short* A_sel = Qt    + (long)NTOK * DD;        // [896][768]
  unsigned short* KVg   = A_sel + (long)BB * KPAD * DD;   // [896][1536]
  unsigned short* A_t8  = KVg   + (long)BB * KPAD * 1536; // [128][768]
  unsigned short* K8    = A_t8  + (long)128 * DD;         // [2][16][768]
  unsigned short* Vt8   = K8    + (long)BB * 16 * DD;     // [2][768][32]
  unsigned short* Vt    = Vt8   + (long)BB * DD * 32;     // [2][768][448]
  unsigned short* Vtl   = Vt    + (long)BB * DD * KPAD;   // [2][768][2048]
  unsigned short* comb  = Vtl   + (long)BB * DD * SS;     // [4096][2304]
  float* Cpart   = (float*)(comb + (long)NTOK * 2304);    // [3][4096][768]
  float* imp     = Cpart + 3L * NTOK * DD;
  float* partial = imp + NTOK;
  float* fw      = partial + 32 * DD;
  int*   sel     = (int*)(fw + 8);

  prep_imp<<<SS, 256, 0, stream>>>(x, w_sparse, b_sparse, xb, xpb, imp);
  transpose_all<<<6912, dim3(32, 8), 0, stream>>>(
      wgq, wgk, wgv, wlq, wlk, wlv, wtq, wtk, wtv, w_out,
      WTx4, WTkv, WTqt, WTtkv, WTo);
  topk_kernel<<<BB, 1024, 0, stream>>>(imp, sel);
  gate1<<<dim3(16, BB), 256, 0, stream>>>(xb, partial);
  gate2<<<BB, 256, 0, stream>>>(partial, w_gate, b_gate, fw);

  gather_pre<<<BB * KPAD + 128, 192, 0, stream>>>(xb, xpb, sel, A_sel, A_t8);
  gemm_multi<<<1056, 256, 0, stream>>>(xb, WTx4, QKV4, A_sel, WTkv, KVg,
                                       xpb, WTqt, Qt, A_t8, WTtkv,
                                       K8, Vt8, Vt, Vtl);

  attn_all<<<dim3(32, BB * HH, 3), 256, 0, stream>>>(QKV4, KVg, Vt, Qt, K8, Vt8,
                                                     Vtl, comb);

  ln_gate_inplace<<<NTOK, 256, 0, stream>>>(comb, g_gamma, g_beta,
                                            l_gamma, l_beta, t_gamma, t_beta, fw);
  gemm_final_sk<<<dim3(6, 32, 3), 256, 0, stream>>>(comb, WTo, Cpart);
  reduce_out<<<NTOK * DD / 4 / 256, 256, 0, stream>>>(Cpart, b_out, outp);
}

// Round 13
// 171.978 us; speedup vs baseline: 1.6337x; 1.1830x over previous
//
#include <hip/hip_runtime.h>
#include <cstdint>

// Problem constants
constexpr int BB   = 2;
constexpr int SS   = 2048;
constexpr int DD   = 768;
constexpr int HH   = 12;
constexpr int NTOK = BB * SS;          // 4096
constexpr int KSEL = 409;              // int((1-0.8)*2048)
constexpr int KPAD = 448;              // 7 kv-tiles of 64
constexpr int NKT  = 7;                // kv tiles of 64 keys

typedef __bf16 bf16x8 __attribute__((ext_vector_type(8)));
typedef float  f32x4  __attribute__((ext_vector_type(4)));

__device__ __forceinline__ float b2f(unsigned short u) {
  return __uint_as_float(((unsigned)u) << 16);
}
__device__ __forceinline__ unsigned short f2b(float f) {
  unsigned u = __float_as_uint(f);
  u += 0x7fffu + ((u >> 16) & 1u);   // RNE
  return (unsigned short)(u >> 16);
}
__device__ __forceinline__ unsigned long long shfl_xor_u64(unsigned long long v, int m) {
  unsigned lo = (unsigned)v, hi = (unsigned)(v >> 32);
  lo = __shfl_xor(lo, m, 64);
  hi = __shfl_xor(hi, m, 64);
  return ((unsigned long long)hi << 32) | lo;
}

__device__ __forceinline__ void gload_lds16(const void* gsrc, void* ldst) {
  __builtin_amdgcn_global_load_lds(
      (__attribute__((address_space(1))) void*)(gsrc),
      (__attribute__((address_space(3))) void*)(ldst), 16, 0, 0);
}

// ------- mega_pre: prep_imp (2048) | weight transpose (6912) | gate1 (32) ---
__global__ __launch_bounds__(256) void mega_pre(
    const float* __restrict__ x, const float* __restrict__ wsp,
    const float* __restrict__ bsp,
    unsigned short* __restrict__ xb, unsigned short* __restrict__ xpb,
    float* __restrict__ imp,
    const float* w0, const float* w1, const float* w2, const float* w3,
    const float* w4, const float* w5, const float* w6, const float* w7,
    const float* w8, const float* w9,
    unsigned short* __restrict__ WTx4, unsigned short* __restrict__ WTkv,
    unsigned short* __restrict__ WTqt, unsigned short* __restrict__ WTtkv,
    unsigned short* __restrict__ WTo,
    float* __restrict__ partial) {
  __shared__ float tile[32][33];
  int id = blockIdx.x;
  int tid = threadIdx.x;

  if (id < SS) {
    // ---- prep_imp: PE shared across both batches (same srow) ----
    int srow = id;
    const float* xr0 = x + (long)srow * DD;
    const float* xr1 = x + (long)(SS + srow) * DD;
    float acc0 = 0.f, acc1 = 0.f;
#pragma unroll
    for (int k = 0; k < 3; ++k) {
      int c = tid + k * 256;
      int j2 = c & ~1;
      float freq = __expf((float)j2 * -0.011992630692677323f);
      float ang = (float)srow * freq;
      float pe = (c & 1) ? cosf(ang) : sinf(ang);
      float w = wsp[c];
      float x0 = xr0[c], x1 = xr1[c];
      xb[(long)srow * DD + c]        = f2b(x0);
      xb[(long)(SS + srow) * DD + c] = f2b(x1);
      xpb[(long)srow * DD + c]        = f2b(x0 + pe);
      xpb[(long)(SS + srow) * DD + c] = f2b(x1 + pe);
      acc0 += x0 * w;
      acc1 += x1 * w;
    }
#pragma unroll
    for (int m = 1; m < 64; m <<= 1) {
      acc0 += __shfl_xor(acc0, m, 64);
      acc1 += __shfl_xor(acc1, m, 64);
    }
    __shared__ float red[8];
    int wv = tid >> 6, lane = tid & 63;
    if (lane == 0) { red[wv] = acc0; red[4 + wv] = acc1; }
    __syncthreads();
    if (tid == 0) {
      imp[srow]      = red[0] + red[1] + red[2] + red[3] + bsp[0];
      imp[SS + srow] = red[4] + red[5] + red[6] + red[7] + bsp[0];
    }
  } else if (id < SS + 6912) {
    // ---- weight transpose ----
    int tidx = id - SS;
    int z, bx, by;
    if (tidx < 5184) { z = tidx / 576; int rem = tidx % 576; by = rem / 24; bx = rem % 24; }
    else             { z = 9; int rem = tidx - 5184; by = rem / 24; bx = rem % 24; }
    const float* srcs[10] = {w0, w1, w2, w3, w4, w5, w6, w7, w8, w9};
    const float* src = srcs[z];
    unsigned short* dst;
    int R = DD;
    switch (z) {
      case 0: dst = WTx4;                       break;
      case 1: dst = WTkv;                       break;
      case 2: dst = WTkv + (long)DD * DD;       break;
      case 3: dst = WTx4 + (long)DD * DD;       break;
      case 4: dst = WTx4 + (long)2 * DD * DD;   break;
      case 5: dst = WTx4 + (long)3 * DD * DD;   break;
      case 6: dst = WTqt;                       break;
      case 7: dst = WTtkv;                      break;
      case 8: dst = WTtkv + (long)DD * DD;      break;
      default: dst = WTo; R = 2304;             break;
    }
    int r0 = by * 32, c0 = bx * 32;
    int tx = tid & 31, ty = tid >> 5;
    for (int i = ty; i < 32; i += 8) tile[i][tx] = src[(long)(r0 + i) * DD + c0 + tx];
    __syncthreads();
    for (int i = ty; i < 32; i += 8) dst[(long)(c0 + i) * R + r0 + tx] = f2b(tile[tx][i]);
  } else {
    // ---- gate1 partial sums from f32 x (independent of xb) ----
    int rem = id - SS - 6912;            // 0..31
    int chunk = rem & 15, b = rem >> 4;
    for (int c = tid; c < DD; c += 256) {
      const float* xp = x + ((long)(b * SS + chunk * 128)) * DD + c;
      float acc = 0.f;
      for (int s2 = 0; s2 < 128; ++s2) acc += xp[(long)s2 * DD];
      partial[(long)(b * 16 + chunk) * DD + c] = acc;
    }
  }
}

// ------- topk (blocks 0..1) + gate2 (blocks 2..3) ---------------------------
__global__ __launch_bounds__(1024) void topk_gate2(
    const float* __restrict__ imp, int* __restrict__ sel,
    const float* __restrict__ partial, const float* __restrict__ w_gate,
    const float* __restrict__ b_gate, float* __restrict__ fw) {
  int tid = threadIdx.x;
  if (blockIdx.x < 2) {
    // hybrid bitonic sort (value desc, index asc): j>=64 in LDS, j<=32 in regs
    __shared__ unsigned long long keys[SS];
    int b = blockIdx.x;
    for (int i = tid; i < SS; i += 1024) {
      float v = imp[b * SS + i];
      unsigned u = __float_as_uint(v);
      u = (u & 0x80000000u) ? ~u : (u | 0x80000000u);
      unsigned du = ~u;
      keys[i] = ((unsigned long long)du << 32) | (unsigned)i;
    }
    __syncthreads();
    for (int k = 2; k <= SS; k <<= 1) {
      for (int j = k >> 1; j >= 64; j >>= 1) {
        for (int i = tid; i < SS; i += 1024) {
          int p = i ^ j;
          if (p > i) {
            unsigned long long a = keys[i], bb = keys[p];
            bool up = ((i & k) == 0);
            if ((a > bb) == up) { keys[i] = bb; keys[p] = a; }
          }
        }
        __syncthreads();
      }
      unsigned long long k0 = keys[tid], k1 = keys[tid + 1024];
      bool up0 = ((tid & k) == 0);
      bool up1 = (((tid + 1024) & k) == 0);
      int j0 = (k >> 1) < 32 ? (k >> 1) : 32;
      for (int j = j0; j >= 1; j >>= 1) {
        bool low = ((tid & j) == 0);
        unsigned long long p0 = shfl_xor_u64(k0, j);
        k0 = ((low == up0) == (k0 < p0)) ? k0 : p0;
        unsigned long long p1 = shfl_xor_u64(k1, j);
        k1 = ((low == up1) == (k1 < p1)) ? k1 : p1;
      }
      keys[tid] = k0; keys[tid + 1024] = k1;
      __syncthreads();
    }
    for (int i = tid; i < KSEL; i += 1024) sel[b * KSEL + i] = (int)(keys[i] & 0xffffffffu);
  } else {
    // gate2
    __shared__ float meanbuf[DD];
    __shared__ float lg[3];
    int b = blockIdx.x - 2;
    if (tid < DD) {
      float acc = 0.f;
      for (int p = 0; p < 16; ++p) acc += partial[(long)(b * 16 + p) * DD + tid];
      meanbuf[tid] = acc * (1.0f / (float)SS);
    }
    __syncthreads();
    if (tid < 3) {
      float acc = b_gate[tid];
      for (int d = 0; d < DD; ++d) acc += meanbuf[d] * w_gate[d * 3 + tid];
      lg[tid] = acc;
    }
    __syncthreads();
    if (tid == 0) {
      float mx = fmaxf(lg[0], fmaxf(lg[1], lg[2]));
      float e0 = expf(lg[0] - mx), e1 = expf(lg[1] - mx), e2 = expf(lg[2] - mx);
      float inv = 1.f / (e0 + e1 + e2);
      fw[b * 3 + 0] = e0 * inv; fw[b * 3 + 1] = e1 * inv; fw[b * 3 + 2] = e2 * inv;
    }
  }
}

// ---------------- fused projection GEMMs (all K=768, 128x128 tiles) ---------
// tiles: QKV4 768 | KVg 84 | Qt 192 | T8 12 => 1056 (8*132, bijective swz).
// KVg tiles gather A rows through sel[] at staging time (per-lane global src);
// T8 tiles map to the 16 temporal xpb rows (clamped; extra rows unused).
// V-region tiles write transposed consumer buffers directly from acc.
__global__ __launch_bounds__(256) void gemm_multi(
    const unsigned short* __restrict__ xb,    const unsigned short* __restrict__ WTx4,
    unsigned short* __restrict__ QKV4,
    const unsigned short* __restrict__ WTkv,  unsigned short* __restrict__ KVg,
    const unsigned short* __restrict__ xpb,   const unsigned short* __restrict__ WTqt,
    unsigned short* __restrict__ Qt,
    const unsigned short* __restrict__ WTtkv,
    const int* __restrict__ sel,
    unsigned short* __restrict__ K8, unsigned short* __restrict__ Vt8,
    unsigned short* __restrict__ Vt, unsigned short* __restrict__ Vtl) {
  __shared__ unsigned short AsB[2][4096];
  __shared__ unsigned short BsB[2][4096];
  constexpr int K = DD;
  const int tid = threadIdx.x;
  const int lane = tid & 63;
  const int wv = tid >> 6;
  const int wr = wv >> 1, wc = wv & 1;

  int lin = blockIdx.x;
  int swz = (lin & 7) * 132 + (lin >> 3);
  const unsigned short* BT;
  int ntx, tile, region;
  if (swz < 768)       { BT = WTx4;  ntx = 24; tile = swz;        region = 0; }
  else if (swz < 852)  { BT = WTkv;  ntx = 12; tile = swz - 768;  region = 1; }
  else if (swz < 1044) { BT = WTqt;  ntx = 6;  tile = swz - 852;  region = 2; }
  else                 { BT = WTtkv; ntx = 12; tile = swz - 1044; region = 3; }
  const long rowBase = (long)(tile / ntx) * 128;
  const long colBase = (long)(tile % ntx) * 128;

  // A-row resolver (indirection for KVg / T8 regions)
  auto arow = [&](int r) -> const unsigned short* {
    long grow = rowBase + r;
    if (region == 0) return xb + grow * (long)K;
    if (region == 2) return xpb + grow * (long)K;
    if (region == 1) {
      int bb2 = (int)(grow / KPAD), j = (int)(grow % KPAD);
      int srow = (j < KSEL) ? sel[bb2 * KSEL + j] : 0;
      return xb + ((long)bb2 * SS + srow) * (long)K;
    }
    if (grow < 16) {
      int bb2 = (int)grow >> 3, j = ((int)grow & 7) * 256;
      return xpb + ((long)bb2 * SS + j) * (long)K;
    }
    return xpb;   // rows >=16 in T8 region are never stored
  };

  f32x4 acc[4][4];
#pragma unroll
  for (int i = 0; i < 4; ++i)
#pragma unroll
    for (int j = 0; j < 4; ++j)
#pragma unroll
      for (int r = 0; r < 4; ++r) acc[i][j][r] = 0.f;

  const int g0 = tid, g1 = tid + 256;
  const int r0 = g0 >> 2, k80 = (g0 & 3) ^ ((r0 >> 1) & 3);
  const int r1 = g1 >> 2, k81 = (g1 & 3) ^ ((r1 >> 1) & 3);
  const unsigned short* ga0 = arow(r0) + k80 * 8;
  const unsigned short* ga1 = arow(r1) + k81 * 8;
  const unsigned short* gb0 = BT + (colBase + r0) * (long)K + k80 * 8;
  const unsigned short* gb1 = BT + (colBase + r1) * (long)K + k81 * 8;

  const int k8 = lane >> 4;
  const int fr = lane & 15;
  int aoff[4], boff[4];
#pragma unroll
  for (int i = 0; i < 4; ++i) {
    int rowA = wr * 64 + i * 16 + fr;
    aoff[i] = (rowA * 4 + (k8 ^ ((rowA >> 1) & 3))) * 8;
    int rowB = wc * 64 + i * 16 + fr;
    boff[i] = (rowB * 4 + (k8 ^ ((rowB >> 1) & 3))) * 8;
  }

  auto stage = [&](int buf, int t) {
    int ko = t * 32;
    gload_lds16(ga0 + ko, &AsB[buf][g0 * 8]);
    gload_lds16(ga1 + ko, &AsB[buf][g1 * 8]);
    gload_lds16(gb0 + ko, &BsB[buf][g0 * 8]);
    gload_lds16(gb1 + ko, &BsB[buf][g1 * 8]);
  };

  constexpr int nk = K >> 5;   // 24
  stage(0, 0);
  __syncthreads();
  for (int t = 0; t < nk; ++t) {
    int cur = t & 1;
    if (t + 1 < nk) stage(cur ^ 1, t + 1);
    bf16x8 af[4], bfr[4];
#pragma unroll
    for (int i = 0; i < 4; ++i) af[i] = *(const bf16x8*)(&AsB[cur][aoff[i]]);
#pragma unroll
    for (int i = 0; i < 4; ++i) bfr[i] = *(const bf16x8*)(&BsB[cur][boff[i]]);
#pragma unroll
    for (int mi = 0; mi < 4; ++mi)
#pragma unroll
      for (int ni = 0; ni < 4; ++ni)
        acc[mi][ni] = __builtin_amdgcn_mfma_f32_16x16x32_bf16(af[mi], bfr[ni], acc[mi][ni], 0, 0, 0);
    __syncthreads();
  }

  // epilogue
  int mode, vcol0 = 0, N = 0;
  unsigned short* C = nullptr;
  if (region == 0)      { mode = (colBase >= 2304) ? 1 : 0; C = QKV4; N = 3072;
                          vcol0 = (int)colBase - 2304; }
  else if (region == 1) { mode = (colBase >= 768) ? 2 : 0;  C = KVg;  N = 1536;
                          vcol0 = (int)colBase - 768; }
  else if (region == 2) { mode = 0; C = Qt; N = 768; }
  else                  { mode = (colBase >= 768) ? 4 : 3;
                          vcol0 = (int)colBase - 768; }

  const int orow0 = (lane >> 4) * 4;
  if (mode == 0) {
#pragma unroll
    for (int mi = 0; mi < 4; ++mi) {
      long gr = rowBase + wr * 64 + mi * 16 + orow0;
#pragma unroll
      for (int ni = 0; ni < 4; ++ni) {
        long gc = colBase + wc * 64 + ni * 16 + fr;
#pragma unroll
        for (int r = 0; r < 4; ++r)
          C[(gr + r) * (long)N + gc] = f2b(acc[mi][ni][r]);
      }
    }
  } else {
#pragma unroll
    for (int mi = 0; mi < 4; ++mi) {
      int lr = wr * 64 + mi * 16 + orow0;
      int grow = (int)rowBase + lr;
#pragma unroll
      for (int ni = 0; ni < 4; ++ni) {
        int lc = wc * 64 + ni * 16 + fr;
        uint2 pk;
        pk.x = (unsigned)f2b(acc[mi][ni][0]) | ((unsigned)f2b(acc[mi][ni][1]) << 16);
        pk.y = (unsigned)f2b(acc[mi][ni][2]) | ((unsigned)f2b(acc[mi][ni][3]) << 16);
        if (mode == 1) {         // QKV4 v_l -> Vtl[b][c][s]
          int bb2 = grow >> 11, s = grow & (SS - 1);
          *(uint2*)(Vtl + ((long)bb2 * DD + vcol0 + lc) * SS + s) = pk;
        } else if (mode == 2) {  // KVg v -> Vt[b][c][j]
          int bb2 = grow / KPAD, j = grow - bb2 * KPAD;
          *(uint2*)(Vt + ((long)bb2 * DD + vcol0 + lc) * KPAD + j) = pk;
        } else if (mode == 3) {  // T8 k -> K8[b][16][768] rows 0..7 per b
          if (grow < 16) {
#pragma unroll
            for (int r = 0; r < 4; ++r) {
              int g2 = grow + r;
              K8[((long)(g2 >> 3) * 16 + (g2 & 7)) * DD + colBase + lc] =
                  f2b(acc[mi][ni][r]);
            }
          }
        } else {                 // mode 4: T8 v -> Vt8[b][c][32] j 0..7
          if (grow < 16) {
            *(uint2*)(Vt8 + ((long)(grow >> 3) * DD + vcol0 + lc) * 32 + (grow & 7)) = pk;
          }
        }
      }
    }
    if (mode == 3) {             // zero K8 rows jj=8..15, both b
      int row16 = tid >> 4, cg = tid & 15;
      int bb2 = row16 >> 3, jj = 8 + (row16 & 7);
      uint4 z4 = {0u, 0u, 0u, 0u};
      *(uint4*)(K8 + ((long)bb2 * 16 + jj) * DD + colBase + cg * 8) = z4;
    }
    if (mode == 4) {             // zero Vt8 j=8..31, both b
#pragma unroll
      for (int e = 0; e < 6; ++e) {
        int id = tid + e * 256;
        int bb2 = id / 768, rem = id % 768;
        int c = rem / 6, ch = rem % 6;
        *(uint2*)(Vt8 + ((long)bb2 * DD + vcol0 + c) * 32 + 8 + ch * 4) = uint2{0u, 0u};
      }
    }
  }
}

// ---------------- final GEMM, split-K=3 into f32 partials -------------------
__global__ __launch_bounds__(256) void gemm_final_sk(const unsigned short* __restrict__ A,
                                                     const unsigned short* __restrict__ BT,
                                                     float* __restrict__ Cpart) {
  __shared__ unsigned short As[2][128 * 32];
  __shared__ unsigned short Bs[2][128 * 32];
  constexpr int N = 768, K = 2304, CK = 768;
  const int tid = threadIdx.x;
  const int lane = tid & 63;
  const int wv = tid >> 6;
  const int wr = wv >> 1, wc = wv & 1;
  const int z = blockIdx.z;

  int lin = blockIdx.y * gridDim.x + blockIdx.x;   // 192 blocks/plane
  int swz = (lin & 7) * 24 + (lin >> 3);
  const long rowBase = (long)(swz / 6) * 128;
  const long colBase = (long)(swz % 6) * 128;

  f32x4 acc[4][4];
#pragma unroll
  for (int i = 0; i < 4; ++i)
#pragma unroll
    for (int j = 0; j < 4; ++j)
#pragma unroll
      for (int r = 0; r < 4; ++r) acc[i][j][r] = 0.f;

  const int g0 = tid, g1 = tid + 256;
  const int r0 = g0 >> 2, k80 = (g0 & 3) ^ ((r0 >> 1) & 3);
  const int r1 = g1 >> 2, k81 = (g1 & 3) ^ ((r1 >> 1) & 3);
  const unsigned short* ga0 = A + (rowBase + r0) * (long)K + z * CK + k80 * 8;
  const unsigned short* ga1 = A + (rowBase + r1) * (long)K + z * CK + k81 * 8;
  const unsigned short* gb0 = BT + (colBase + r0) * (long)K + z * CK + k80 * 8;
  const unsigned short* gb1 = BT + (colBase + r1) * (long)K + z * CK + k81 * 8;

  const int k8 = lane >> 4;
  const int fr = lane & 15;
  int aoff[4], boff[4];
#pragma unroll
  for (int i = 0; i < 4; ++i) {
    int rowA = wr * 64 + i * 16 + fr;
    aoff[i] = (rowA * 4 + (k8 ^ ((rowA >> 1) & 3))) * 8;
    int rowB = wc * 64 + i * 16 + fr;
    boff[i] = (rowB * 4 + (k8 ^ ((rowB >> 1) & 3))) * 8;
  }

  auto stage = [&](int buf, int t) {
    int ko = t * 32;
    gload_lds16(ga0 + ko, &As[buf][g0 * 8]);
    gload_lds16(ga1 + ko, &As[buf][g1 * 8]);
    gload_lds16(gb0 + ko, &Bs[buf][g0 * 8]);
    gload_lds16(gb1 + ko, &Bs[buf][g1 * 8]);
  };

  constexpr int nk = CK >> 5;   // 24
  stage(0, 0);
  __syncthreads();
  for (int t = 0; t < nk; ++t) {
    int cur = t & 1;
    if (t + 1 < nk) stage(cur ^ 1, t + 1);
    bf16x8 af[4], bfr[4];
#pragma unroll
    for (int i = 0; i < 4; ++i) af[i] = *(const bf16x8*)(&As[cur][aoff[i]]);
#pragma unroll
    for (int i = 0; i < 4; ++i) bfr[i] = *(const bf16x8*)(&Bs[cur][boff[i]]);
#pragma unroll
    for (int mi = 0; mi < 4; ++mi)
#pragma unroll
      for (int ni = 0; ni < 4; ++ni)
        acc[mi][ni] = __builtin_amdgcn_mfma_f32_16x16x32_bf16(af[mi], bfr[ni], acc[mi][ni], 0, 0, 0);
    __syncthreads();
  }

  float* Cz = Cpart + (long)z * NTOK * DD;
  const int orow0 = (lane >> 4) * 4;
#pragma unroll
  for (int mi = 0; mi < 4; ++mi) {
    long gr = rowBase + wr * 64 + mi * 16 + orow0;
#pragma unroll
    for (int ni = 0; ni < 4; ++ni) {
      long gc = colBase + wc * 64 + ni * 16 + fr;
#pragma unroll
      for (int r = 0; r < 4; ++r)
        Cz[(gr + r) * (long)N + gc] = acc[mi][ni][r];
    }
  }
}

// ---------------- reduce split-K partials + bias -> d_out -------------------
__global__ __launch_bounds__(256) void reduce_out(const float* __restrict__ P,
                                                  const float* __restrict__ bias,
                                                  float* __restrict__ out) {
  long i = (long)blockIdx.x * 256 + threadIdx.x;   // over NTOK*DD/4 f32x4
  const f32x4* p0 = (const f32x4*)P;
  const f32x4* p1 = (const f32x4*)(P + (long)NTOK * DD);
  const f32x4* p2 = (const f32x4*)(P + 2L * NTOK * DD);
  f32x4 v = p0[i];
  v += p1[i];
  v += p2[i];
  int c4 = (int)(i % (DD / 4));
  v += *(const f32x4*)(bias + c4 * 4);
  ((f32x4*)out)[i] = v;
}

// ---------------- attention bodies (bf16 output into comb layout) -----------
__device__ __forceinline__ void attn_flash_body(
    const unsigned short* __restrict__ QKV4,  // [4096][3072]
    const unsigned short* __restrict__ KVg,   // [b*448][1536]
    const unsigned short* __restrict__ Vt,    // [b][768][448]
    unsigned short* __restrict__ comb,        // [4096][2304], br 0
    unsigned short* smem) {
  unsigned short* Kl = smem;            // [2][64*64]
  unsigned short* Vl = smem + 8192;     // [2][64*64]
  unsigned short* Pl = smem + 16384;    // [4][16*68]
  int tid = threadIdx.x, w = tid >> 6, lane = tid & 63;
  int fr = lane & 15, g = lane >> 4;
  int b = blockIdx.y / HH, h = blockIdx.y % HH, hoff = h * 64;
  int qbase = blockIdx.x * 64 + w * 16;
  long qrow = (long)b * SS + qbase + fr;

  const unsigned short* qptr = QKV4 + qrow * 3072 + hoff + g * 8;
  bf16x8 bq0 = *(const bf16x8*)(qptr);
  bf16x8 bq1 = *(const bf16x8*)(qptr + 32);

  const int s0 = tid, s1 = tid + 256;
  const int r0 = s0 >> 3, c0 = (s0 & 7) ^ (r0 & 7);
  const int r1 = s1 >> 3, c1 = (s1 & 7) ^ (r1 & 7);
  const unsigned short* kg_b = KVg + (long)b * KPAD * 1536 + hoff;
  const unsigned short* vt_b = Vt + ((long)b * DD + hoff) * KPAD;

  auto stage = [&](int buf, int t0) {
    gload_lds16(kg_b + (long)(t0 * 64 + r0) * 1536 + c0 * 8, &Kl[buf * 4096 + s0 * 8]);
    gload_lds16(kg_b + (long)(t0 * 64 + r1) * 1536 + c1 * 8, &Kl[buf * 4096 + s1 * 8]);
    gload_lds16(vt_b + (long)r0 * KPAD + t0 * 64 + c0 * 8, &Vl[buf * 4096 + s0 * 8]);
    gload_lds16(vt_b + (long)r1 * KPAD + t0 * 64 + c1 * 8, &Vl[buf * 4096 + s1 * 8]);
  };

  f32x4 oacc[4];
#pragma unroll
  for (int mf = 0; mf < 4; ++mf)
#pragma unroll
    for (int r = 0; r < 4; ++r) oacc[mf][r] = 0.f;
  float m = -3.0e38f, l = 0.f;

  stage(0, 0);
  asm volatile("s_waitcnt vmcnt(0)" ::: "memory");
  __syncthreads();

  for (int t = 0; t < NKT; ++t) {
    int cur = t & 1;
    if (t + 1 < NKT) stage(cur ^ 1, t + 1);

    f32x4 st[4];
#pragma unroll
    for (int kt = 0; kt < 4; ++kt) {
      int row = kt * 16 + fr;
      bf16x8 a0 = *(const bf16x8*)(&Kl[cur * 4096 + (row * 8 + (g ^ (row & 7))) * 8]);
      bf16x8 a1 = *(const bf16x8*)(&Kl[cur * 4096 + (row * 8 + ((4 + g) ^ (row & 7))) * 8]);
      f32x4 z = {0.f, 0.f, 0.f, 0.f};
      z = __builtin_amdgcn_mfma_f32_16x16x32_bf16(a0, bq0, z, 0, 0, 0);
      st[kt] = __builtin_amdgcn_mfma_f32_16x16x32_bf16(a1, bq1, z, 0, 0, 0);
    }

    float tm = -3.0e38f;
#pragma unroll
    for (int kt = 0; kt < 4; ++kt)
#pragma unroll
      for (int r = 0; r < 4; ++r) {
        int key = t * 64 + kt * 16 + g * 4 + r;
        float s = (key < KSEL) ? st[kt][r] * 0.125f : -1.0e30f;
        st[kt][r] = s;
        tm = fmaxf(tm, s);
      }
    tm = fmaxf(tm, __shfl_xor(tm, 16, 64));
    tm = fmaxf(tm, __shfl_xor(tm, 32, 64));
    float newm = fmaxf(m, tm);
    float f = __expf(m - newm);
    float tsum = 0.f;
#pragma unroll
    for (int kt = 0; kt < 4; ++kt)
#pragma unroll
      for (int r = 0; r < 4; ++r) {
        float e = __expf(st[kt][r] - newm);
        st[kt][r] = e;
        tsum += e;
      }
    tsum += __shfl_xor(tsum, 16, 64);
    tsum += __shfl_xor(tsum, 32, 64);
    l = l * f + tsum;
    m = newm;
#pragma unroll
    for (int mf = 0; mf < 4; ++mf)
#pragma unroll
      for (int r = 0; r < 4; ++r) oacc[mf][r] *= f;

    unsigned short* pw = &Pl[w * 1088 + fr * 68 + g * 4];
#pragma unroll
    for (int kt = 0; kt < 4; ++kt) {
      uint2 pk;
      pk.x = (unsigned)f2b(st[kt][0]) | ((unsigned)f2b(st[kt][1]) << 16);
      pk.y = (unsigned)f2b(st[kt][2]) | ((unsigned)f2b(st[kt][3]) << 16);
      *(uint2*)(pw + kt * 16) = pk;
    }

    const unsigned short* prd = &Pl[w * 1088 + fr * 68];
#pragma unroll
    for (int ks2 = 0; ks2 < 2; ++ks2) {
      bf16x8 pf = *(const bf16x8*)(prd + ks2 * 32 + g * 8);
#pragma unroll
      for (int mf = 0; mf < 4; ++mf) {
        int vr = mf * 16 + fr;
        int vc = ks2 * 4 + g;
        bf16x8 vf = *(const bf16x8*)(&Vl[cur * 4096 + (vr * 8 + (vc ^ (vr & 7))) * 8]);
        oacc[mf] = __builtin_amdgcn_mfma_f32_16x16x32_bf16(vf, pf, oacc[mf], 0, 0, 0);
      }
    }

    asm volatile("s_waitcnt vmcnt(0)" ::: "memory");
    __syncthreads();
  }

  float inv = 1.f / l;
  unsigned short* orow = comb + qrow * 2304 + hoff;
#pragma unroll
  for (int mf = 0; mf < 4; ++mf) {
    uint2 pk;
    pk.x = (unsigned)f2b(oacc[mf][0] * inv) | ((unsigned)f2b(oacc[mf][1] * inv) << 16);
    pk.y = (unsigned)f2b(oacc[mf][2] * inv) | ((unsigned)f2b(oacc[mf][3] * inv) << 16);
    *(uint2*)(orow + mf * 16 + g * 4) = pk;
  }
}

__device__ __forceinline__ void attn_win_body(
    const unsigned short* __restrict__ QKV,
    const unsigned short* __restrict__ K8,
    const unsigned short* __restrict__ Vt,
    unsigned short* __restrict__ comb, int brOff,
    int LD, int QO, long VSTR, bool local,
    unsigned short* smem) {
  int tid = threadIdx.x, w = tid >> 6, lane = tid & 63;
  int fr = lane & 15, g = lane >> 4;
  int b = blockIdx.y / HH, h = blockIdx.y % HH, hoff = h * 64;
  int qbase = blockIdx.x * 64 + w * 16;
  long qrow = (long)b * SS + qbase + fr;

  const unsigned short* qptr = QKV + qrow * LD + QO + hoff + g * 8;
  bf16x8 bq0 = *(const bf16x8*)(qptr);
  bf16x8 bq1 = *(const bf16x8*)(qptr + 32);

  int kstart = qbase - 8;
  if (kstart < 0) kstart = 0;
  if (kstart > SS - 32) kstart = SS - 32;

  f32x4 st[2];
  if (local) {
#pragma unroll
    for (int kt = 0; kt < 2; ++kt) {
      const unsigned short* kp =
          QKV + ((long)b * SS + kstart + kt * 16 + fr) * LD + 1536 + hoff + g * 8;
      bf16x8 a0 = *(const bf16x8*)(kp);
      bf16x8 a1 = *(const bf16x8*)(kp + 32);
      f32x4 z = {0.f, 0.f, 0.f, 0.f};
      z = __builtin_amdgcn_mfma_f32_16x16x32_bf16(a0, bq0, z, 0, 0, 0);
      st[kt] = __builtin_amdgcn_mfma_f32_16x16x32_bf16(a1, bq1, z, 0, 0, 0);
    }
  } else {
    const unsigned short* kp = K8 + ((long)b * 16 + fr) * DD + hoff + g * 8;
    bf16x8 a0 = *(const bf16x8*)(kp);
    bf16x8 a1 = *(const bf16x8*)(kp + 32);
    f32x4 z = {0.f, 0.f, 0.f, 0.f};
    z = __builtin_amdgcn_mfma_f32_16x16x32_bf16(a0, bq0, z, 0, 0, 0);
    st[0] = __builtin_amdgcn_mfma_f32_16x16x32_bf16(a1, bq1, z, 0, 0, 0);
    st[1] = f32x4{0.f, 0.f, 0.f, 0.f};
  }

  float m = -3.0e38f;
#pragma unroll
  for (int kt = 0; kt < 2; ++kt)
#pragma unroll
    for (int r = 0; r < 4; ++r) {
      int idx = kt * 16 + g * 4 + r;
      bool valid;
      if (local) {
        int rel = kstart + idx - qbase - fr;
        valid = (rel >= -8) && (rel <= 8);
      } else {
        valid = (idx < 8);
      }
      float s = valid ? st[kt][r] * 0.125f : -1.0e30f;
      st[kt][r] = s;
      m = fmaxf(m, s);
    }
  m = fmaxf(m, __shfl_xor(m, 16, 64));
  m = fmaxf(m, __shfl_xor(m, 32, 64));

  float lsum = 0.f;
#pragma unroll
  for (int kt = 0; kt < 2; ++kt)
#pragma unroll
    for (int r = 0; r < 4; ++r) {
      float e = __expf(st[kt][r] - m);
      st[kt][r] = e;
      lsum += e;
    }
  lsum += __shfl_xor(lsum, 16, 64);
  lsum += __shfl_xor(lsum, 32, 64);

  unsigned short* pl = smem + w * 640 + fr * 40 + g * 4;
#pragma unroll
  for (int kt = 0; kt < 2; ++kt) {
    uint2 pk;
    pk.x = (unsigned)f2b(st[kt][0]) | ((unsigned)f2b(st[kt][1]) << 16);
    pk.y = (unsigned)f2b(st[kt][2]) | ((unsigned)f2b(st[kt][3]) << 16);
    *(uint2*)(pl + kt * 16) = pk;
  }

  f32x4 oacc[4];
#pragma unroll
  for (int mf = 0; mf < 4; ++mf)
#pragma unroll
    for (int r = 0; r < 4; ++r) oacc[mf][r] = 0.f;

  const unsigned short* pr = smem + w * 640 + fr * 40 + g * 8;
  bf16x8 pf = *(const bf16x8*)(pr);
  long kb2 = local ? kstart : 0;
#pragma unroll
  for (int mf = 0; mf < 4; ++mf) {
    const unsigned short* vp =
        Vt + ((long)b * DD + hoff + mf * 16 + fr) * VSTR + kb2 + g * 8;
    bf16x8 vf = *(const bf16x8*)(vp);
    oacc[mf] = __builtin_amdgcn_mfma_f32_16x16x32_bf16(vf, pf, oacc[mf], 0, 0, 0);
  }

  float inv = 1.f / lsum;
  unsigned short* orow = comb + qrow * 2304 + brOff + hoff;
#pragma unroll
  for (int mf = 0; mf < 4; ++mf) {
    uint2 pk;
    pk.x = (unsigned)f2b(oacc[mf][0] * inv) | ((unsigned)f2b(oacc[mf][1] * inv) << 16);
    pk.y = (unsigned)f2b(oacc[mf][2] * inv) | ((unsigned)f2b(oacc[mf][3] * inv) << 16);
    *(uint2*)(orow + mf * 16 + g * 4) = pk;
  }
}

// ---------------- merged attention dispatch (z: 0=global 1=local 2=temporal)
__global__ __launch_bounds__(256) void attn_all(
    const unsigned short* __restrict__ QKV4,
    const unsigned short* __restrict__ KVg,
    const unsigned short* __restrict__ Vt,
    const unsigned short* __restrict__ Qt,
    const unsigned short* __restrict__ K8,
    const unsigned short* __restrict__ Vt8,
    const unsigned short* __restrict__ Vtl,
    unsigned short* __restrict__ comb) {
  __shared__ unsigned short smem[20736];
  int z = blockIdx.z;
  if (z == 0) {
    attn_flash_body(QKV4, KVg, Vt, comb, smem);
  } else if (z == 1) {
    attn_win_body(QKV4, nullptr, Vtl, comb, 768, 3072, 768, SS, true, smem);
  } else {
    attn_win_body(Qt, K8, Vt8, comb, 1536, 768, 0, 32, false, smem);
  }
}

// ---------------- in-place layernorm + gate scale on comb (bf16) ------------
__global__ __launch_bounds__(256) void ln_gate_inplace(
    unsigned short* __restrict__ comb,
    const float* __restrict__ gg, const float* __restrict__ gb,
    const float* __restrict__ lgam, const float* __restrict__ lbet,
    const float* __restrict__ tg, const float* __restrict__ tb,
    const float* __restrict__ fw) {
  int row = blockIdx.x;
  int b = row >> 11;
  int tid = threadIdx.x;
  __shared__ float red[8];
  const float* gams[3] = {gg, lgam, tg};
  const float* bets[3] = {gb, lbet, tb};
#pragma unroll
  for (int br = 0; br < 3; ++br) {
    unsigned short* p = comb + (long)row * 2304 + br * DD;
    float x0 = b2f(p[tid]), x1 = b2f(p[tid + 256]), x2 = b2f(p[tid + 512]);
    float s = x0 + x1 + x2;
    float ss = x0 * x0 + x1 * x1 + x2 * x2;
#pragma unroll
    for (int msk = 1; msk < 64; msk <<= 1) {
      s += __shfl_xor(s, msk, 64);
      ss += __shfl_xor(ss, msk, 64);
    }
    int wv = tid >> 6, lane = tid & 63;
    if (lane == 0) { red[wv] = s; red[4 + wv] = ss; }
    __syncthreads();
    float S4 = red[0] + red[1] + red[2] + red[3];
    float SQ = red[4] + red[5] + red[6] + red[7];
    float mean = S4 * (1.f / (float)DD);
    float var = SQ * (1.f / (float)DD) - mean * mean;
    float rs = rsqrtf(var + 1e-5f);
    float gate = fw[b * 3 + br];
    const float* gam = gams[br];
    const float* bet = bets[br];
    p[tid]       = f2b(((x0 - mean) * rs * gam[tid]       + bet[tid])       * gate);
    p[tid + 256] = f2b(((x1 - mean) * rs * gam[tid + 256] + bet[tid + 256]) * gate);
    p[tid + 512] = f2b(((x2 - mean) * rs * gam[tid + 512] + bet[tid + 512]) * gate);
    __syncthreads();
  }
}

// ---------------- launcher ---------------------------------------------------
extern "C" void kernel_launch(void* const* d_in, const int* in_sizes, int n_in,
                              void* d_out, int out_size, void* d_ws, size_t ws_size,
                              hipStream_t stream) {
  const float* x        = (const float*)d_in[0];
  const float* wgq      = (const float*)d_in[1];
  const float* wgk      = (const float*)d_in[2];
  const float* wgv      = (const float*)d_in[3];
  const float* wlq      = (const float*)d_in[4];
  const float* wlk      = (const float*)d_in[5];
  const float* wlv      = (const float*)d_in[6];
  const float* wtq      = (const float*)d_in[7];
  const float* wtk      = (const float*)d_in[8];
  const float* wtv      = (const float*)d_in[9];
  const float* w_out    = (const float*)d_in[10];
  const float* b_out    = (const float*)d_in[11];
  const float* w_gate   = (const float*)d_in[12];
  const float* b_gate   = (const float*)d_in[13];
  const float* w_sparse = (const float*)d_in[14];
  const float* b_sparse = (const float*)d_in[15];
  const float* g_gamma  = (const float*)d_in[16];
  const float* g_beta   = (const float*)d_in[17];
  const float* l_gamma  = (const float*)d_in[18];
  const float* l_beta   = (const float*)d_in[19];
  const float* t_gamma  = (const float*)d_in[20];
  const float* t_beta   = (const float*)d_in[21];
  float* outp = (float*)d_out;

  unsigned short* xb    = (unsigned short*)d_ws;
  unsigned short* xpb   = xb    + (long)NTOK * DD;
  unsigned short* WTx4  = xpb   + (long)NTOK * DD;        // [3072][768]
  unsigned short* WTkv  = WTx4  + (long)3072 * DD;        // [1536][768]
  unsigned short* WTqt  = WTkv  + (long)1536 * DD;        // [768][768]
  unsigned short* WTtkv = WTqt  + (long)DD * DD;          // [1536][768]
  unsigned short* WTo   = WTtkv + (long)1536 * DD;        // [768][2304]
  unsigned short* QKV4  = WTo   + (long)DD * 2304;        // [4096][3072]
  unsigned short* Qt    = QKV4  + (long)NTOK * 3072;      // [4096][768]
  unsigned short* KVg   = Qt    + (long)NTOK * DD;        // [896][1536]
  unsigned short* K8    = KVg   + (long)BB * KPAD * 1536; // [2][16][768]
  unsigned short* Vt8   = K8    + (long)BB * 16 * DD;     // [2][768][32]
  unsigned short* Vt    = Vt8   + (long)BB * DD * 32;     // [2][768][448]
  unsigned short* Vtl   = Vt    + (long)BB * DD * KPAD;   // [2][768][2048]
  unsigned short* comb  = Vtl   + (long)BB * DD * SS;     // [4096][2304]
  float* Cpart   = (float*)(comb + (long)NTOK * 2304);    // [3][4096][768]
  float* imp     = Cpart + 3L * NTOK * DD;
  float* partial = imp + NTOK;
  float* fw      = partial + 32 * DD;
  int*   sel     = (int*)(fw + 8);

  mega_pre<<<SS + 6912 + 32, 256, 0, stream>>>(
      x, w_sparse, b_sparse, xb, xpb, imp,
      wgq, wgk, wgv, wlq, wlk, wlv, wtq, wtk, wtv, w_out,
      WTx4, WTkv, WTqt, WTtkv, WTo, partial);
  topk_gate2<<<4, 1024, 0, stream>>>(imp, sel, partial, w_gate, b_gate, fw);

  gemm_multi<<<1056, 256, 0, stream>>>(xb, WTx4, QKV4, WTkv, KVg,
                                       xpb, WTqt, Qt, WTtkv, sel,
                                       K8, Vt8, Vt, Vtl);

  attn_all<<<dim3(32, BB * HH, 3), 256, 0, stream>>>(QKV4, KVg, Vt, Qt, K8, Vt8,
                                                     Vtl, comb);

  ln_gate_inplace<<<NTOK, 256, 0, stream>>>(comb, g_gamma, g_beta,
                                            l_gamma, l_beta, t_gamma, t_beta, fw);
  gemm_final_sk<<<dim3(6, 32, 3), 256, 0, stream>>>(comb, WTo, Cpart);
  reduce_out<<<NTOK * DD / 4 / 256, 256, 0, stream>>>(Cpart, b_out, outp);
}